// Round 1
// baseline (1281.941 us; speedup 1.0000x reference)
//
#include <hip/hip_runtime.h>
#include <hip/hip_bf16.h>
#include <math.h>

#define NN 100000
#define NE 1600000
#define NEP 1700000        // NE + NN (self loops)
#define HD 64
#define NEGS 0.2f

// ============================ CSR build ============================

__global__ void k_init_cnt(int* __restrict__ cnt) {
  int i = blockIdx.x * 256 + threadIdx.x;
  if (i < NN) cnt[i] = 1;             // self loop pre-counted
}

__global__ void k_count(const int* __restrict__ dst, int* __restrict__ cnt) {
  int i = blockIdx.x * 256 + threadIdx.x;
  if (i < NE) atomicAdd(&cnt[dst[i]], 1);
}

__global__ void k_scan_a(const int* __restrict__ cnt, int* __restrict__ rp,
                         int* __restrict__ bsum) {
  __shared__ int tmp[1024];
  int t = threadIdx.x, b = blockIdx.x;
  int i = b * 1024 + t;
  int v = (i < NN) ? cnt[i] : 0;
  tmp[t] = v; __syncthreads();
  for (int off = 1; off < 1024; off <<= 1) {
    int a = (t >= off) ? tmp[t - off] : 0;
    __syncthreads(); tmp[t] += a; __syncthreads();
  }
  if (i < NN) rp[i] = tmp[t] - v;     // exclusive
  if (t == 1023) bsum[b] = tmp[t];    // block total
}

__global__ void k_scan_b(const int* __restrict__ bsum, int* __restrict__ boff, int nb) {
  __shared__ int tmp[1024];
  int t = threadIdx.x;
  int v = (t < nb) ? bsum[t] : 0;
  tmp[t] = v; __syncthreads();
  for (int off = 1; off < 1024; off <<= 1) {
    int a = (t >= off) ? tmp[t - off] : 0;
    __syncthreads(); tmp[t] += a; __syncthreads();
  }
  if (t < nb) boff[t] = tmp[t] - v;
}

__global__ void k_scan_c(int* __restrict__ rp, const int* __restrict__ boff,
                         int* __restrict__ cursor) {
  int t = threadIdx.x, b = blockIdx.x;
  int i = b * 1024 + t;
  if (i < NN) { int r = rp[i] + boff[b]; rp[i] = r; cursor[i] = r; }
  if (i == 0) rp[NN] = NEP;
}

__global__ void k_scatter(const int* __restrict__ src, const int* __restrict__ dst,
                          int* __restrict__ cursor, int2* __restrict__ pse) {
  int i = blockIdx.x * 256 + threadIdx.x;
  if (i >= NEP) return;
  int s, d;
  if (i < NE) { s = src[i]; d = dst[i]; }
  else        { s = i - NE; d = s; }     // self loop, edge id = NE + n
  int p = atomicAdd(&cursor[d], 1);
  pse[p] = make_int2(s, i);
}

// loop attr = mean of incoming ORIGINAL edge_attr per node (0 if none)
__global__ void k_loopattr(const int* __restrict__ rp, const int2* __restrict__ pse,
                           const float* __restrict__ ea, float* __restrict__ la) {
  int n = blockIdx.x * 256 + threadIdx.x;
  if (n >= NN) return;
  int p0 = rp[n], p1 = rp[n + 1];
  float s0 = 0, s1 = 0, s2 = 0, s3 = 0, s4 = 0, s5 = 0; int c = 0;
  for (int p = p0; p < p1; ++p) {
    int id = pse[p].y;
    if (id < NE) {
      const float* r = ea + (size_t)id * 6;
      s0 += r[0]; s1 += r[1]; s2 += r[2]; s3 += r[3]; s4 += r[4]; s5 += r[5];
      ++c;
    }
  }
  float inv = c ? 1.0f / (float)c : 0.0f;
  float* o = la + (size_t)n * 6;
  o[0] = s0 * inv; o[1] = s1 * inv; o[2] = s2 * inv;
  o[3] = s3 * inv; o[4] = s4 * inv; o[5] = s5 * inv;
}

// ====================== node transforms (xl, xr) ======================
// wave per node; lane h owns output channel h; weights held in registers.
template <int DIN>
__global__ void __launch_bounds__(256) k_xform(
    const float* __restrict__ x,
    const float* __restrict__ wl, const float* __restrict__ bl,
    const float* __restrict__ wr, const float* __restrict__ br,
    float* __restrict__ xl, float* __restrict__ xr) {
  int tid = threadIdx.x;
  int lane = tid & 63, wid = tid >> 6;
  int h = lane;
  float wlr[DIN], wrr[DIN];
#pragma unroll
  for (int k = 0; k < DIN; ++k) { wlr[k] = wl[k * 64 + h]; wrr[k] = wr[k * 64 + h]; }
  float blv = bl[h], brv = br[h];
  int stride = gridDim.x * 4;
  for (int n = blockIdx.x * 4 + wid; n < NN; n += stride) {
    float xv = (lane < DIN) ? x[(size_t)n * DIN + lane] : 0.0f;
    float aL = blv, aR = brv;
#pragma unroll
    for (int k = 0; k < DIN; ++k) {
      float xk = __shfl(xv, k);           // literal k -> v_readlane + scalar FMA
      aL = fmaf(xk, wlr[k], aL);
      aR = fmaf(xk, wrr[k], aR);
    }
    xl[(size_t)n * 64 + h] = aL;
    xr[(size_t)n * 64 + h] = aR;
  }
}

// ============== fused edge-logit + online softmax + aggregate ==============
// wave per node; lane = channel; online (flash-style) max/den/acc; all
// cross-lane state is wave-uniform after the butterfly reduce.
__global__ void __launch_bounds__(256) k_fused(
    const float* __restrict__ xl, const float* __restrict__ xr,
    const float* __restrict__ ea, const float* __restrict__ la,
    const int* __restrict__ rp, const int2* __restrict__ pse,
    const float* __restrict__ we, const float* __restrict__ att,
    const float* __restrict__ bo, float* __restrict__ hout) {
  int tid = threadIdx.x;
  int lane = tid & 63, wid = tid >> 6;
  int h = lane;
  float w0 = we[h], w1 = we[64 + h], w2 = we[128 + h],
        w3 = we[192 + h], w4 = we[256 + h], w5 = we[320 + h];
  float av = att[h], bov = bo[h];
  int stride = gridDim.x * 4;
  for (int n = blockIdx.x * 4 + wid; n < NN; n += stride) {
    int p0 = rp[n], p1 = rp[n + 1];
    float xrh = xr[(size_t)n * 64 + h];
    float m = -INFINITY, den = 0.0f, acc = 0.0f;
    for (int p = p0; p < p1; ++p) {
      int2 se = pse[p];
      int s = se.x, id = se.y;
      const float* ar = (id < NE) ? (ea + (size_t)id * 6)
                                  : (la + (size_t)(id - NE) * 6);
      float xlh = xl[(size_t)s * 64 + h];
      float mv = xlh + xrh + ar[0] * w0 + ar[1] * w1 + ar[2] * w2
                            + ar[3] * w3 + ar[4] * w4 + ar[5] * w5;
      float lr = mv > 0.0f ? mv : NEGS * mv;
      float v = lr * av;
#pragma unroll
      for (int off = 32; off; off >>= 1) v += __shfl_xor(v, off);
      // v identical in all lanes -> uniform branch
      if (v > m) {
        float r = __expf(m - v);          // first iter: exp(-inf)=0
        den *= r; acc *= r; m = v;
      }
      float ex = __expf(v - m);
      den += ex;
      acc = fmaf(ex, xlh, acc);
    }
    float o = acc / (den + 1e-16f) + bov;
    hout[(size_t)n * 64 + h] = o > 0.0f ? o : 0.0f;  // relu
  }
}

// ====================== MLP head: 64 -> 32 (relu) -> 4 ======================
// wave handles 2 nodes: lanes 0-31 node n0, lanes 32-63 node n1.
__global__ void __launch_bounds__(256) k_mlp(
    const float* __restrict__ hin,
    const float* __restrict__ wlin, const float* __restrict__ blin,
    const float* __restrict__ wout, const float* __restrict__ bout,
    float* __restrict__ out) {
  int tid = threadIdx.x;
  int lane = tid & 63, wid = tid >> 6;
  int j = lane & 31, half = lane >> 5;
  float wr_[64];
#pragma unroll
  for (int k = 0; k < 64; ++k) wr_[k] = wlin[k * 32 + j];
  float blv = blin[j];
  float wo0 = wout[j * 4 + 0], wo1 = wout[j * 4 + 1],
        wo2 = wout[j * 4 + 2], wo3 = wout[j * 4 + 3];
  float bo0 = bout[0], bo1 = bout[1], bo2 = bout[2], bo3 = bout[3];
  const int NP = NN / 2;
  int stride = gridDim.x * 4;
  for (int np = blockIdx.x * 4 + wid; np < NP; np += stride) {
    int n0 = np * 2, n1 = np * 2 + 1;
    float v0 = hin[(size_t)n0 * 64 + lane];
    float v1 = hin[(size_t)n1 * 64 + lane];
    float acc = blv;
#pragma unroll
    for (int k = 0; k < 64; ++k) {
      float a = __shfl(v0, k), b = __shfl(v1, k);
      float xk = half ? b : a;
      acc = fmaf(xk, wr_[k], acc);
    }
    float t = acc > 0.0f ? acc : 0.0f;
    float p0 = t * wo0, p1 = t * wo1, p2 = t * wo2, p3 = t * wo3;
#pragma unroll
    for (int off = 16; off; off >>= 1) {   // stays within each 32-lane half
      p0 += __shfl_xor(p0, off); p1 += __shfl_xor(p1, off);
      p2 += __shfl_xor(p2, off); p3 += __shfl_xor(p3, off);
    }
    if (j == 0) {
      int n = half ? n1 : n0;
      float4 r = make_float4(p0 + bo0, p1 + bo1, p2 + bo2, p3 + bo3);
      *(float4*)(out + (size_t)n * 4) = r;
    }
  }
}

// ============================ launch ============================

extern "C" void kernel_launch(void* const* d_in, const int* in_sizes, int n_in,
                              void* d_out, int out_size, void* d_ws, size_t ws_size,
                              hipStream_t stream) {
  const float* x  = (const float*)d_in[0];
  const int*   ei = (const int*)d_in[1];
  const float* ea = (const float*)d_in[2];
  const int* src = ei;
  const int* dst = ei + NE;

  const float *wl[3], *bl[3], *wrm[3], *br[3], *wem[3], *attv[3], *bov[3];
  for (int l = 0; l < 3; ++l) {
    int b = 3 + l * 7;
    wl[l]  = (const float*)d_in[b + 0];
    bl[l]  = (const float*)d_in[b + 1];
    wrm[l] = (const float*)d_in[b + 2];
    br[l]  = (const float*)d_in[b + 3];
    wem[l] = (const float*)d_in[b + 4];
    attv[l]= (const float*)d_in[b + 5];
    bov[l] = (const float*)d_in[b + 6];
  }
  const float* wlin = (const float*)d_in[24];
  const float* blin = (const float*)d_in[25];
  const float* wout = (const float*)d_in[26];
  const float* bout = (const float*)d_in[27];
  float* outp = (float*)d_out;

  // workspace carve (256B aligned)
  char* w = (char*)d_ws;
  size_t off = 0;
  auto carve = [&](size_t bytes) -> void* {
    void* p = w + off;
    off += (bytes + 255) & ~(size_t)255;
    return p;
  };
  int*   cnt  = (int*)carve((size_t)NN * 4);          // then reused as cursor
  int*   rp   = (int*)carve((size_t)(NN + 1) * 4);
  int*   bsum = (int*)carve(1024 * 4);
  int*   boff = (int*)carve(1024 * 4);
  int2*  pse  = (int2*)carve((size_t)NEP * 8);
  float* la   = (float*)carve((size_t)NN * 6 * 4);
  float* xlb  = (float*)carve((size_t)NN * 64 * 4);
  float* xrb  = (float*)carve((size_t)NN * 64 * 4);
  float* hA   = (float*)carve((size_t)NN * 64 * 4);
  float* hB   = (float*)carve((size_t)NN * 64 * 4);
  (void)ws_size; (void)n_in; (void)in_sizes; (void)out_size;

  const int SCAN_NB = (NN + 1023) / 1024;  // 98

  hipLaunchKernelGGL(k_init_cnt, dim3((NN + 255) / 256), dim3(256), 0, stream, cnt);
  hipLaunchKernelGGL(k_count, dim3((NE + 255) / 256), dim3(256), 0, stream, dst, cnt);
  hipLaunchKernelGGL(k_scan_a, dim3(SCAN_NB), dim3(1024), 0, stream, cnt, rp, bsum);
  hipLaunchKernelGGL(k_scan_b, dim3(1), dim3(1024), 0, stream, bsum, boff, SCAN_NB);
  hipLaunchKernelGGL(k_scan_c, dim3(SCAN_NB), dim3(1024), 0, stream, rp, boff, cnt);
  hipLaunchKernelGGL(k_scatter, dim3((NEP + 255) / 256), dim3(256), 0, stream,
                     src, dst, cnt, pse);
  hipLaunchKernelGGL(k_loopattr, dim3((NN + 255) / 256), dim3(256), 0, stream,
                     rp, pse, ea, la);

  // layer 1 (din=6): x -> hA
  hipLaunchKernelGGL((k_xform<6>), dim3(1024), dim3(256), 0, stream,
                     x, wl[0], bl[0], wrm[0], br[0], xlb, xrb);
  hipLaunchKernelGGL(k_fused, dim3(4096), dim3(256), 0, stream,
                     xlb, xrb, ea, la, rp, pse, wem[0], attv[0], bov[0], hA);
  // layer 2: hA -> hB
  hipLaunchKernelGGL((k_xform<64>), dim3(2048), dim3(256), 0, stream,
                     hA, wl[1], bl[1], wrm[1], br[1], xlb, xrb);
  hipLaunchKernelGGL(k_fused, dim3(4096), dim3(256), 0, stream,
                     xlb, xrb, ea, la, rp, pse, wem[1], attv[1], bov[1], hB);
  // layer 3: hB -> hA
  hipLaunchKernelGGL((k_xform<64>), dim3(2048), dim3(256), 0, stream,
                     hB, wl[2], bl[2], wrm[2], br[2], xlb, xrb);
  hipLaunchKernelGGL(k_fused, dim3(4096), dim3(256), 0, stream,
                     xlb, xrb, ea, la, rp, pse, wem[2], attv[2], bov[2], hA);
  // MLP head
  hipLaunchKernelGGL(k_mlp, dim3(2048), dim3(256), 0, stream,
                     hA, wlin, blin, wout, bout, outp);
}

// Round 2
// 1146.499 us; speedup vs baseline: 1.1181x; 1.1181x over previous
//
#include <hip/hip_runtime.h>
#include <hip/hip_bf16.h>
#include <math.h>

#define NN 100000
#define NE 1600000
#define NEP 1700000        // NE + NN (self loops)
#define HD 64
#define NEGS 0.2f

// ============================ CSR build ============================

__global__ void k_init_cnt(int* __restrict__ cnt, int* __restrict__ hist,
                           int* __restrict__ cursor2) {
  int i = blockIdx.x * 256 + threadIdx.x;
  if (i < NN) cnt[i] = 1;             // self loop pre-counted
  if (blockIdx.x == 0) {
    if (threadIdx.x < 64) hist[threadIdx.x] = 0;
    else if (threadIdx.x < 128) cursor2[threadIdx.x - 64] = 0;
  }
}

__global__ void k_count(const int* __restrict__ dst, int* __restrict__ cnt) {
  int i = blockIdx.x * 256 + threadIdx.x;
  if (i < NE) atomicAdd(&cnt[dst[i]], 1);
}

// scan of cnt -> rp (exclusive) ; also 64-bin degree histogram (LDS-batched)
__global__ void k_scan_a(const int* __restrict__ cnt, int* __restrict__ rp,
                         int* __restrict__ bsum, int* __restrict__ hist) {
  __shared__ int tmp[1024];
  __shared__ int lh[64];
  int t = threadIdx.x, b = blockIdx.x;
  int i = b * 1024 + t;
  int v = (i < NN) ? cnt[i] : 0;
  tmp[t] = v;
  if (t < 64) lh[t] = 0;
  __syncthreads();
  if (i < NN) atomicAdd(&lh[v < 63 ? v : 63], 1);
  for (int off = 1; off < 1024; off <<= 1) {
    int a = (t >= off) ? tmp[t - off] : 0;
    __syncthreads(); tmp[t] += a; __syncthreads();
  }
  if (i < NN) rp[i] = tmp[t] - v;     // exclusive
  if (t == 1023) bsum[b] = tmp[t];    // block total
  if (t < 64) { int h = lh[t]; if (h) atomicAdd(&hist[t], h); }
}

__global__ void k_scan_b(const int* __restrict__ bsum, int* __restrict__ boff, int nb,
                         const int* __restrict__ hist, int* __restrict__ cursor2) {
  __shared__ int tmp[1024];
  int t = threadIdx.x;
  int v = (t < nb) ? bsum[t] : 0;
  tmp[t] = v; __syncthreads();
  for (int off = 1; off < 1024; off <<= 1) {
    int a = (t >= off) ? tmp[t - off] : 0;
    __syncthreads(); tmp[t] += a; __syncthreads();
  }
  if (t < nb) boff[t] = tmp[t] - v;
  // exclusive scan of 64-bin degree histogram (wave 0 only)
  if (t < 64) {
    int h = hist[t];
    int s = h;
#pragma unroll
    for (int off = 1; off < 64; off <<= 1) {
      int u = __shfl_up(s, off);
      if (t >= off) s += u;
    }
    cursor2[t] = s - h;
  }
}

// finalize rp, init cursor, and scatter nodes into degree-sorted order[]
__global__ void k_scan_c(int* __restrict__ rp, const int* __restrict__ boff,
                         int* __restrict__ cursor,   // aliases cnt (holds degree)
                         int* __restrict__ cursor2, int* __restrict__ order) {
  int t = threadIdx.x, b = blockIdx.x;
  int i = b * 1024 + t;
  if (i < NN) {
    int d = cursor[i];                 // read degree BEFORE overwrite
    int r = rp[i] + boff[b];
    rp[i] = r;
    cursor[i] = r;
    int pos = atomicAdd(&cursor2[d < 63 ? d : 63], 1);
    order[pos] = i;
  }
  if (i == 0) rp[NN] = NEP;
}

__global__ void k_scatter(const int* __restrict__ src, const int* __restrict__ dst,
                          int* __restrict__ cursor, int2* __restrict__ pse) {
  int i = blockIdx.x * 256 + threadIdx.x;
  if (i >= NEP) return;
  int s, d;
  if (i < NE) { s = src[i]; d = dst[i]; }
  else        { s = i - NE; d = s; }     // self loop, edge id = NE + n
  int p = atomicAdd(&cursor[d], 1);
  pse[p] = make_int2(s, i);
}

// loop attr = mean of incoming ORIGINAL edge_attr per node (0 if none)
__global__ void k_loopattr(const int* __restrict__ rp, const int2* __restrict__ pse,
                           const float* __restrict__ ea, float* __restrict__ la) {
  int n = blockIdx.x * 256 + threadIdx.x;
  if (n >= NN) return;
  int p0 = rp[n], p1 = rp[n + 1];
  float s0 = 0, s1 = 0, s2 = 0, s3 = 0, s4 = 0, s5 = 0; int c = 0;
  for (int p = p0; p < p1; ++p) {
    int id = pse[p].y;
    if (id < NE) {
      const float* r = ea + (size_t)id * 6;
      s0 += r[0]; s1 += r[1]; s2 += r[2]; s3 += r[3]; s4 += r[4]; s5 += r[5];
      ++c;
    }
  }
  float inv = c ? 1.0f / (float)c : 0.0f;
  float* o = la + (size_t)n * 6;
  o[0] = s0 * inv; o[1] = s1 * inv; o[2] = s2 * inv;
  o[3] = s3 * inv; o[4] = s4 * inv; o[5] = s5 * inv;
}

// ====================== node transforms (xl, xr) ======================
template <int DIN>
__global__ void __launch_bounds__(256) k_xform(
    const float* __restrict__ x,
    const float* __restrict__ wl, const float* __restrict__ bl,
    const float* __restrict__ wr, const float* __restrict__ br,
    float* __restrict__ xl, float* __restrict__ xr) {
  int tid = threadIdx.x;
  int lane = tid & 63, wid = tid >> 6;
  int h = lane;
  float wlr[DIN], wrr[DIN];
#pragma unroll
  for (int k = 0; k < DIN; ++k) { wlr[k] = wl[k * 64 + h]; wrr[k] = wr[k * 64 + h]; }
  float blv = bl[h], brv = br[h];
  int stride = gridDim.x * 4;
  for (int n = blockIdx.x * 4 + wid; n < NN; n += stride) {
    float xv = (lane < DIN) ? x[(size_t)n * DIN + lane] : 0.0f;
    float aL = blv, aR = brv;
#pragma unroll
    for (int k = 0; k < DIN; ++k) {
      float xk = __shfl(xv, k);
      aL = fmaf(xk, wlr[k], aL);
      aR = fmaf(xk, wrr[k], aR);
    }
    xl[(size_t)n * 64 + h] = aL;
    xr[(size_t)n * 64 + h] = aR;
  }
}

// ============== fused edge-logit + online softmax + aggregate ==============
// 16 lanes per node, 4 channels per lane, 4 node-groups per wave.
// Nodes assigned via degree-sorted order[] so the 4 groups have similar
// trip counts. Branchless online softmax in log2 domain.
__global__ void __launch_bounds__(256) k_fused(
    const float* __restrict__ xl, const float* __restrict__ xr,
    const float* __restrict__ ea, const float* __restrict__ la,
    const int* __restrict__ rp, const int2* __restrict__ pse,
    const int* __restrict__ order,
    const float* __restrict__ we, const float* __restrict__ att,
    const float* __restrict__ bo, float* __restrict__ hout) {
  int tid = threadIdx.x;
  int lane = tid & 63;
  int q = lane & 15;
  int c0 = q * 4;
  float w0[4], w1[4], w2[4], w3[4], w4[4], w5[4], atv[4], bov[4];
#pragma unroll
  for (int c = 0; c < 4; ++c) {
    w0[c] = we[0 * 64 + c0 + c]; w1[c] = we[1 * 64 + c0 + c];
    w2[c] = we[2 * 64 + c0 + c]; w3[c] = we[3 * 64 + c0 + c];
    w4[c] = we[4 * 64 + c0 + c]; w5[c] = we[5 * 64 + c0 + c];
    atv[c] = att[c0 + c] * 1.44269504f;   // fold log2(e) into att
    bov[c] = bo[c0 + c];
  }
  int gw = (blockIdx.x * 256 + tid) >> 6;       // global wave id
  int slot = gw * 4 + (lane >> 4);              // node slot for this group
  int n = (slot < NN) ? order[slot] : -1;
  int p0 = 0, p1 = 0;
  float xrv[4] = {0, 0, 0, 0};
  if (n >= 0) {
    p0 = rp[n]; p1 = rp[n + 1];
    const float4 t = *(const float4*)(xr + (size_t)n * 64 + c0);
    xrv[0] = t.x; xrv[1] = t.y; xrv[2] = t.z; xrv[3] = t.w;
  }
  float m = -INFINITY, den = 0.0f;
  float acc[4] = {0, 0, 0, 0};
  for (int p = p0; p < p1; ++p) {
    int2 se = pse[p];
    int s = se.x, id = se.y;
    const float* ar = (id < NE) ? (ea + (size_t)id * 6)
                                : (la + (size_t)(id - NE) * 6);
    float2 a01 = *(const float2*)ar;
    float2 a23 = *(const float2*)(ar + 2);
    float2 a45 = *(const float2*)(ar + 4);
    float4 xt = *(const float4*)(xl + (size_t)s * 64 + c0);
    float xlv[4] = {xt.x, xt.y, xt.z, xt.w};
    float part = 0.0f;
#pragma unroll
    for (int c = 0; c < 4; ++c) {
      float t = xlv[c] + xrv[c];
      t = fmaf(a01.x, w0[c], t); t = fmaf(a01.y, w1[c], t);
      t = fmaf(a23.x, w2[c], t); t = fmaf(a23.y, w3[c], t);
      t = fmaf(a45.x, w4[c], t); t = fmaf(a45.y, w5[c], t);
      float lr = fmaxf(t, 0.2f * t);          // leaky relu, slope 0.2
      part = fmaf(lr, atv[c], part);
    }
    // 16-lane butterfly -> group-uniform logit (already *log2e)
    part += __shfl_xor(part, 1);
    part += __shfl_xor(part, 2);
    part += __shfl_xor(part, 4);
    part += __shfl_xor(part, 8);
    // branchless online softmax (log2 domain)
    float nm = fmaxf(m, part);
    float sc = exp2f(m - nm);                 // first iter: exp2(-inf)=0
    float ex = exp2f(part - nm);
    m = nm;
    den = fmaf(den, sc, ex);
#pragma unroll
    for (int c = 0; c < 4; ++c) acc[c] = fmaf(acc[c], sc, ex * xlv[c]);
  }
  if (n >= 0) {
    float inv = 1.0f / (den + 1e-16f);
    float4 o;
    o.x = fmaf(acc[0], inv, bov[0]);
    o.y = fmaf(acc[1], inv, bov[1]);
    o.z = fmaf(acc[2], inv, bov[2]);
    o.w = fmaf(acc[3], inv, bov[3]);
    o.x = o.x > 0.0f ? o.x : 0.0f;
    o.y = o.y > 0.0f ? o.y : 0.0f;
    o.z = o.z > 0.0f ? o.z : 0.0f;
    o.w = o.w > 0.0f ? o.w : 0.0f;
    *(float4*)(hout + (size_t)n * 64 + c0) = o;
  }
}

// ====================== MLP head: 64 -> 32 (relu) -> 4 ======================
__global__ void __launch_bounds__(256) k_mlp(
    const float* __restrict__ hin,
    const float* __restrict__ wlin, const float* __restrict__ blin,
    const float* __restrict__ wout, const float* __restrict__ bout,
    float* __restrict__ out) {
  int tid = threadIdx.x;
  int lane = tid & 63, wid = tid >> 6;
  int j = lane & 31, half = lane >> 5;
  float wr_[64];
#pragma unroll
  for (int k = 0; k < 64; ++k) wr_[k] = wlin[k * 32 + j];
  float blv = blin[j];
  float wo0 = wout[j * 4 + 0], wo1 = wout[j * 4 + 1],
        wo2 = wout[j * 4 + 2], wo3 = wout[j * 4 + 3];
  float bo0 = bout[0], bo1 = bout[1], bo2 = bout[2], bo3 = bout[3];
  const int NP = NN / 2;
  int stride = gridDim.x * 4;
  for (int np = blockIdx.x * 4 + wid; np < NP; np += stride) {
    int n0 = np * 2, n1 = np * 2 + 1;
    float v0 = hin[(size_t)n0 * 64 + lane];
    float v1 = hin[(size_t)n1 * 64 + lane];
    float acc = blv;
#pragma unroll
    for (int k = 0; k < 64; ++k) {
      float a = __shfl(v0, k), b = __shfl(v1, k);
      float xk = half ? b : a;
      acc = fmaf(xk, wr_[k], acc);
    }
    float t = acc > 0.0f ? acc : 0.0f;
    float p0 = t * wo0, p1 = t * wo1, p2 = t * wo2, p3 = t * wo3;
#pragma unroll
    for (int off = 16; off; off >>= 1) {
      p0 += __shfl_xor(p0, off); p1 += __shfl_xor(p1, off);
      p2 += __shfl_xor(p2, off); p3 += __shfl_xor(p3, off);
    }
    if (j == 0) {
      int n = half ? n1 : n0;
      float4 r = make_float4(p0 + bo0, p1 + bo1, p2 + bo2, p3 + bo3);
      *(float4*)(out + (size_t)n * 4) = r;
    }
  }
}

// ============================ launch ============================

extern "C" void kernel_launch(void* const* d_in, const int* in_sizes, int n_in,
                              void* d_out, int out_size, void* d_ws, size_t ws_size,
                              hipStream_t stream) {
  const float* x  = (const float*)d_in[0];
  const int*   ei = (const int*)d_in[1];
  const float* ea = (const float*)d_in[2];
  const int* src = ei;
  const int* dst = ei + NE;

  const float *wl[3], *bl[3], *wrm[3], *br[3], *wem[3], *attv[3], *bov[3];
  for (int l = 0; l < 3; ++l) {
    int b = 3 + l * 7;
    wl[l]  = (const float*)d_in[b + 0];
    bl[l]  = (const float*)d_in[b + 1];
    wrm[l] = (const float*)d_in[b + 2];
    br[l]  = (const float*)d_in[b + 3];
    wem[l] = (const float*)d_in[b + 4];
    attv[l]= (const float*)d_in[b + 5];
    bov[l] = (const float*)d_in[b + 6];
  }
  const float* wlin = (const float*)d_in[24];
  const float* blin = (const float*)d_in[25];
  const float* wout = (const float*)d_in[26];
  const float* bout = (const float*)d_in[27];
  float* outp = (float*)d_out;

  // workspace carve (256B aligned)
  char* w = (char*)d_ws;
  size_t off = 0;
  auto carve = [&](size_t bytes) -> void* {
    void* p = w + off;
    off += (bytes + 255) & ~(size_t)255;
    return p;
  };
  int*   cnt  = (int*)carve((size_t)NN * 4);          // then reused as cursor
  int*   rp   = (int*)carve((size_t)(NN + 1) * 4);
  int*   bsum = (int*)carve(1024 * 4);
  int*   boff = (int*)carve(1024 * 4);
  int*   hist = (int*)carve(64 * 4);
  int*   cur2 = (int*)carve(64 * 4);
  int*   order= (int*)carve((size_t)NN * 4);
  int2*  pse  = (int2*)carve((size_t)NEP * 8);
  float* la   = (float*)carve((size_t)NN * 6 * 4);
  float* xlb  = (float*)carve((size_t)NN * 64 * 4);
  float* xrb  = (float*)carve((size_t)NN * 64 * 4);
  float* hA   = (float*)carve((size_t)NN * 64 * 4);
  float* hB   = (float*)carve((size_t)NN * 64 * 4);
  (void)ws_size; (void)n_in; (void)in_sizes; (void)out_size;

  const int SCAN_NB = (NN + 1023) / 1024;  // 98
  const int FUSE_NB = (NN + 15) / 16;      // 6250 blocks: 4 waves x 4 groups each

  hipLaunchKernelGGL(k_init_cnt, dim3((NN + 255) / 256), dim3(256), 0, stream,
                     cnt, hist, cur2);
  hipLaunchKernelGGL(k_count, dim3((NE + 255) / 256), dim3(256), 0, stream, dst, cnt);
  hipLaunchKernelGGL(k_scan_a, dim3(SCAN_NB), dim3(1024), 0, stream, cnt, rp, bsum, hist);
  hipLaunchKernelGGL(k_scan_b, dim3(1), dim3(1024), 0, stream, bsum, boff, SCAN_NB,
                     hist, cur2);
  hipLaunchKernelGGL(k_scan_c, dim3(SCAN_NB), dim3(1024), 0, stream, rp, boff, cnt,
                     cur2, order);
  hipLaunchKernelGGL(k_scatter, dim3((NEP + 255) / 256), dim3(256), 0, stream,
                     src, dst, cnt, pse);
  hipLaunchKernelGGL(k_loopattr, dim3((NN + 255) / 256), dim3(256), 0, stream,
                     rp, pse, ea, la);

  // layer 1 (din=6): x -> hA
  hipLaunchKernelGGL((k_xform<6>), dim3(1024), dim3(256), 0, stream,
                     x, wl[0], bl[0], wrm[0], br[0], xlb, xrb);
  hipLaunchKernelGGL(k_fused, dim3(FUSE_NB), dim3(256), 0, stream,
                     xlb, xrb, ea, la, rp, pse, order, wem[0], attv[0], bov[0], hA);
  // layer 2: hA -> hB
  hipLaunchKernelGGL((k_xform<64>), dim3(2048), dim3(256), 0, stream,
                     hA, wl[1], bl[1], wrm[1], br[1], xlb, xrb);
  hipLaunchKernelGGL(k_fused, dim3(FUSE_NB), dim3(256), 0, stream,
                     xlb, xrb, ea, la, rp, pse, order, wem[1], attv[1], bov[1], hB);
  // layer 3: hB -> hA
  hipLaunchKernelGGL((k_xform<64>), dim3(2048), dim3(256), 0, stream,
                     hB, wl[2], bl[2], wrm[2], br[2], xlb, xrb);
  hipLaunchKernelGGL(k_fused, dim3(FUSE_NB), dim3(256), 0, stream,
                     xlb, xrb, ea, la, rp, pse, order, wem[2], attv[2], bov[2], hA);
  // MLP head
  hipLaunchKernelGGL(k_mlp, dim3(2048), dim3(256), 0, stream,
                     hA, wlin, blin, wout, bout, outp);
}

// Round 3
// 875.093 us; speedup vs baseline: 1.4649x; 1.3101x over previous
//
#include <hip/hip_runtime.h>
#include <hip/hip_bf16.h>
#include <math.h>

#define NN 100000
#define NE 1600000
#define NEP 1700000        // NE + NN (self loops)
#define HD 64
#define NEGS 0.2f

// ============================ CSR build ============================

__global__ void k_init_cnt(int* __restrict__ cnt, int* __restrict__ hist,
                           int* __restrict__ cursor2) {
  int i = blockIdx.x * 256 + threadIdx.x;
  if (i < NN) cnt[i] = 1;             // self loop pre-counted
  if (blockIdx.x == 0) {
    if (threadIdx.x < 64) hist[threadIdx.x] = 0;
    else if (threadIdx.x < 128) cursor2[threadIdx.x - 64] = 0;
  }
}

__global__ void k_count(const int* __restrict__ dst, int* __restrict__ cnt) {
  int i = blockIdx.x * 256 + threadIdx.x;
  if (i < NE) atomicAdd(&cnt[dst[i]], 1);
}

// scan of cnt -> rp (exclusive) ; also 64-bin degree histogram (LDS-batched)
__global__ void k_scan_a(const int* __restrict__ cnt, int* __restrict__ rp,
                         int* __restrict__ bsum, int* __restrict__ hist) {
  __shared__ int tmp[1024];
  __shared__ int lh[64];
  int t = threadIdx.x, b = blockIdx.x;
  int i = b * 1024 + t;
  int v = (i < NN) ? cnt[i] : 0;
  tmp[t] = v;
  if (t < 64) lh[t] = 0;
  __syncthreads();
  if (i < NN) atomicAdd(&lh[v < 63 ? v : 63], 1);
  for (int off = 1; off < 1024; off <<= 1) {
    int a = (t >= off) ? tmp[t - off] : 0;
    __syncthreads(); tmp[t] += a; __syncthreads();
  }
  if (i < NN) rp[i] = tmp[t] - v;     // exclusive
  if (t == 1023) bsum[b] = tmp[t];    // block total
  if (t < 64) { int h = lh[t]; if (h) atomicAdd(&hist[t], h); }
}

__global__ void k_scan_b(const int* __restrict__ bsum, int* __restrict__ boff, int nb,
                         const int* __restrict__ hist, int* __restrict__ cursor2) {
  __shared__ int tmp[1024];
  int t = threadIdx.x;
  int v = (t < nb) ? bsum[t] : 0;
  tmp[t] = v; __syncthreads();
  for (int off = 1; off < 1024; off <<= 1) {
    int a = (t >= off) ? tmp[t - off] : 0;
    __syncthreads(); tmp[t] += a; __syncthreads();
  }
  if (t < nb) boff[t] = tmp[t] - v;
  // exclusive scan of 64-bin degree histogram (wave 0 only) -> bin bases
  if (t < 64) {
    int h = hist[t];
    int s = h;
#pragma unroll
    for (int off = 1; off < 64; off <<= 1) {
      int u = __shfl_up(s, off);
      if (t >= off) s += u;
    }
    cursor2[t] = s - h;
  }
}

// finalize rp, init cursor, and scatter nodes into degree-bucketed order[].
// Hierarchical rank: LDS histogram -> one global atomic per (block,bin)
// reserves a contiguous range -> order[base+rank]=i. No hot global atomics.
__global__ void k_scan_c(int* __restrict__ rp, const int* __restrict__ boff,
                         int* __restrict__ cursor,   // aliases cnt (holds degree)
                         int* __restrict__ cursor2, int* __restrict__ order) {
  __shared__ int lh[64];
  __shared__ int lbase[64];
  int t = threadIdx.x, b = blockIdx.x;
  int i = b * 1024 + t;
  if (t < 64) lh[t] = 0;
  __syncthreads();
  int bin = 0, lr = 0;
  if (i < NN) {
    int d = cursor[i];                 // read degree BEFORE overwrite
    bin = d < 63 ? d : 63;
    lr = atomicAdd(&lh[bin], 1);       // local rank within (block, bin)
    int r = rp[i] + boff[b];
    rp[i] = r;
    cursor[i] = r;
  }
  __syncthreads();
  if (t < 64) {
    int h = lh[t];
    lbase[t] = h ? atomicAdd(&cursor2[t], h) : 0;   // reserve range
  }
  __syncthreads();
  if (i < NN) order[lbase[bin] + lr] = i;
  if (i == 0) rp[NN] = NEP;
}

__global__ void k_scatter(const int* __restrict__ src, const int* __restrict__ dst,
                          int* __restrict__ cursor, int2* __restrict__ pse) {
  int i = blockIdx.x * 256 + threadIdx.x;
  if (i >= NEP) return;
  int s, d;
  if (i < NE) { s = src[i]; d = dst[i]; }
  else        { s = i - NE; d = s; }     // self loop, edge id = NE + n
  int p = atomicAdd(&cursor[d], 1);
  pse[p] = make_int2(s, i);
}

// loop attr = mean of incoming ORIGINAL edge_attr per node (0 if none)
__global__ void k_loopattr(const int* __restrict__ rp, const int2* __restrict__ pse,
                           const float* __restrict__ ea, float* __restrict__ la) {
  int n = blockIdx.x * 256 + threadIdx.x;
  if (n >= NN) return;
  int p0 = rp[n], p1 = rp[n + 1];
  float s0 = 0, s1 = 0, s2 = 0, s3 = 0, s4 = 0, s5 = 0; int c = 0;
  for (int p = p0; p < p1; ++p) {
    int id = pse[p].y;
    if (id < NE) {
      const float* r = ea + (size_t)id * 6;
      s0 += r[0]; s1 += r[1]; s2 += r[2]; s3 += r[3]; s4 += r[4]; s5 += r[5];
      ++c;
    }
  }
  float inv = c ? 1.0f / (float)c : 0.0f;
  float* o = la + (size_t)n * 6;
  o[0] = s0 * inv; o[1] = s1 * inv; o[2] = s2 * inv;
  o[3] = s3 * inv; o[4] = s4 * inv; o[5] = s5 * inv;
}

// ====================== node transforms (xl, xr) ======================
template <int DIN>
__global__ void __launch_bounds__(256) k_xform(
    const float* __restrict__ x,
    const float* __restrict__ wl, const float* __restrict__ bl,
    const float* __restrict__ wr, const float* __restrict__ br,
    float* __restrict__ xl, float* __restrict__ xr) {
  int tid = threadIdx.x;
  int lane = tid & 63, wid = tid >> 6;
  int h = lane;
  float wlr[DIN], wrr[DIN];
#pragma unroll
  for (int k = 0; k < DIN; ++k) { wlr[k] = wl[k * 64 + h]; wrr[k] = wr[k * 64 + h]; }
  float blv = bl[h], brv = br[h];
  int stride = gridDim.x * 4;
  for (int n = blockIdx.x * 4 + wid; n < NN; n += stride) {
    float xv = (lane < DIN) ? x[(size_t)n * DIN + lane] : 0.0f;
    float aL = blv, aR = brv;
#pragma unroll
    for (int k = 0; k < DIN; ++k) {
      float xk = __shfl(xv, k);
      aL = fmaf(xk, wlr[k], aL);
      aR = fmaf(xk, wrr[k], aR);
    }
    xl[(size_t)n * 64 + h] = aL;
    xr[(size_t)n * 64 + h] = aR;
  }
}

// ============== fused edge-logit + online softmax + aggregate ==============
// 16 lanes per node, 4 channels per lane, 4 node-groups per wave.
// Nodes assigned via degree-bucketed order[] so the 4 groups have similar
// trip counts. Branchless online softmax in log2 domain.
__global__ void __launch_bounds__(256) k_fused(
    const float* __restrict__ xl, const float* __restrict__ xr,
    const float* __restrict__ ea, const float* __restrict__ la,
    const int* __restrict__ rp, const int2* __restrict__ pse,
    const int* __restrict__ order,
    const float* __restrict__ we, const float* __restrict__ att,
    const float* __restrict__ bo, float* __restrict__ hout) {
  int tid = threadIdx.x;
  int lane = tid & 63;
  int q = lane & 15;
  int c0 = q * 4;
  float w0[4], w1[4], w2[4], w3[4], w4[4], w5[4], atv[4], bov[4];
#pragma unroll
  for (int c = 0; c < 4; ++c) {
    w0[c] = we[0 * 64 + c0 + c]; w1[c] = we[1 * 64 + c0 + c];
    w2[c] = we[2 * 64 + c0 + c]; w3[c] = we[3 * 64 + c0 + c];
    w4[c] = we[4 * 64 + c0 + c]; w5[c] = we[5 * 64 + c0 + c];
    atv[c] = att[c0 + c] * 1.44269504f;   // fold log2(e) into att
    bov[c] = bo[c0 + c];
  }
  int gw = (blockIdx.x * 256 + tid) >> 6;       // global wave id
  int slot = gw * 4 + (lane >> 4);              // node slot for this group
  int n = (slot < NN) ? order[slot] : -1;
  int p0 = 0, p1 = 0;
  float xrv[4] = {0, 0, 0, 0};
  if (n >= 0) {
    p0 = rp[n]; p1 = rp[n + 1];
    const float4 t = *(const float4*)(xr + (size_t)n * 64 + c0);
    xrv[0] = t.x; xrv[1] = t.y; xrv[2] = t.z; xrv[3] = t.w;
  }
  float m = -INFINITY, den = 0.0f;
  float acc[4] = {0, 0, 0, 0};
  for (int p = p0; p < p1; ++p) {
    int2 se = pse[p];
    int s = se.x, id = se.y;
    const float* ar = (id < NE) ? (ea + (size_t)id * 6)
                                : (la + (size_t)(id - NE) * 6);
    float2 a01 = *(const float2*)ar;
    float2 a23 = *(const float2*)(ar + 2);
    float2 a45 = *(const float2*)(ar + 4);
    float4 xt = *(const float4*)(xl + (size_t)s * 64 + c0);
    float xlv[4] = {xt.x, xt.y, xt.z, xt.w};
    float part = 0.0f;
#pragma unroll
    for (int c = 0; c < 4; ++c) {
      float t = xlv[c] + xrv[c];
      t = fmaf(a01.x, w0[c], t); t = fmaf(a01.y, w1[c], t);
      t = fmaf(a23.x, w2[c], t); t = fmaf(a23.y, w3[c], t);
      t = fmaf(a45.x, w4[c], t); t = fmaf(a45.y, w5[c], t);
      float lr = fmaxf(t, 0.2f * t);          // leaky relu, slope 0.2
      part = fmaf(lr, atv[c], part);
    }
    // 16-lane butterfly -> group-uniform logit (already *log2e)
    part += __shfl_xor(part, 1);
    part += __shfl_xor(part, 2);
    part += __shfl_xor(part, 4);
    part += __shfl_xor(part, 8);
    // branchless online softmax (log2 domain)
    float nm = fmaxf(m, part);
    float sc = exp2f(m - nm);                 // first iter: exp2(-inf)=0
    float ex = exp2f(part - nm);
    m = nm;
    den = fmaf(den, sc, ex);
#pragma unroll
    for (int c = 0; c < 4; ++c) acc[c] = fmaf(acc[c], sc, ex * xlv[c]);
  }
  if (n >= 0) {
    float inv = 1.0f / (den + 1e-16f);
    float4 o;
    o.x = fmaf(acc[0], inv, bov[0]);
    o.y = fmaf(acc[1], inv, bov[1]);
    o.z = fmaf(acc[2], inv, bov[2]);
    o.w = fmaf(acc[3], inv, bov[3]);
    o.x = o.x > 0.0f ? o.x : 0.0f;
    o.y = o.y > 0.0f ? o.y : 0.0f;
    o.z = o.z > 0.0f ? o.z : 0.0f;
    o.w = o.w > 0.0f ? o.w : 0.0f;
    *(float4*)(hout + (size_t)n * 64 + c0) = o;
  }
}

// ====================== MLP head: 64 -> 32 (relu) -> 4 ======================
__global__ void __launch_bounds__(256) k_mlp(
    const float* __restrict__ hin,
    const float* __restrict__ wlin, const float* __restrict__ blin,
    const float* __restrict__ wout, const float* __restrict__ bout,
    float* __restrict__ out) {
  int tid = threadIdx.x;
  int lane = tid & 63, wid = tid >> 6;
  int j = lane & 31, half = lane >> 5;
  float wr_[64];
#pragma unroll
  for (int k = 0; k < 64; ++k) wr_[k] = wlin[k * 32 + j];
  float blv = blin[j];
  float wo0 = wout[j * 4 + 0], wo1 = wout[j * 4 + 1],
        wo2 = wout[j * 4 + 2], wo3 = wout[j * 4 + 3];
  float bo0 = bout[0], bo1 = bout[1], bo2 = bout[2], bo3 = bout[3];
  const int NP = NN / 2;
  int stride = gridDim.x * 4;
  for (int np = blockIdx.x * 4 + wid; np < NP; np += stride) {
    int n0 = np * 2, n1 = np * 2 + 1;
    float v0 = hin[(size_t)n0 * 64 + lane];
    float v1 = hin[(size_t)n1 * 64 + lane];
    float acc = blv;
#pragma unroll
    for (int k = 0; k < 64; ++k) {
      float a = __shfl(v0, k), b = __shfl(v1, k);
      float xk = half ? b : a;
      acc = fmaf(xk, wr_[k], acc);
    }
    float t = acc > 0.0f ? acc : 0.0f;
    float p0 = t * wo0, p1 = t * wo1, p2 = t * wo2, p3 = t * wo3;
#pragma unroll
    for (int off = 16; off; off >>= 1) {
      p0 += __shfl_xor(p0, off); p1 += __shfl_xor(p1, off);
      p2 += __shfl_xor(p2, off); p3 += __shfl_xor(p3, off);
    }
    if (j == 0) {
      int n = half ? n1 : n0;
      float4 r = make_float4(p0 + bo0, p1 + bo1, p2 + bo2, p3 + bo3);
      *(float4*)(out + (size_t)n * 4) = r;
    }
  }
}

// ============================ launch ============================

extern "C" void kernel_launch(void* const* d_in, const int* in_sizes, int n_in,
                              void* d_out, int out_size, void* d_ws, size_t ws_size,
                              hipStream_t stream) {
  const float* x  = (const float*)d_in[0];
  const int*   ei = (const int*)d_in[1];
  const float* ea = (const float*)d_in[2];
  const int* src = ei;
  const int* dst = ei + NE;

  const float *wl[3], *bl[3], *wrm[3], *br[3], *wem[3], *attv[3], *bov[3];
  for (int l = 0; l < 3; ++l) {
    int b = 3 + l * 7;
    wl[l]  = (const float*)d_in[b + 0];
    bl[l]  = (const float*)d_in[b + 1];
    wrm[l] = (const float*)d_in[b + 2];
    br[l]  = (const float*)d_in[b + 3];
    wem[l] = (const float*)d_in[b + 4];
    attv[l]= (const float*)d_in[b + 5];
    bov[l] = (const float*)d_in[b + 6];
  }
  const float* wlin = (const float*)d_in[24];
  const float* blin = (const float*)d_in[25];
  const float* wout = (const float*)d_in[26];
  const float* bout = (const float*)d_in[27];
  float* outp = (float*)d_out;

  // workspace carve (256B aligned)
  char* w = (char*)d_ws;
  size_t off = 0;
  auto carve = [&](size_t bytes) -> void* {
    void* p = w + off;
    off += (bytes + 255) & ~(size_t)255;
    return p;
  };
  int*   cnt  = (int*)carve((size_t)NN * 4);          // then reused as cursor
  int*   rp   = (int*)carve((size_t)(NN + 1) * 4);
  int*   bsum = (int*)carve(1024 * 4);
  int*   boff = (int*)carve(1024 * 4);
  int*   hist = (int*)carve(64 * 4);
  int*   cur2 = (int*)carve(64 * 4);
  int*   order= (int*)carve((size_t)NN * 4);
  int2*  pse  = (int2*)carve((size_t)NEP * 8);
  float* la   = (float*)carve((size_t)NN * 6 * 4);
  float* xlb  = (float*)carve((size_t)NN * 64 * 4);
  float* xrb  = (float*)carve((size_t)NN * 64 * 4);
  float* hA   = (float*)carve((size_t)NN * 64 * 4);
  float* hB   = (float*)carve((size_t)NN * 64 * 4);
  (void)ws_size; (void)n_in; (void)in_sizes; (void)out_size;

  const int SCAN_NB = (NN + 1023) / 1024;  // 98
  const int FUSE_NB = (NN + 15) / 16;      // 6250 blocks: 4 waves x 4 groups each

  hipLaunchKernelGGL(k_init_cnt, dim3((NN + 255) / 256), dim3(256), 0, stream,
                     cnt, hist, cur2);
  hipLaunchKernelGGL(k_count, dim3((NE + 255) / 256), dim3(256), 0, stream, dst, cnt);
  hipLaunchKernelGGL(k_scan_a, dim3(SCAN_NB), dim3(1024), 0, stream, cnt, rp, bsum, hist);
  hipLaunchKernelGGL(k_scan_b, dim3(1), dim3(1024), 0, stream, bsum, boff, SCAN_NB,
                     hist, cur2);
  hipLaunchKernelGGL(k_scan_c, dim3(SCAN_NB), dim3(1024), 0, stream, rp, boff, cnt,
                     cur2, order);
  hipLaunchKernelGGL(k_scatter, dim3((NEP + 255) / 256), dim3(256), 0, stream,
                     src, dst, cnt, pse);
  hipLaunchKernelGGL(k_loopattr, dim3((NN + 255) / 256), dim3(256), 0, stream,
                     rp, pse, ea, la);

  // layer 1 (din=6): x -> hA
  hipLaunchKernelGGL((k_xform<6>), dim3(1024), dim3(256), 0, stream,
                     x, wl[0], bl[0], wrm[0], br[0], xlb, xrb);
  hipLaunchKernelGGL(k_fused, dim3(FUSE_NB), dim3(256), 0, stream,
                     xlb, xrb, ea, la, rp, pse, order, wem[0], attv[0], bov[0], hA);
  // layer 2: hA -> hB
  hipLaunchKernelGGL((k_xform<64>), dim3(2048), dim3(256), 0, stream,
                     hA, wl[1], bl[1], wrm[1], br[1], xlb, xrb);
  hipLaunchKernelGGL(k_fused, dim3(FUSE_NB), dim3(256), 0, stream,
                     xlb, xrb, ea, la, rp, pse, order, wem[1], attv[1], bov[1], hB);
  // layer 3: hB -> hA
  hipLaunchKernelGGL((k_xform<64>), dim3(2048), dim3(256), 0, stream,
                     hB, wl[2], bl[2], wrm[2], br[2], xlb, xrb);
  hipLaunchKernelGGL(k_fused, dim3(FUSE_NB), dim3(256), 0, stream,
                     xlb, xrb, ea, la, rp, pse, order, wem[2], attv[2], bov[2], hA);
  // MLP head
  hipLaunchKernelGGL(k_mlp, dim3(2048), dim3(256), 0, stream,
                     hA, wlin, blin, wout, bout, outp);
}

// Round 4
// 706.201 us; speedup vs baseline: 1.8153x; 1.2392x over previous
//
#include <hip/hip_runtime.h>
#include <hip/hip_bf16.h>
#include <math.h>

#define NN 100000
#define NE 1600000
#define NEP 1700000        // NE + NN (self loops)
#define HD 64
#define NEGS 0.2f

// ============================ CSR build ============================

__global__ void k_init_cnt(int* __restrict__ cnt, int* __restrict__ hist,
                           int* __restrict__ cursor2) {
  int i = blockIdx.x * 256 + threadIdx.x;
  if (i < NN) cnt[i] = 1;             // self loop pre-counted
  if (blockIdx.x == 0) {
    if (threadIdx.x < 64) hist[threadIdx.x] = 0;
    else if (threadIdx.x < 128) cursor2[threadIdx.x - 64] = 0;
  }
}

__global__ void k_count(const int* __restrict__ dst, int* __restrict__ cnt) {
  int i = blockIdx.x * 256 + threadIdx.x;
  if (i < NE) atomicAdd(&cnt[dst[i]], 1);
}

// scan of cnt -> rp (exclusive) ; also 64-bin degree histogram (LDS-batched)
__global__ void k_scan_a(const int* __restrict__ cnt, int* __restrict__ rp,
                         int* __restrict__ bsum, int* __restrict__ hist) {
  __shared__ int tmp[1024];
  __shared__ int lh[64];
  int t = threadIdx.x, b = blockIdx.x;
  int i = b * 1024 + t;
  int v = (i < NN) ? cnt[i] : 0;
  tmp[t] = v;
  if (t < 64) lh[t] = 0;
  __syncthreads();
  if (i < NN) atomicAdd(&lh[v < 63 ? v : 63], 1);
  for (int off = 1; off < 1024; off <<= 1) {
    int a = (t >= off) ? tmp[t - off] : 0;
    __syncthreads(); tmp[t] += a; __syncthreads();
  }
  if (i < NN) rp[i] = tmp[t] - v;     // exclusive
  if (t == 1023) bsum[b] = tmp[t];    // block total
  if (t < 64) { int h = lh[t]; if (h) atomicAdd(&hist[t], h); }
}

__global__ void k_scan_b(const int* __restrict__ bsum, int* __restrict__ boff, int nb,
                         const int* __restrict__ hist, int* __restrict__ cursor2) {
  __shared__ int tmp[1024];
  int t = threadIdx.x;
  int v = (t < nb) ? bsum[t] : 0;
  tmp[t] = v; __syncthreads();
  for (int off = 1; off < 1024; off <<= 1) {
    int a = (t >= off) ? tmp[t - off] : 0;
    __syncthreads(); tmp[t] += a; __syncthreads();
  }
  if (t < nb) boff[t] = tmp[t] - v;
  // exclusive scan of 64-bin degree histogram (wave 0 only) -> bin bases
  if (t < 64) {
    int h = hist[t];
    int s = h;
#pragma unroll
    for (int off = 1; off < 64; off <<= 1) {
      int u = __shfl_up(s, off);
      if (t >= off) s += u;
    }
    cursor2[t] = s - h;
  }
}

// finalize rp, init cursor, and scatter nodes into degree-bucketed order[].
// Hierarchical rank: LDS histogram -> one global atomic per (block,bin).
__global__ void k_scan_c(int* __restrict__ rp, const int* __restrict__ boff,
                         int* __restrict__ cursor,   // aliases cnt (holds degree)
                         int* __restrict__ cursor2, int* __restrict__ order) {
  __shared__ int lh[64];
  __shared__ int lbase[64];
  int t = threadIdx.x, b = blockIdx.x;
  int i = b * 1024 + t;
  if (t < 64) lh[t] = 0;
  __syncthreads();
  int bin = 0, lr = 0;
  if (i < NN) {
    int d = cursor[i];                 // read degree BEFORE overwrite
    bin = d < 63 ? d : 63;
    lr = atomicAdd(&lh[bin], 1);       // local rank within (block, bin)
    int r = rp[i] + boff[b];
    rp[i] = r;
    cursor[i] = r;
  }
  __syncthreads();
  if (t < 64) {
    int h = lh[t];
    lbase[t] = h ? atomicAdd(&cursor2[t], h) : 0;   // reserve range
  }
  __syncthreads();
  if (i < NN) order[lbase[bin] + lr] = i;
  if (i == 0) rp[NN] = NEP;
}

// ============ scatter edges into CSR-ordered 32B records ============
// rec[p] = {src_as_float, a0..a5, pad}. 4 edges/thread -> 4 outstanding
// returned-atomic chains (hides device-scope atomic latency). Self loops
// (i>=NE) only record their position; k_lamean fills their record.
__global__ void __launch_bounds__(256) k_scatter2(
    const int* __restrict__ src, const int* __restrict__ dst,
    const float* __restrict__ ea, int* __restrict__ cursor,
    float* __restrict__ rec, int* __restrict__ selfpos) {
  int base = (blockIdx.x * 256 + threadIdx.x) * 4;
  if (base >= NEP) return;
  if (base < NE) {                       // NE % 4 == 0 -> whole thread is edges
    int4 sv = *(const int4*)(src + base);
    int4 dv = *(const int4*)(dst + base);
    const float4* e4 = (const float4*)(ea + (size_t)base * 6);
    float4 e0 = e4[0], e1 = e4[1], e2 = e4[2], e3 = e4[3], e4v = e4[4], e5 = e4[5];
    int d[4] = {dv.x, dv.y, dv.z, dv.w};
    int p[4];
#pragma unroll
    for (int k = 0; k < 4; ++k) p[k] = atomicAdd(&cursor[d[k]], 1);
    float a[24] = {e0.x, e0.y, e0.z, e0.w, e1.x, e1.y, e1.z, e1.w,
                   e2.x, e2.y, e2.z, e2.w, e3.x, e3.y, e3.z, e3.w,
                   e4v.x, e4v.y, e4v.z, e4v.w, e5.x, e5.y, e5.z, e5.w};
    int s[4] = {sv.x, sv.y, sv.z, sv.w};
#pragma unroll
    for (int k = 0; k < 4; ++k) {
      float* r = rec + (size_t)p[k] * 8;
      *(float4*)r       = make_float4(__int_as_float(s[k]),
                                      a[6 * k + 0], a[6 * k + 1], a[6 * k + 2]);
      *(float4*)(r + 4) = make_float4(a[6 * k + 3], a[6 * k + 4], a[6 * k + 5], 0.f);
    }
  } else {                               // self-loop range
#pragma unroll
    for (int k = 0; k < 4; ++k) {
      int n = base + k - NE;
      int p = atomicAdd(&cursor[n], 1);
      selfpos[n] = p;
    }
  }
}

// self-loop attr = mean of incoming ORIGINAL edge attrs, read from the
// sorted records (dense cross-thread sweep); writes the self record.
__global__ void k_lamean(const int* __restrict__ rp, const int* __restrict__ selfpos,
                         float* __restrict__ rec) {
  int n = blockIdx.x * 256 + threadIdx.x;
  if (n >= NN) return;
  int p0 = rp[n], p1 = rp[n + 1], sp = selfpos[n];
  float s0 = 0, s1 = 0, s2 = 0, s3 = 0, s4 = 0, s5 = 0;
  for (int p = p0; p < p1; ++p) {
    if (p == sp) continue;
    const float* r = rec + (size_t)p * 8;
    float4 r0 = *(const float4*)r;
    float4 r1 = *(const float4*)(r + 4);
    s0 += r0.y; s1 += r0.z; s2 += r0.w;
    s3 += r1.x; s4 += r1.y; s5 += r1.z;
  }
  int c = p1 - p0 - 1;
  float inv = c > 0 ? 1.0f / (float)c : 0.0f;
  float* r = rec + (size_t)sp * 8;
  *(float4*)r       = make_float4(__int_as_float(n), s0 * inv, s1 * inv, s2 * inv);
  *(float4*)(r + 4) = make_float4(s3 * inv, s4 * inv, s5 * inv, 0.f);
}

// ====================== node transforms (xl, xr) ======================
template <int DIN>
__global__ void __launch_bounds__(256) k_xform(
    const float* __restrict__ x,
    const float* __restrict__ wl, const float* __restrict__ bl,
    const float* __restrict__ wr, const float* __restrict__ br,
    float* __restrict__ xl, float* __restrict__ xr) {
  int tid = threadIdx.x;
  int lane = tid & 63, wid = tid >> 6;
  int h = lane;
  float wlr[DIN], wrr[DIN];
#pragma unroll
  for (int k = 0; k < DIN; ++k) { wlr[k] = wl[k * 64 + h]; wrr[k] = wr[k * 64 + h]; }
  float blv = bl[h], brv = br[h];
  int stride = gridDim.x * 4;
  for (int n = blockIdx.x * 4 + wid; n < NN; n += stride) {
    float xv = (lane < DIN) ? x[(size_t)n * DIN + lane] : 0.0f;
    float aL = blv, aR = brv;
#pragma unroll
    for (int k = 0; k < DIN; ++k) {
      float xk = __shfl(xv, k);
      aL = fmaf(xk, wlr[k], aL);
      aR = fmaf(xk, wrr[k], aR);
    }
    xl[(size_t)n * 64 + h] = aL;
    xr[(size_t)n * 64 + h] = aR;
  }
}

// ============== fused edge-logit + online softmax + aggregate ==============
// 16 lanes per node, 4 channels per lane, 4 node-groups per wave.
// Edge data comes as a sequential stream of 32B records (src + attrs).
__global__ void __launch_bounds__(256) k_fused(
    const float* __restrict__ xl, const float* __restrict__ xr,
    const float* __restrict__ rec,
    const int* __restrict__ rp, const int* __restrict__ order,
    const float* __restrict__ we, const float* __restrict__ att,
    const float* __restrict__ bo, float* __restrict__ hout) {
  int tid = threadIdx.x;
  int lane = tid & 63;
  int q = lane & 15;
  int c0 = q * 4;
  float w0[4], w1[4], w2[4], w3[4], w4[4], w5[4], atv[4], bov[4];
#pragma unroll
  for (int c = 0; c < 4; ++c) {
    w0[c] = we[0 * 64 + c0 + c]; w1[c] = we[1 * 64 + c0 + c];
    w2[c] = we[2 * 64 + c0 + c]; w3[c] = we[3 * 64 + c0 + c];
    w4[c] = we[4 * 64 + c0 + c]; w5[c] = we[5 * 64 + c0 + c];
    atv[c] = att[c0 + c] * 1.44269504f;   // fold log2(e) into att
    bov[c] = bo[c0 + c];
  }
  int gw = (blockIdx.x * 256 + tid) >> 6;       // global wave id
  int slot = gw * 4 + (lane >> 4);              // node slot for this group
  int n = (slot < NN) ? order[slot] : -1;
  int p0 = 0, p1 = 0;
  float xrv[4] = {0, 0, 0, 0};
  if (n >= 0) {
    p0 = rp[n]; p1 = rp[n + 1];
    const float4 t = *(const float4*)(xr + (size_t)n * 64 + c0);
    xrv[0] = t.x; xrv[1] = t.y; xrv[2] = t.z; xrv[3] = t.w;
  }
  float m = -INFINITY, den = 0.0f;
  float acc[4] = {0, 0, 0, 0};
  for (int p = p0; p < p1; ++p) {
    const float* rr = rec + (size_t)p * 8;
    float4 r0 = *(const float4*)rr;           // {src, a0, a1, a2}
    float4 r1 = *(const float4*)(rr + 4);     // {a3, a4, a5, pad}
    int s = __float_as_int(r0.x);
    float4 xt = *(const float4*)(xl + (size_t)s * 64 + c0);
    float xlv[4] = {xt.x, xt.y, xt.z, xt.w};
    float part = 0.0f;
#pragma unroll
    for (int c = 0; c < 4; ++c) {
      float t = xlv[c] + xrv[c];
      t = fmaf(r0.y, w0[c], t); t = fmaf(r0.z, w1[c], t);
      t = fmaf(r0.w, w2[c], t); t = fmaf(r1.x, w3[c], t);
      t = fmaf(r1.y, w4[c], t); t = fmaf(r1.z, w5[c], t);
      float lr = fmaxf(t, 0.2f * t);          // leaky relu, slope 0.2
      part = fmaf(lr, atv[c], part);
    }
    // 16-lane butterfly -> group-uniform logit (already *log2e)
    part += __shfl_xor(part, 1);
    part += __shfl_xor(part, 2);
    part += __shfl_xor(part, 4);
    part += __shfl_xor(part, 8);
    // branchless online softmax (log2 domain)
    float nm = fmaxf(m, part);
    float sc = exp2f(m - nm);                 // first iter: exp2(-inf)=0
    float ex = exp2f(part - nm);
    m = nm;
    den = fmaf(den, sc, ex);
#pragma unroll
    for (int c = 0; c < 4; ++c) acc[c] = fmaf(acc[c], sc, ex * xlv[c]);
  }
  if (n >= 0) {
    float inv = 1.0f / (den + 1e-16f);
    float4 o;
    o.x = fmaf(acc[0], inv, bov[0]);
    o.y = fmaf(acc[1], inv, bov[1]);
    o.z = fmaf(acc[2], inv, bov[2]);
    o.w = fmaf(acc[3], inv, bov[3]);
    o.x = o.x > 0.0f ? o.x : 0.0f;
    o.y = o.y > 0.0f ? o.y : 0.0f;
    o.z = o.z > 0.0f ? o.z : 0.0f;
    o.w = o.w > 0.0f ? o.w : 0.0f;
    *(float4*)(hout + (size_t)n * 64 + c0) = o;
  }
}

// ====================== MLP head: 64 -> 32 (relu) -> 4 ======================
__global__ void __launch_bounds__(256) k_mlp(
    const float* __restrict__ hin,
    const float* __restrict__ wlin, const float* __restrict__ blin,
    const float* __restrict__ wout, const float* __restrict__ bout,
    float* __restrict__ out) {
  int tid = threadIdx.x;
  int lane = tid & 63, wid = tid >> 6;
  int j = lane & 31, half = lane >> 5;
  float wr_[64];
#pragma unroll
  for (int k = 0; k < 64; ++k) wr_[k] = wlin[k * 32 + j];
  float blv = blin[j];
  float wo0 = wout[j * 4 + 0], wo1 = wout[j * 4 + 1],
        wo2 = wout[j * 4 + 2], wo3 = wout[j * 4 + 3];
  float bo0 = bout[0], bo1 = bout[1], bo2 = bout[2], bo3 = bout[3];
  const int NP = NN / 2;
  int stride = gridDim.x * 4;
  for (int np = blockIdx.x * 4 + wid; np < NP; np += stride) {
    int n0 = np * 2, n1 = np * 2 + 1;
    float v0 = hin[(size_t)n0 * 64 + lane];
    float v1 = hin[(size_t)n1 * 64 + lane];
    float acc = blv;
#pragma unroll
    for (int k = 0; k < 64; ++k) {
      float a = __shfl(v0, k), b = __shfl(v1, k);
      float xk = half ? b : a;
      acc = fmaf(xk, wr_[k], acc);
    }
    float t = acc > 0.0f ? acc : 0.0f;
    float p0 = t * wo0, p1 = t * wo1, p2 = t * wo2, p3 = t * wo3;
#pragma unroll
    for (int off = 16; off; off >>= 1) {
      p0 += __shfl_xor(p0, off); p1 += __shfl_xor(p1, off);
      p2 += __shfl_xor(p2, off); p3 += __shfl_xor(p3, off);
    }
    if (j == 0) {
      int n = half ? n1 : n0;
      float4 r = make_float4(p0 + bo0, p1 + bo1, p2 + bo2, p3 + bo3);
      *(float4*)(out + (size_t)n * 4) = r;
    }
  }
}

// ============================ launch ============================

extern "C" void kernel_launch(void* const* d_in, const int* in_sizes, int n_in,
                              void* d_out, int out_size, void* d_ws, size_t ws_size,
                              hipStream_t stream) {
  const float* x  = (const float*)d_in[0];
  const int*   ei = (const int*)d_in[1];
  const float* ea = (const float*)d_in[2];
  const int* src = ei;
  const int* dst = ei + NE;

  const float *wl[3], *bl[3], *wrm[3], *br[3], *wem[3], *attv[3], *bov[3];
  for (int l = 0; l < 3; ++l) {
    int b = 3 + l * 7;
    wl[l]  = (const float*)d_in[b + 0];
    bl[l]  = (const float*)d_in[b + 1];
    wrm[l] = (const float*)d_in[b + 2];
    br[l]  = (const float*)d_in[b + 3];
    wem[l] = (const float*)d_in[b + 4];
    attv[l]= (const float*)d_in[b + 5];
    bov[l] = (const float*)d_in[b + 6];
  }
  const float* wlin = (const float*)d_in[24];
  const float* blin = (const float*)d_in[25];
  const float* wout = (const float*)d_in[26];
  const float* bout = (const float*)d_in[27];
  float* outp = (float*)d_out;

  // workspace carve (256B aligned)
  char* w = (char*)d_ws;
  size_t off = 0;
  auto carve = [&](size_t bytes) -> void* {
    void* p = w + off;
    off += (bytes + 255) & ~(size_t)255;
    return p;
  };
  int*   cnt  = (int*)carve((size_t)NN * 4);          // then reused as cursor
  int*   rp   = (int*)carve((size_t)(NN + 1) * 4);
  int*   bsum = (int*)carve(1024 * 4);
  int*   boff = (int*)carve(1024 * 4);
  int*   hist = (int*)carve(64 * 4);
  int*   cur2 = (int*)carve(64 * 4);
  int*   order= (int*)carve((size_t)NN * 4);
  int*   selfp= (int*)carve((size_t)NN * 4);
  float* rec  = (float*)carve((size_t)NEP * 32);      // 32B records
  float* xlb  = (float*)carve((size_t)NN * 64 * 4);
  float* xrb  = (float*)carve((size_t)NN * 64 * 4);
  float* hA   = (float*)carve((size_t)NN * 64 * 4);
  float* hB   = (float*)carve((size_t)NN * 64 * 4);
  (void)ws_size; (void)n_in; (void)in_sizes; (void)out_size;

  const int SCAN_NB = (NN + 1023) / 1024;  // 98
  const int FUSE_NB = (NN + 15) / 16;      // 6250 blocks: 4 waves x 4 groups each
  const int SCAT_NB = (NEP / 4 + 255) / 256;

  hipLaunchKernelGGL(k_init_cnt, dim3((NN + 255) / 256), dim3(256), 0, stream,
                     cnt, hist, cur2);
  hipLaunchKernelGGL(k_count, dim3((NE + 255) / 256), dim3(256), 0, stream, dst, cnt);
  hipLaunchKernelGGL(k_scan_a, dim3(SCAN_NB), dim3(1024), 0, stream, cnt, rp, bsum, hist);
  hipLaunchKernelGGL(k_scan_b, dim3(1), dim3(1024), 0, stream, bsum, boff, SCAN_NB,
                     hist, cur2);
  hipLaunchKernelGGL(k_scan_c, dim3(SCAN_NB), dim3(1024), 0, stream, rp, boff, cnt,
                     cur2, order);
  hipLaunchKernelGGL(k_scatter2, dim3(SCAT_NB), dim3(256), 0, stream,
                     src, dst, ea, cnt, rec, selfp);
  hipLaunchKernelGGL(k_lamean, dim3((NN + 255) / 256), dim3(256), 0, stream,
                     rp, selfp, rec);

  // layer 1 (din=6): x -> hA
  hipLaunchKernelGGL((k_xform<6>), dim3(1024), dim3(256), 0, stream,
                     x, wl[0], bl[0], wrm[0], br[0], xlb, xrb);
  hipLaunchKernelGGL(k_fused, dim3(FUSE_NB), dim3(256), 0, stream,
                     xlb, xrb, rec, rp, order, wem[0], attv[0], bov[0], hA);
  // layer 2: hA -> hB
  hipLaunchKernelGGL((k_xform<64>), dim3(2048), dim3(256), 0, stream,
                     hA, wl[1], bl[1], wrm[1], br[1], xlb, xrb);
  hipLaunchKernelGGL(k_fused, dim3(FUSE_NB), dim3(256), 0, stream,
                     xlb, xrb, rec, rp, order, wem[1], attv[1], bov[1], hB);
  // layer 3: hB -> hA
  hipLaunchKernelGGL((k_xform<64>), dim3(2048), dim3(256), 0, stream,
                     hB, wl[2], bl[2], wrm[2], br[2], xlb, xrb);
  hipLaunchKernelGGL(k_fused, dim3(FUSE_NB), dim3(256), 0, stream,
                     xlb, xrb, rec, rp, order, wem[2], attv[2], bov[2], hA);
  // MLP head
  hipLaunchKernelGGL(k_mlp, dim3(2048), dim3(256), 0, stream,
                     hA, wlin, blin, wout, bout, outp);
}

// Round 6
// 675.903 us; speedup vs baseline: 1.8966x; 1.0448x over previous
//
#include <hip/hip_runtime.h>
#include <hip/hip_bf16.h>
#include <math.h>

#define NN 100000
#define NE 1600000
#define NEP 1700000        // NE + NN (self loops)
#define HD 64
#define NEGS 0.2f

typedef float f4 __attribute__((ext_vector_type(4)));   // clang vector: OK for
                                                        // __builtin_nontemporal_load

// ============================ CSR build ============================

__global__ void k_init_cnt(int* __restrict__ cnt, int* __restrict__ hist,
                           int* __restrict__ cursor2) {
  int i = blockIdx.x * 256 + threadIdx.x;
  if (i < NN) cnt[i] = 1;             // self loop pre-counted -> ranks start at 1
  if (blockIdx.x == 0) {
    if (threadIdx.x < 64) hist[threadIdx.x] = 0;
    else if (threadIdx.x < 128) cursor2[threadIdx.x - 64] = 0;
  }
}

// count in-degree AND record each edge's rank within its dst segment.
// rank >= 1; slot rp[dst]+0 is reserved for the self loop.
__global__ void k_count_rank(const int* __restrict__ dst, int* __restrict__ cnt,
                             int* __restrict__ rank) {
  int base = (blockIdx.x * 256 + threadIdx.x) * 4;
  if (base >= NE) return;
  int4 dv = *(const int4*)(dst + base);
  int4 rv;
  rv.x = atomicAdd(&cnt[dv.x], 1);
  rv.y = atomicAdd(&cnt[dv.y], 1);
  rv.z = atomicAdd(&cnt[dv.z], 1);
  rv.w = atomicAdd(&cnt[dv.w], 1);
  *(int4*)(rank + base) = rv;
}

// scan of cnt -> rp (exclusive) ; also 64-bin degree histogram (LDS-batched)
__global__ void k_scan_a(const int* __restrict__ cnt, int* __restrict__ rp,
                         int* __restrict__ bsum, int* __restrict__ hist) {
  __shared__ int tmp[1024];
  __shared__ int lh[64];
  int t = threadIdx.x, b = blockIdx.x;
  int i = b * 1024 + t;
  int v = (i < NN) ? cnt[i] : 0;
  tmp[t] = v;
  if (t < 64) lh[t] = 0;
  __syncthreads();
  if (i < NN) atomicAdd(&lh[v < 63 ? v : 63], 1);
  for (int off = 1; off < 1024; off <<= 1) {
    int a = (t >= off) ? tmp[t - off] : 0;
    __syncthreads(); tmp[t] += a; __syncthreads();
  }
  if (i < NN) rp[i] = tmp[t] - v;     // exclusive
  if (t == 1023) bsum[b] = tmp[t];    // block total
  if (t < 64) { int h = lh[t]; if (h) atomicAdd(&hist[t], h); }
}

__global__ void k_scan_b(const int* __restrict__ bsum, int* __restrict__ boff, int nb,
                         const int* __restrict__ hist, int* __restrict__ cursor2) {
  __shared__ int tmp[1024];
  int t = threadIdx.x;
  int v = (t < nb) ? bsum[t] : 0;
  tmp[t] = v; __syncthreads();
  for (int off = 1; off < 1024; off <<= 1) {
    int a = (t >= off) ? tmp[t - off] : 0;
    __syncthreads(); tmp[t] += a; __syncthreads();
  }
  if (t < nb) boff[t] = tmp[t] - v;
  // exclusive scan of 64-bin degree histogram (wave 0 only) -> bin bases
  if (t < 64) {
    int h = hist[t];
    int s = h;
#pragma unroll
    for (int off = 1; off < 64; off <<= 1) {
      int u = __shfl_up(s, off);
      if (t >= off) s += u;
    }
    cursor2[t] = s - h;
  }
}

// finalize rp and scatter nodes into degree-bucketed order[].
// Hierarchical rank: LDS histogram -> one global atomic per (block,bin).
__global__ void k_scan_c(int* __restrict__ rp, const int* __restrict__ boff,
                         const int* __restrict__ deg,   // aliases cnt (degree)
                         int* __restrict__ cursor2, int* __restrict__ order) {
  __shared__ int lh[64];
  __shared__ int lbase[64];
  int t = threadIdx.x, b = blockIdx.x;
  int i = b * 1024 + t;
  if (t < 64) lh[t] = 0;
  __syncthreads();
  int bin = 0, lr = 0;
  if (i < NN) {
    int d = deg[i];
    bin = d < 63 ? d : 63;
    lr = atomicAdd(&lh[bin], 1);       // local rank within (block, bin)
    rp[i] = rp[i] + boff[b];
  }
  __syncthreads();
  if (t < 64) {
    int h = lh[t];
    lbase[t] = h ? atomicAdd(&cursor2[t], h) : 0;   // reserve range
  }
  __syncthreads();
  if (i < NN) order[lbase[bin] + lr] = i;
  if (i == 0) rp[NN] = NEP;
}

// ============ scatter edges into CSR-ordered 32B records ============
// p = rp[dst] + rank  (no atomics; rp is L2-resident).
// rec[p] = {src_as_float, a0..a5, pad}.
__global__ void __launch_bounds__(256) k_scatter3(
    const int* __restrict__ src, const int* __restrict__ dst,
    const int* __restrict__ rank, const float* __restrict__ ea,
    const int* __restrict__ rp, float* __restrict__ rec) {
  int base = (blockIdx.x * 256 + threadIdx.x) * 4;
  if (base >= NE) return;
  int4 sv = *(const int4*)(src + base);
  int4 dv = *(const int4*)(dst + base);
  int4 rv = *(const int4*)(rank + base);
  const float4* e4 = (const float4*)(ea + (size_t)base * 6);
  float4 e0 = e4[0], e1 = e4[1], e2 = e4[2], e3 = e4[3], e4v = e4[4], e5 = e4[5];
  int d[4] = {dv.x, dv.y, dv.z, dv.w};
  int rk[4] = {rv.x, rv.y, rv.z, rv.w};
  int s[4] = {sv.x, sv.y, sv.z, sv.w};
  int p[4];
#pragma unroll
  for (int k = 0; k < 4; ++k) p[k] = rp[d[k]] + rk[k];
  float a[24] = {e0.x, e0.y, e0.z, e0.w, e1.x, e1.y, e1.z, e1.w,
                 e2.x, e2.y, e2.z, e2.w, e3.x, e3.y, e3.z, e3.w,
                 e4v.x, e4v.y, e4v.z, e4v.w, e5.x, e5.y, e5.z, e5.w};
#pragma unroll
  for (int k = 0; k < 4; ++k) {
    float* r = rec + (size_t)p[k] * 8;
    *(float4*)r       = make_float4(__int_as_float(s[k]),
                                    a[6 * k + 0], a[6 * k + 1], a[6 * k + 2]);
    *(float4*)(r + 4) = make_float4(a[6 * k + 3], a[6 * k + 4], a[6 * k + 5], 0.f);
  }
}

// self-loop attr = mean of incoming edge attrs; 16 lanes per node sweep the
// node's record segment (coalesced 512B per group), butterfly-reduce, and
// lane 0 writes the self record at slot rp[n].
__global__ void __launch_bounds__(256) k_lamean2(const int* __restrict__ rp,
                                                 float* __restrict__ rec) {
  int tid = threadIdx.x;
  int q = tid & 15;
  int n = (blockIdx.x * 256 + tid) >> 4;     // 16 groups/block, exact fit
  if (n >= NN) return;
  int p0 = rp[n], p1 = rp[n + 1];
  float s0 = 0, s1 = 0, s2 = 0, s3 = 0, s4 = 0, s5 = 0;
  for (int p = p0 + 1 + q; p < p1; p += 16) {
    const float* r = rec + (size_t)p * 8;
    float4 r0 = *(const float4*)r;
    float4 r1 = *(const float4*)(r + 4);
    s0 += r0.y; s1 += r0.z; s2 += r0.w;
    s3 += r1.x; s4 += r1.y; s5 += r1.z;
  }
#pragma unroll
  for (int off = 1; off < 16; off <<= 1) {
    s0 += __shfl_xor(s0, off); s1 += __shfl_xor(s1, off);
    s2 += __shfl_xor(s2, off); s3 += __shfl_xor(s3, off);
    s4 += __shfl_xor(s4, off); s5 += __shfl_xor(s5, off);
  }
  if (q == 0) {
    int c = p1 - p0 - 1;
    float inv = c > 0 ? 1.0f / (float)c : 0.0f;
    float* r = rec + (size_t)p0 * 8;
    *(float4*)r       = make_float4(__int_as_float(n), s0 * inv, s1 * inv, s2 * inv);
    *(float4*)(r + 4) = make_float4(s3 * inv, s4 * inv, s5 * inv, 0.f);
  }
}

// ====================== node transforms (xl, xr) ======================
template <int DIN>
__global__ void __launch_bounds__(256) k_xform(
    const float* __restrict__ x,
    const float* __restrict__ wl, const float* __restrict__ bl,
    const float* __restrict__ wr, const float* __restrict__ br,
    float* __restrict__ xl, float* __restrict__ xr) {
  int tid = threadIdx.x;
  int lane = tid & 63, wid = tid >> 6;
  int h = lane;
  float wlr[DIN], wrr[DIN];
#pragma unroll
  for (int k = 0; k < DIN; ++k) { wlr[k] = wl[k * 64 + h]; wrr[k] = wr[k * 64 + h]; }
  float blv = bl[h], brv = br[h];
  int stride = gridDim.x * 4;
  for (int n = blockIdx.x * 4 + wid; n < NN; n += stride) {
    float xv = (lane < DIN) ? x[(size_t)n * DIN + lane] : 0.0f;
    float aL = blv, aR = brv;
#pragma unroll
    for (int k = 0; k < DIN; ++k) {
      float xk = __shfl(xv, k);
      aL = fmaf(xk, wlr[k], aL);
      aR = fmaf(xk, wrr[k], aR);
    }
    xl[(size_t)n * 64 + h] = aL;
    xr[(size_t)n * 64 + h] = aR;
  }
}

// ============== fused edge-logit + online softmax + aggregate ==============
// 16 lanes per node, 4 channels per lane, 4 node-groups per wave.
// Unrolled by 2 edges: paired loads (2x outstanding latency chains) and a
// paired online-softmax update (3 exp2 per pair). rec loads nontemporal so
// the 54MB stream doesn't evict the reuse-heavy xl from L2.
__global__ void __launch_bounds__(256) k_fused(
    const float* __restrict__ xl, const float* __restrict__ xr,
    const float* __restrict__ rec,
    const int* __restrict__ rp, const int* __restrict__ order,
    const float* __restrict__ we, const float* __restrict__ att,
    const float* __restrict__ bo, float* __restrict__ hout) {
  int tid = threadIdx.x;
  int lane = tid & 63;
  int q = lane & 15;
  int c0 = q * 4;
  float w0[4], w1[4], w2[4], w3[4], w4[4], w5[4], atv[4], bov[4];
#pragma unroll
  for (int c = 0; c < 4; ++c) {
    w0[c] = we[0 * 64 + c0 + c]; w1[c] = we[1 * 64 + c0 + c];
    w2[c] = we[2 * 64 + c0 + c]; w3[c] = we[3 * 64 + c0 + c];
    w4[c] = we[4 * 64 + c0 + c]; w5[c] = we[5 * 64 + c0 + c];
    atv[c] = att[c0 + c] * 1.44269504f;   // fold log2(e) into att
    bov[c] = bo[c0 + c];
  }
  int gw = (blockIdx.x * 256 + tid) >> 6;       // global wave id
  int slot = gw * 4 + (lane >> 4);              // node slot for this group
  int n = (slot < NN) ? order[slot] : -1;
  int p0 = 0, p1 = 0;
  float xrv[4] = {0, 0, 0, 0};
  if (n >= 0) {
    p0 = rp[n]; p1 = rp[n + 1];
    const float4 t = *(const float4*)(xr + (size_t)n * 64 + c0);
    xrv[0] = t.x; xrv[1] = t.y; xrv[2] = t.z; xrv[3] = t.w;
  }
  float m = -INFINITY, den = 0.0f;
  float acc[4] = {0, 0, 0, 0};
  int p = p0;
  for (; p + 2 <= p1; p += 2) {
    const f4* ra = (const f4*)(rec + (size_t)p * 8);
    f4 qa0 = __builtin_nontemporal_load(ra);
    f4 qa1 = __builtin_nontemporal_load(ra + 1);
    f4 qb0 = __builtin_nontemporal_load(ra + 2);
    f4 qb1 = __builtin_nontemporal_load(ra + 3);
    int sA = __float_as_int(qa0.x), sB = __float_as_int(qb0.x);
    float4 xA = *(const float4*)(xl + (size_t)sA * 64 + c0);
    float4 xB = *(const float4*)(xl + (size_t)sB * 64 + c0);
    float xAv[4] = {xA.x, xA.y, xA.z, xA.w};
    float xBv[4] = {xB.x, xB.y, xB.z, xB.w};
    float pa = 0.0f, pb = 0.0f;
#pragma unroll
    for (int c = 0; c < 4; ++c) {
      float tA = xAv[c] + xrv[c];
      tA = fmaf(qa0.y, w0[c], tA); tA = fmaf(qa0.z, w1[c], tA);
      tA = fmaf(qa0.w, w2[c], tA); tA = fmaf(qa1.x, w3[c], tA);
      tA = fmaf(qa1.y, w4[c], tA); tA = fmaf(qa1.z, w5[c], tA);
      pa = fmaf(fmaxf(tA, 0.2f * tA), atv[c], pa);
      float tB = xBv[c] + xrv[c];
      tB = fmaf(qb0.y, w0[c], tB); tB = fmaf(qb0.z, w1[c], tB);
      tB = fmaf(qb0.w, w2[c], tB); tB = fmaf(qb1.x, w3[c], tB);
      tB = fmaf(qb1.y, w4[c], tB); tB = fmaf(qb1.z, w5[c], tB);
      pb = fmaf(fmaxf(tB, 0.2f * tB), atv[c], pb);
    }
    pa += __shfl_xor(pa, 1); pb += __shfl_xor(pb, 1);
    pa += __shfl_xor(pa, 2); pb += __shfl_xor(pb, 2);
    pa += __shfl_xor(pa, 4); pb += __shfl_xor(pb, 4);
    pa += __shfl_xor(pa, 8); pb += __shfl_xor(pb, 8);
    float nm = fmaxf(m, fmaxf(pa, pb));
    float sc = exp2f(m - nm);                 // first iter: exp2(-inf)=0
    float eA = exp2f(pa - nm);
    float eB = exp2f(pb - nm);
    m = nm;
    den = fmaf(den, sc, eA + eB);
#pragma unroll
    for (int c = 0; c < 4; ++c)
      acc[c] = fmaf(acc[c], sc, fmaf(eA, xAv[c], eB * xBv[c]));
  }
  if (p < p1) {                                  // tail edge
    const f4* ra = (const f4*)(rec + (size_t)p * 8);
    f4 r0 = __builtin_nontemporal_load(ra);
    f4 r1 = __builtin_nontemporal_load(ra + 1);
    int s = __float_as_int(r0.x);
    float4 xt = *(const float4*)(xl + (size_t)s * 64 + c0);
    float xlv[4] = {xt.x, xt.y, xt.z, xt.w};
    float part = 0.0f;
#pragma unroll
    for (int c = 0; c < 4; ++c) {
      float t = xlv[c] + xrv[c];
      t = fmaf(r0.y, w0[c], t); t = fmaf(r0.z, w1[c], t);
      t = fmaf(r0.w, w2[c], t); t = fmaf(r1.x, w3[c], t);
      t = fmaf(r1.y, w4[c], t); t = fmaf(r1.z, w5[c], t);
      part = fmaf(fmaxf(t, 0.2f * t), atv[c], part);
    }
    part += __shfl_xor(part, 1);
    part += __shfl_xor(part, 2);
    part += __shfl_xor(part, 4);
    part += __shfl_xor(part, 8);
    float nm = fmaxf(m, part);
    float sc = exp2f(m - nm);
    float ex = exp2f(part - nm);
    m = nm;
    den = fmaf(den, sc, ex);
#pragma unroll
    for (int c = 0; c < 4; ++c) acc[c] = fmaf(acc[c], sc, ex * xlv[c]);
  }
  if (n >= 0) {
    float inv = 1.0f / (den + 1e-16f);
    float4 o;
    o.x = fmaf(acc[0], inv, bov[0]);
    o.y = fmaf(acc[1], inv, bov[1]);
    o.z = fmaf(acc[2], inv, bov[2]);
    o.w = fmaf(acc[3], inv, bov[3]);
    o.x = o.x > 0.0f ? o.x : 0.0f;
    o.y = o.y > 0.0f ? o.y : 0.0f;
    o.z = o.z > 0.0f ? o.z : 0.0f;
    o.w = o.w > 0.0f ? o.w : 0.0f;
    *(float4*)(hout + (size_t)n * 64 + c0) = o;
  }
}

// ====================== MLP head: 64 -> 32 (relu) -> 4 ======================
__global__ void __launch_bounds__(256) k_mlp(
    const float* __restrict__ hin,
    const float* __restrict__ wlin, const float* __restrict__ blin,
    const float* __restrict__ wout, const float* __restrict__ bout,
    float* __restrict__ out) {
  int tid = threadIdx.x;
  int lane = tid & 63, wid = tid >> 6;
  int j = lane & 31, half = lane >> 5;
  float wr_[64];
#pragma unroll
  for (int k = 0; k < 64; ++k) wr_[k] = wlin[k * 32 + j];
  float blv = blin[j];
  float wo0 = wout[j * 4 + 0], wo1 = wout[j * 4 + 1],
        wo2 = wout[j * 4 + 2], wo3 = wout[j * 4 + 3];
  float bo0 = bout[0], bo1 = bout[1], bo2 = bout[2], bo3 = bout[3];
  const int NP = NN / 2;
  int stride = gridDim.x * 4;
  for (int np = blockIdx.x * 4 + wid; np < NP; np += stride) {
    int n0 = np * 2, n1 = np * 2 + 1;
    float v0 = hin[(size_t)n0 * 64 + lane];
    float v1 = hin[(size_t)n1 * 64 + lane];
    float acc = blv;
#pragma unroll
    for (int k = 0; k < 64; ++k) {
      float a = __shfl(v0, k), b = __shfl(v1, k);
      float xk = half ? b : a;
      acc = fmaf(xk, wr_[k], acc);
    }
    float t = acc > 0.0f ? acc : 0.0f;
    float p0 = t * wo0, p1 = t * wo1, p2 = t * wo2, p3 = t * wo3;
#pragma unroll
    for (int off = 16; off; off >>= 1) {
      p0 += __shfl_xor(p0, off); p1 += __shfl_xor(p1, off);
      p2 += __shfl_xor(p2, off); p3 += __shfl_xor(p3, off);
    }
    if (j == 0) {
      int n = half ? n1 : n0;
      float4 r = make_float4(p0 + bo0, p1 + bo1, p2 + bo2, p3 + bo3);
      *(float4*)(out + (size_t)n * 4) = r;
    }
  }
}

// ============================ launch ============================

extern "C" void kernel_launch(void* const* d_in, const int* in_sizes, int n_in,
                              void* d_out, int out_size, void* d_ws, size_t ws_size,
                              hipStream_t stream) {
  const float* x  = (const float*)d_in[0];
  const int*   ei = (const int*)d_in[1];
  const float* ea = (const float*)d_in[2];
  const int* src = ei;
  const int* dst = ei + NE;

  const float *wl[3], *bl[3], *wrm[3], *br[3], *wem[3], *attv[3], *bov[3];
  for (int l = 0; l < 3; ++l) {
    int b = 3 + l * 7;
    wl[l]  = (const float*)d_in[b + 0];
    bl[l]  = (const float*)d_in[b + 1];
    wrm[l] = (const float*)d_in[b + 2];
    br[l]  = (const float*)d_in[b + 3];
    wem[l] = (const float*)d_in[b + 4];
    attv[l]= (const float*)d_in[b + 5];
    bov[l] = (const float*)d_in[b + 6];
  }
  const float* wlin = (const float*)d_in[24];
  const float* blin = (const float*)d_in[25];
  const float* wout = (const float*)d_in[26];
  const float* bout = (const float*)d_in[27];
  float* outp = (float*)d_out;

  // workspace carve (256B aligned)
  char* w = (char*)d_ws;
  size_t off = 0;
  auto carve = [&](size_t bytes) -> void* {
    void* p = w + off;
    off += (bytes + 255) & ~(size_t)255;
    return p;
  };
  int*   cnt  = (int*)carve((size_t)NN * 4);
  int*   rp   = (int*)carve((size_t)(NN + 1) * 4);
  int*   bsum = (int*)carve(1024 * 4);
  int*   boff = (int*)carve(1024 * 4);
  int*   hist = (int*)carve(64 * 4);
  int*   cur2 = (int*)carve(64 * 4);
  int*   order= (int*)carve((size_t)NN * 4);
  int*   rank = (int*)carve((size_t)NE * 4);
  float* rec  = (float*)carve((size_t)NEP * 32);      // 32B records
  float* xlb  = (float*)carve((size_t)NN * 64 * 4);
  float* xrb  = (float*)carve((size_t)NN * 64 * 4);
  float* hA   = (float*)carve((size_t)NN * 64 * 4);
  float* hB   = (float*)carve((size_t)NN * 64 * 4);
  (void)ws_size; (void)n_in; (void)in_sizes; (void)out_size;

  const int SCAN_NB = (NN + 1023) / 1024;  // 98
  const int FUSE_NB = (NN + 15) / 16;      // 6250 blocks: 4 waves x 4 groups each
  const int CR_NB   = (NE / 4 + 255) / 256;

  hipLaunchKernelGGL(k_init_cnt, dim3((NN + 255) / 256), dim3(256), 0, stream,
                     cnt, hist, cur2);
  hipLaunchKernelGGL(k_count_rank, dim3(CR_NB), dim3(256), 0, stream, dst, cnt, rank);
  hipLaunchKernelGGL(k_scan_a, dim3(SCAN_NB), dim3(1024), 0, stream, cnt, rp, bsum, hist);
  hipLaunchKernelGGL(k_scan_b, dim3(1), dim3(1024), 0, stream, bsum, boff, SCAN_NB,
                     hist, cur2);
  hipLaunchKernelGGL(k_scan_c, dim3(SCAN_NB), dim3(1024), 0, stream, rp, boff, cnt,
                     cur2, order);
  hipLaunchKernelGGL(k_scatter3, dim3(CR_NB), dim3(256), 0, stream,
                     src, dst, rank, ea, rp, rec);
  hipLaunchKernelGGL(k_lamean2, dim3((NN + 15) / 16), dim3(256), 0, stream, rp, rec);

  // layer 1 (din=6): x -> hA
  hipLaunchKernelGGL((k_xform<6>), dim3(1024), dim3(256), 0, stream,
                     x, wl[0], bl[0], wrm[0], br[0], xlb, xrb);
  hipLaunchKernelGGL(k_fused, dim3(FUSE_NB), dim3(256), 0, stream,
                     xlb, xrb, rec, rp, order, wem[0], attv[0], bov[0], hA);
  // layer 2: hA -> hB
  hipLaunchKernelGGL((k_xform<64>), dim3(2048), dim3(256), 0, stream,
                     hA, wl[1], bl[1], wrm[1], br[1], xlb, xrb);
  hipLaunchKernelGGL(k_fused, dim3(FUSE_NB), dim3(256), 0, stream,
                     xlb, xrb, rec, rp, order, wem[1], attv[1], bov[1], hB);
  // layer 3: hB -> hA
  hipLaunchKernelGGL((k_xform<64>), dim3(2048), dim3(256), 0, stream,
                     hB, wl[2], bl[2], wrm[2], br[2], xlb, xrb);
  hipLaunchKernelGGL(k_fused, dim3(FUSE_NB), dim3(256), 0, stream,
                     xlb, xrb, rec, rp, order, wem[2], attv[2], bov[2], hA);
  // MLP head
  hipLaunchKernelGGL(k_mlp, dim3(2048), dim3(256), 0, stream,
                     hA, wlin, blin, wout, bout, outp);
}

// Round 7
// 605.367 us; speedup vs baseline: 2.1176x; 1.1165x over previous
//
#include <hip/hip_runtime.h>
#include <hip/hip_bf16.h>
#include <math.h>

#define NN 100000
#define NE 1600000
#define NEP 1700000        // NE + NN (self loops)
#define HD 64
#define NEGS 0.2f

typedef float f2 __attribute__((ext_vector_type(2)));
typedef float f4 __attribute__((ext_vector_type(4)));

__device__ __forceinline__ f2 sp2(float v) { return (f2){v, v}; }
__device__ __forceinline__ f2 ffma2(f2 a, f2 b, f2 c) {
#if __has_builtin(__builtin_elementwise_fma)
  return __builtin_elementwise_fma(a, b, c);
#else
  return a * b + c;
#endif
}
__device__ __forceinline__ f2 fmax2(f2 a, f2 b) {
#if __has_builtin(__builtin_elementwise_max)
  return __builtin_elementwise_max(a, b);
#else
  f2 r; r.x = fmaxf(a.x, b.x); r.y = fmaxf(a.y, b.y); return r;
#endif
}

// ============================ CSR build ============================

__global__ void k_init_cnt(int* __restrict__ cnt, int* __restrict__ hist,
                           int* __restrict__ cursor2) {
  int i = blockIdx.x * 256 + threadIdx.x;
  if (i < NN) cnt[i] = 1;             // self loop pre-counted -> ranks start at 1
  if (blockIdx.x == 0) {
    if (threadIdx.x < 64) hist[threadIdx.x] = 0;
    else if (threadIdx.x < 128) cursor2[threadIdx.x - 64] = 0;
  }
}

// count in-degree AND record each edge's rank within its dst segment.
// rank >= 1; slot rp[dst]+0 is reserved for the self loop.
__global__ void k_count_rank(const int* __restrict__ dst, int* __restrict__ cnt,
                             int* __restrict__ rank) {
  int base = (blockIdx.x * 256 + threadIdx.x) * 4;
  if (base >= NE) return;
  int4 dv = *(const int4*)(dst + base);
  int4 rv;
  rv.x = atomicAdd(&cnt[dv.x], 1);
  rv.y = atomicAdd(&cnt[dv.y], 1);
  rv.z = atomicAdd(&cnt[dv.z], 1);
  rv.w = atomicAdd(&cnt[dv.w], 1);
  *(int4*)(rank + base) = rv;
}

// scan of cnt -> rp (exclusive) ; also 64-bin degree histogram (LDS-batched)
__global__ void k_scan_a(const int* __restrict__ cnt, int* __restrict__ rp,
                         int* __restrict__ bsum, int* __restrict__ hist) {
  __shared__ int tmp[1024];
  __shared__ int lh[64];
  int t = threadIdx.x, b = blockIdx.x;
  int i = b * 1024 + t;
  int v = (i < NN) ? cnt[i] : 0;
  tmp[t] = v;
  if (t < 64) lh[t] = 0;
  __syncthreads();
  if (i < NN) atomicAdd(&lh[v < 63 ? v : 63], 1);
  for (int off = 1; off < 1024; off <<= 1) {
    int a = (t >= off) ? tmp[t - off] : 0;
    __syncthreads(); tmp[t] += a; __syncthreads();
  }
  if (i < NN) rp[i] = tmp[t] - v;     // exclusive
  if (t == 1023) bsum[b] = tmp[t];    // block total
  if (t < 64) { int h = lh[t]; if (h) atomicAdd(&hist[t], h); }
}

__global__ void k_scan_b(const int* __restrict__ bsum, int* __restrict__ boff, int nb,
                         const int* __restrict__ hist, int* __restrict__ cursor2) {
  __shared__ int tmp[1024];
  int t = threadIdx.x;
  int v = (t < nb) ? bsum[t] : 0;
  tmp[t] = v; __syncthreads();
  for (int off = 1; off < 1024; off <<= 1) {
    int a = (t >= off) ? tmp[t - off] : 0;
    __syncthreads(); tmp[t] += a; __syncthreads();
  }
  if (t < nb) boff[t] = tmp[t] - v;
  // exclusive scan of 64-bin degree histogram (wave 0 only) -> bin bases
  if (t < 64) {
    int h = hist[t];
    int s = h;
#pragma unroll
    for (int off = 1; off < 64; off <<= 1) {
      int u = __shfl_up(s, off);
      if (t >= off) s += u;
    }
    cursor2[t] = s - h;
  }
}

// finalize rp and scatter nodes into degree-bucketed order[].
// Hierarchical rank: LDS histogram -> one global atomic per (block,bin).
__global__ void k_scan_c(int* __restrict__ rp, const int* __restrict__ boff,
                         const int* __restrict__ deg,   // aliases cnt (degree)
                         int* __restrict__ cursor2, int* __restrict__ order) {
  __shared__ int lh[64];
  __shared__ int lbase[64];
  int t = threadIdx.x, b = blockIdx.x;
  int i = b * 1024 + t;
  if (t < 64) lh[t] = 0;
  __syncthreads();
  int bin = 0, lr = 0;
  if (i < NN) {
    int d = deg[i];
    bin = d < 63 ? d : 63;
    lr = atomicAdd(&lh[bin], 1);       // local rank within (block, bin)
    rp[i] = rp[i] + boff[b];
  }
  __syncthreads();
  if (t < 64) {
    int h = lh[t];
    lbase[t] = h ? atomicAdd(&cursor2[t], h) : 0;   // reserve range
  }
  __syncthreads();
  if (i < NN) order[lbase[bin] + lr] = i;
  if (i == 0) rp[NN] = NEP;
}

// ============ scatter edges into CSR-ordered 32B records ============
// p = rp[dst] + rank  (no atomics; rp is L2-resident).
// rec[p] = {src_as_float, a0..a5, pad}.
__global__ void __launch_bounds__(256) k_scatter3(
    const int* __restrict__ src, const int* __restrict__ dst,
    const int* __restrict__ rank, const float* __restrict__ ea,
    const int* __restrict__ rp, float* __restrict__ rec) {
  int base = (blockIdx.x * 256 + threadIdx.x) * 4;
  if (base >= NE) return;
  int4 sv = *(const int4*)(src + base);
  int4 dv = *(const int4*)(dst + base);
  int4 rv = *(const int4*)(rank + base);
  const float4* e4 = (const float4*)(ea + (size_t)base * 6);
  float4 e0 = e4[0], e1 = e4[1], e2 = e4[2], e3 = e4[3], e4v = e4[4], e5 = e4[5];
  int d[4] = {dv.x, dv.y, dv.z, dv.w};
  int rk[4] = {rv.x, rv.y, rv.z, rv.w};
  int s[4] = {sv.x, sv.y, sv.z, sv.w};
  int p[4];
#pragma unroll
  for (int k = 0; k < 4; ++k) p[k] = rp[d[k]] + rk[k];
  float a[24] = {e0.x, e0.y, e0.z, e0.w, e1.x, e1.y, e1.z, e1.w,
                 e2.x, e2.y, e2.z, e2.w, e3.x, e3.y, e3.z, e3.w,
                 e4v.x, e4v.y, e4v.z, e4v.w, e5.x, e5.y, e5.z, e5.w};
#pragma unroll
  for (int k = 0; k < 4; ++k) {
    float* r = rec + (size_t)p[k] * 8;
    *(float4*)r       = make_float4(__int_as_float(s[k]),
                                    a[6 * k + 0], a[6 * k + 1], a[6 * k + 2]);
    *(float4*)(r + 4) = make_float4(a[6 * k + 3], a[6 * k + 4], a[6 * k + 5], 0.f);
  }
}

// self-loop attr = mean of incoming edge attrs; 16 lanes per node sweep the
// node's record segment (coalesced 512B per group), butterfly-reduce, and
// lane 0 writes the self record at slot rp[n].
__global__ void __launch_bounds__(256) k_lamean2(const int* __restrict__ rp,
                                                 float* __restrict__ rec) {
  int tid = threadIdx.x;
  int q = tid & 15;
  int n = (blockIdx.x * 256 + tid) >> 4;     // 16 groups/block, exact fit
  if (n >= NN) return;
  int p0 = rp[n], p1 = rp[n + 1];
  float s0 = 0, s1 = 0, s2 = 0, s3 = 0, s4 = 0, s5 = 0;
  for (int p = p0 + 1 + q; p < p1; p += 16) {
    const float* r = rec + (size_t)p * 8;
    float4 r0 = *(const float4*)r;
    float4 r1 = *(const float4*)(r + 4);
    s0 += r0.y; s1 += r0.z; s2 += r0.w;
    s3 += r1.x; s4 += r1.y; s5 += r1.z;
  }
#pragma unroll
  for (int off = 1; off < 16; off <<= 1) {
    s0 += __shfl_xor(s0, off); s1 += __shfl_xor(s1, off);
    s2 += __shfl_xor(s2, off); s3 += __shfl_xor(s3, off);
    s4 += __shfl_xor(s4, off); s5 += __shfl_xor(s5, off);
  }
  if (q == 0) {
    int c = p1 - p0 - 1;
    float inv = c > 0 ? 1.0f / (float)c : 0.0f;
    float* r = rec + (size_t)p0 * 8;
    *(float4*)r       = make_float4(__int_as_float(n), s0 * inv, s1 * inv, s2 * inv);
    *(float4*)(r + 4) = make_float4(s3 * inv, s4 * inv, s5 * inv, 0.f);
  }
}

// ====================== node transforms (xl, xr) ======================
template <int DIN>
__global__ void __launch_bounds__(256) k_xform(
    const float* __restrict__ x,
    const float* __restrict__ wl, const float* __restrict__ bl,
    const float* __restrict__ wr, const float* __restrict__ br,
    float* __restrict__ xl, float* __restrict__ xr) {
  int tid = threadIdx.x;
  int lane = tid & 63, wid = tid >> 6;
  int h = lane;
  float wlr[DIN], wrr[DIN];
#pragma unroll
  for (int k = 0; k < DIN; ++k) { wlr[k] = wl[k * 64 + h]; wrr[k] = wr[k * 64 + h]; }
  float blv = bl[h], brv = br[h];
  int stride = gridDim.x * 4;
  for (int n = blockIdx.x * 4 + wid; n < NN; n += stride) {
    float xv = (lane < DIN) ? x[(size_t)n * DIN + lane] : 0.0f;
    float aL = blv, aR = brv;
#pragma unroll
    for (int k = 0; k < DIN; ++k) {
      float xk = __shfl(xv, k);
      aL = fmaf(xk, wlr[k], aL);
      aR = fmaf(xk, wrr[k], aR);
    }
    xl[(size_t)n * 64 + h] = aL;
    xr[(size_t)n * 64 + h] = aR;
  }
}

// ============== fused edge-logit + online softmax + aggregate ==============
// 16 lanes per node, 4 channels per lane (2x f2 for v_pk_fma_f32), 4 groups
// per wave. LPT: slots consumed in reverse degree order (heavy blocks first).
// Unrolled by 2 edges; paired online-softmax update (3 exp2 per pair).
__global__ void __launch_bounds__(256) k_fused(
    const float* __restrict__ xl, const float* __restrict__ xr,
    const float* __restrict__ rec,
    const int* __restrict__ rp, const int* __restrict__ order,
    const float* __restrict__ we, const float* __restrict__ att,
    const float* __restrict__ bo, float* __restrict__ hout) {
  int tid = threadIdx.x;
  int lane = tid & 63;
  int q = lane & 15;
  int c0 = q * 4;
  f2 w0a, w0b, w1a, w1b, w2a, w2b, w3a, w3b, w4a, w4b, w5a, w5b;
  w0a = *(const f2*)(we + 0 * 64 + c0); w0b = *(const f2*)(we + 0 * 64 + c0 + 2);
  w1a = *(const f2*)(we + 1 * 64 + c0); w1b = *(const f2*)(we + 1 * 64 + c0 + 2);
  w2a = *(const f2*)(we + 2 * 64 + c0); w2b = *(const f2*)(we + 2 * 64 + c0 + 2);
  w3a = *(const f2*)(we + 3 * 64 + c0); w3b = *(const f2*)(we + 3 * 64 + c0 + 2);
  w4a = *(const f2*)(we + 4 * 64 + c0); w4b = *(const f2*)(we + 4 * 64 + c0 + 2);
  w5a = *(const f2*)(we + 5 * 64 + c0); w5b = *(const f2*)(we + 5 * 64 + c0 + 2);
  f2 ata = *(const f2*)(att + c0) * 1.44269504f;       // fold log2(e)
  f2 atb = *(const f2*)(att + c0 + 2) * 1.44269504f;
  f2 boa = *(const f2*)(bo + c0);
  f2 bob = *(const f2*)(bo + c0 + 2);
  int gw = (blockIdx.x * 256 + tid) >> 6;       // global wave id
  int slot = gw * 4 + (lane >> 4);              // node slot for this group
  int n = (slot < NN) ? order[NN - 1 - slot] : -1;   // LPT: heavy first
  int p0 = 0, p1 = 0;
  f2 xra = (f2){0, 0}, xrb2 = (f2){0, 0};
  if (n >= 0) {
    p0 = rp[n]; p1 = rp[n + 1];
    const f4 t = *(const f4*)(xr + (size_t)n * 64 + c0);
    xra = (f2){t.x, t.y}; xrb2 = (f2){t.z, t.w};
  }
  float m = -INFINITY, den = 0.0f;
  f2 acca = (f2){0, 0}, accb = (f2){0, 0};
  int p = p0;
  for (; p + 2 <= p1; p += 2) {
    const f4* ra = (const f4*)(rec + (size_t)p * 8);
    f4 qa0 = ra[0], qa1 = ra[1], qb0 = ra[2], qb1 = ra[3];
    int sA = __float_as_int(qa0.x), sB = __float_as_int(qb0.x);
    f4 xA = *(const f4*)(xl + (size_t)sA * 64 + c0);
    f4 xB = *(const f4*)(xl + (size_t)sB * 64 + c0);
    f2 xAa = (f2){xA.x, xA.y}, xAb = (f2){xA.z, xA.w};
    f2 xBa = (f2){xB.x, xB.y}, xBb = (f2){xB.z, xB.w};
    // edge A logit (packed pairs)
    f2 tA = xAa + xra;
    tA = ffma2(sp2(qa0.y), w0a, tA); tA = ffma2(sp2(qa0.z), w1a, tA);
    tA = ffma2(sp2(qa0.w), w2a, tA); tA = ffma2(sp2(qa1.x), w3a, tA);
    tA = ffma2(sp2(qa1.y), w4a, tA); tA = ffma2(sp2(qa1.z), w5a, tA);
    f2 pav = fmax2(tA, sp2(0.2f) * tA) * ata;
    f2 uA = xAb + xrb2;
    uA = ffma2(sp2(qa0.y), w0b, uA); uA = ffma2(sp2(qa0.z), w1b, uA);
    uA = ffma2(sp2(qa0.w), w2b, uA); uA = ffma2(sp2(qa1.x), w3b, uA);
    uA = ffma2(sp2(qa1.y), w4b, uA); uA = ffma2(sp2(qa1.z), w5b, uA);
    pav = ffma2(fmax2(uA, sp2(0.2f) * uA), atb, pav);
    // edge B logit
    f2 tB = xBa + xra;
    tB = ffma2(sp2(qb0.y), w0a, tB); tB = ffma2(sp2(qb0.z), w1a, tB);
    tB = ffma2(sp2(qb0.w), w2a, tB); tB = ffma2(sp2(qb1.x), w3a, tB);
    tB = ffma2(sp2(qb1.y), w4a, tB); tB = ffma2(sp2(qb1.z), w5a, tB);
    f2 pbv = fmax2(tB, sp2(0.2f) * tB) * ata;
    f2 uB = xBb + xrb2;
    uB = ffma2(sp2(qb0.y), w0b, uB); uB = ffma2(sp2(qb0.z), w1b, uB);
    uB = ffma2(sp2(qb0.w), w2b, uB); uB = ffma2(sp2(qb1.x), w3b, uB);
    uB = ffma2(sp2(qb1.y), w4b, uB); uB = ffma2(sp2(qb1.z), w5b, uB);
    pbv = ffma2(fmax2(uB, sp2(0.2f) * uB), atb, pbv);
    float pa = pav.x + pav.y;
    float pb = pbv.x + pbv.y;
    pa += __shfl_xor(pa, 1); pb += __shfl_xor(pb, 1);
    pa += __shfl_xor(pa, 2); pb += __shfl_xor(pb, 2);
    pa += __shfl_xor(pa, 4); pb += __shfl_xor(pb, 4);
    pa += __shfl_xor(pa, 8); pb += __shfl_xor(pb, 8);
    float nm = fmaxf(m, fmaxf(pa, pb));
    float sc = exp2f(m - nm);                 // first iter: exp2(-inf)=0
    float eA = exp2f(pa - nm);
    float eB = exp2f(pb - nm);
    m = nm;
    den = fmaf(den, sc, eA + eB);
    acca = ffma2(acca, sp2(sc), ffma2(sp2(eA), xAa, sp2(eB) * xBa));
    accb = ffma2(accb, sp2(sc), ffma2(sp2(eA), xAb, sp2(eB) * xBb));
  }
  if (p < p1) {                                  // tail edge
    const f4* ra = (const f4*)(rec + (size_t)p * 8);
    f4 r0 = ra[0], r1 = ra[1];
    int s = __float_as_int(r0.x);
    f4 xt = *(const f4*)(xl + (size_t)s * 64 + c0);
    f2 xa = (f2){xt.x, xt.y}, xb = (f2){xt.z, xt.w};
    f2 t = xa + xra;
    t = ffma2(sp2(r0.y), w0a, t); t = ffma2(sp2(r0.z), w1a, t);
    t = ffma2(sp2(r0.w), w2a, t); t = ffma2(sp2(r1.x), w3a, t);
    t = ffma2(sp2(r1.y), w4a, t); t = ffma2(sp2(r1.z), w5a, t);
    f2 pv = fmax2(t, sp2(0.2f) * t) * ata;
    f2 u = xb + xrb2;
    u = ffma2(sp2(r0.y), w0b, u); u = ffma2(sp2(r0.z), w1b, u);
    u = ffma2(sp2(r0.w), w2b, u); u = ffma2(sp2(r1.x), w3b, u);
    u = ffma2(sp2(r1.y), w4b, u); u = ffma2(sp2(r1.z), w5b, u);
    pv = ffma2(fmax2(u, sp2(0.2f) * u), atb, pv);
    float part = pv.x + pv.y;
    part += __shfl_xor(part, 1);
    part += __shfl_xor(part, 2);
    part += __shfl_xor(part, 4);
    part += __shfl_xor(part, 8);
    float nm = fmaxf(m, part);
    float sc = exp2f(m - nm);
    float ex = exp2f(part - nm);
    m = nm;
    den = fmaf(den, sc, ex);
    acca = ffma2(acca, sp2(sc), sp2(ex) * xa);
    accb = ffma2(accb, sp2(sc), sp2(ex) * xb);
  }
  if (n >= 0) {
    float inv = 1.0f / (den + 1e-16f);
    f2 oa = ffma2(acca, sp2(inv), boa);
    f2 ob = ffma2(accb, sp2(inv), bob);
    oa = fmax2(oa, (f2){0, 0});
    ob = fmax2(ob, (f2){0, 0});
    f4 o = (f4){oa.x, oa.y, ob.x, ob.y};
    *(f4*)(hout + (size_t)n * 64 + c0) = o;
  }
}

// ====================== MLP head: 64 -> 32 (relu) -> 4 ======================
__global__ void __launch_bounds__(256) k_mlp(
    const float* __restrict__ hin,
    const float* __restrict__ wlin, const float* __restrict__ blin,
    const float* __restrict__ wout, const float* __restrict__ bout,
    float* __restrict__ out) {
  int tid = threadIdx.x;
  int lane = tid & 63, wid = tid >> 6;
  int j = lane & 31, half = lane >> 5;
  float wr_[64];
#pragma unroll
  for (int k = 0; k < 64; ++k) wr_[k] = wlin[k * 32 + j];
  float blv = blin[j];
  float wo0 = wout[j * 4 + 0], wo1 = wout[j * 4 + 1],
        wo2 = wout[j * 4 + 2], wo3 = wout[j * 4 + 3];
  float bo0 = bout[0], bo1 = bout[1], bo2 = bout[2], bo3 = bout[3];
  const int NP = NN / 2;
  int stride = gridDim.x * 4;
  for (int np = blockIdx.x * 4 + wid; np < NP; np += stride) {
    int n0 = np * 2, n1 = np * 2 + 1;
    float v0 = hin[(size_t)n0 * 64 + lane];
    float v1 = hin[(size_t)n1 * 64 + lane];
    float acc = blv;
#pragma unroll
    for (int k = 0; k < 64; ++k) {
      float a = __shfl(v0, k), b = __shfl(v1, k);
      float xk = half ? b : a;
      acc = fmaf(xk, wr_[k], acc);
    }
    float t = acc > 0.0f ? acc : 0.0f;
    float p0 = t * wo0, p1 = t * wo1, p2 = t * wo2, p3 = t * wo3;
#pragma unroll
    for (int off = 16; off; off >>= 1) {
      p0 += __shfl_xor(p0, off); p1 += __shfl_xor(p1, off);
      p2 += __shfl_xor(p2, off); p3 += __shfl_xor(p3, off);
    }
    if (j == 0) {
      int n = half ? n1 : n0;
      float4 r = make_float4(p0 + bo0, p1 + bo1, p2 + bo2, p3 + bo3);
      *(float4*)(out + (size_t)n * 4) = r;
    }
  }
}

// ============================ launch ============================

extern "C" void kernel_launch(void* const* d_in, const int* in_sizes, int n_in,
                              void* d_out, int out_size, void* d_ws, size_t ws_size,
                              hipStream_t stream) {
  const float* x  = (const float*)d_in[0];
  const int*   ei = (const int*)d_in[1];
  const float* ea = (const float*)d_in[2];
  const int* src = ei;
  const int* dst = ei + NE;

  const float *wl[3], *bl[3], *wrm[3], *br[3], *wem[3], *attv[3], *bov[3];
  for (int l = 0; l < 3; ++l) {
    int b = 3 + l * 7;
    wl[l]  = (const float*)d_in[b + 0];
    bl[l]  = (const float*)d_in[b + 1];
    wrm[l] = (const float*)d_in[b + 2];
    br[l]  = (const float*)d_in[b + 3];
    wem[l] = (const float*)d_in[b + 4];
    attv[l]= (const float*)d_in[b + 5];
    bov[l] = (const float*)d_in[b + 6];
  }
  const float* wlin = (const float*)d_in[24];
  const float* blin = (const float*)d_in[25];
  const float* wout = (const float*)d_in[26];
  const float* bout = (const float*)d_in[27];
  float* outp = (float*)d_out;

  // workspace carve (256B aligned)
  char* w = (char*)d_ws;
  size_t off = 0;
  auto carve = [&](size_t bytes) -> void* {
    void* p = w + off;
    off += (bytes + 255) & ~(size_t)255;
    return p;
  };
  int*   cnt  = (int*)carve((size_t)NN * 4);
  int*   rp   = (int*)carve((size_t)(NN + 1) * 4);
  int*   bsum = (int*)carve(1024 * 4);
  int*   boff = (int*)carve(1024 * 4);
  int*   hist = (int*)carve(64 * 4);
  int*   cur2 = (int*)carve(64 * 4);
  int*   order= (int*)carve((size_t)NN * 4);
  int*   rank = (int*)carve((size_t)NE * 4);
  float* rec  = (float*)carve((size_t)NEP * 32);      // 32B records
  float* xlb  = (float*)carve((size_t)NN * 64 * 4);
  float* xrb  = (float*)carve((size_t)NN * 64 * 4);
  float* hA   = (float*)carve((size_t)NN * 64 * 4);
  float* hB   = (float*)carve((size_t)NN * 64 * 4);
  (void)ws_size; (void)n_in; (void)in_sizes; (void)out_size;

  const int SCAN_NB = (NN + 1023) / 1024;  // 98
  const int FUSE_NB = (NN + 15) / 16;      // 6250 blocks: 4 waves x 4 groups each
  const int CR_NB   = (NE / 4 + 255) / 256;

  hipLaunchKernelGGL(k_init_cnt, dim3((NN + 255) / 256), dim3(256), 0, stream,
                     cnt, hist, cur2);
  hipLaunchKernelGGL(k_count_rank, dim3(CR_NB), dim3(256), 0, stream, dst, cnt, rank);
  hipLaunchKernelGGL(k_scan_a, dim3(SCAN_NB), dim3(1024), 0, stream, cnt, rp, bsum, hist);
  hipLaunchKernelGGL(k_scan_b, dim3(1), dim3(1024), 0, stream, bsum, boff, SCAN_NB,
                     hist, cur2);
  hipLaunchKernelGGL(k_scan_c, dim3(SCAN_NB), dim3(1024), 0, stream, rp, boff, cnt,
                     cur2, order);
  hipLaunchKernelGGL(k_scatter3, dim3(CR_NB), dim3(256), 0, stream,
                     src, dst, rank, ea, rp, rec);
  hipLaunchKernelGGL(k_lamean2, dim3((NN + 15) / 16), dim3(256), 0, stream, rp, rec);

  // layer 1 (din=6): x -> hA
  hipLaunchKernelGGL((k_xform<6>), dim3(1024), dim3(256), 0, stream,
                     x, wl[0], bl[0], wrm[0], br[0], xlb, xrb);
  hipLaunchKernelGGL(k_fused, dim3(FUSE_NB), dim3(256), 0, stream,
                     xlb, xrb, rec, rp, order, wem[0], attv[0], bov[0], hA);
  // layer 2: hA -> hB
  hipLaunchKernelGGL((k_xform<64>), dim3(2048), dim3(256), 0, stream,
                     hA, wl[1], bl[1], wrm[1], br[1], xlb, xrb);
  hipLaunchKernelGGL(k_fused, dim3(FUSE_NB), dim3(256), 0, stream,
                     xlb, xrb, rec, rp, order, wem[1], attv[1], bov[1], hB);
  // layer 3: hB -> hA
  hipLaunchKernelGGL((k_xform<64>), dim3(2048), dim3(256), 0, stream,
                     hB, wl[2], bl[2], wrm[2], br[2], xlb, xrb);
  hipLaunchKernelGGL(k_fused, dim3(FUSE_NB), dim3(256), 0, stream,
                     xlb, xrb, rec, rp, order, wem[2], attv[2], bov[2], hA);
  // MLP head
  hipLaunchKernelGGL(k_mlp, dim3(2048), dim3(256), 0, stream,
                     hA, wlin, blin, wout, bout, outp);
}

// Round 8
// 539.720 us; speedup vs baseline: 2.3752x; 1.1216x over previous
//
#include <hip/hip_runtime.h>
#include <hip/hip_bf16.h>
#include <math.h>

#define NN 100000
#define NE 1600000
#define NEP 1700000        // NE + NN (self loops)
#define HD 64
#define NEGS 0.2f

typedef float f2 __attribute__((ext_vector_type(2)));
typedef float f4 __attribute__((ext_vector_type(4)));

__device__ __forceinline__ f2 sp2(float v) { return (f2){v, v}; }
__device__ __forceinline__ f4 sp4(float v) { return (f4){v, v, v, v}; }
__device__ __forceinline__ f2 ffma2(f2 a, f2 b, f2 c) {
#if __has_builtin(__builtin_elementwise_fma)
  return __builtin_elementwise_fma(a, b, c);
#else
  return a * b + c;
#endif
}
__device__ __forceinline__ f4 ffma4(f4 a, f4 b, f4 c) {
#if __has_builtin(__builtin_elementwise_fma)
  return __builtin_elementwise_fma(a, b, c);
#else
  return a * b + c;
#endif
}
__device__ __forceinline__ f2 fmax2(f2 a, f2 b) {
#if __has_builtin(__builtin_elementwise_max)
  return __builtin_elementwise_max(a, b);
#else
  f2 r; r.x = fmaxf(a.x, b.x); r.y = fmaxf(a.y, b.y); return r;
#endif
}
__device__ __forceinline__ f4 fmax4(f4 a, f4 b) {
#if __has_builtin(__builtin_elementwise_max)
  return __builtin_elementwise_max(a, b);
#else
  f4 r; r.x = fmaxf(a.x, b.x); r.y = fmaxf(a.y, b.y);
  r.z = fmaxf(a.z, b.z); r.w = fmaxf(a.w, b.w); return r;
#endif
}

// ============================ CSR build ============================

__global__ void k_init_cnt(int* __restrict__ cnt, int* __restrict__ hist,
                           int* __restrict__ cursor2) {
  int i = blockIdx.x * 256 + threadIdx.x;
  if (i < NN) cnt[i] = 1;             // self loop pre-counted -> ranks start at 1
  if (blockIdx.x == 0) {
    if (threadIdx.x < 64) hist[threadIdx.x] = 0;
    else if (threadIdx.x < 128) cursor2[threadIdx.x - 64] = 0;
  }
}

// count in-degree AND record each edge's rank within its dst segment.
// rank >= 1; slot rp[dst]+0 is reserved for the self loop.
__global__ void k_count_rank(const int* __restrict__ dst, int* __restrict__ cnt,
                             int* __restrict__ rank) {
  int base = (blockIdx.x * 256 + threadIdx.x) * 4;
  if (base >= NE) return;
  int4 dv = *(const int4*)(dst + base);
  int4 rv;
  rv.x = atomicAdd(&cnt[dv.x], 1);
  rv.y = atomicAdd(&cnt[dv.y], 1);
  rv.z = atomicAdd(&cnt[dv.z], 1);
  rv.w = atomicAdd(&cnt[dv.w], 1);
  *(int4*)(rank + base) = rv;
}

// scan of cnt -> rp (exclusive) ; also 64-bin degree histogram (LDS-batched)
__global__ void k_scan_a(const int* __restrict__ cnt, int* __restrict__ rp,
                         int* __restrict__ bsum, int* __restrict__ hist) {
  __shared__ int tmp[1024];
  __shared__ int lh[64];
  int t = threadIdx.x, b = blockIdx.x;
  int i = b * 1024 + t;
  int v = (i < NN) ? cnt[i] : 0;
  tmp[t] = v;
  if (t < 64) lh[t] = 0;
  __syncthreads();
  if (i < NN) atomicAdd(&lh[v < 63 ? v : 63], 1);
  for (int off = 1; off < 1024; off <<= 1) {
    int a = (t >= off) ? tmp[t - off] : 0;
    __syncthreads(); tmp[t] += a; __syncthreads();
  }
  if (i < NN) rp[i] = tmp[t] - v;     // exclusive
  if (t == 1023) bsum[b] = tmp[t];    // block total
  if (t < 64) { int h = lh[t]; if (h) atomicAdd(&hist[t], h); }
}

__global__ void k_scan_b(const int* __restrict__ bsum, int* __restrict__ boff, int nb,
                         const int* __restrict__ hist, int* __restrict__ cursor2) {
  __shared__ int tmp[1024];
  int t = threadIdx.x;
  int v = (t < nb) ? bsum[t] : 0;
  tmp[t] = v; __syncthreads();
  for (int off = 1; off < 1024; off <<= 1) {
    int a = (t >= off) ? tmp[t - off] : 0;
    __syncthreads(); tmp[t] += a; __syncthreads();
  }
  if (t < nb) boff[t] = tmp[t] - v;
  // exclusive scan of 64-bin degree histogram (wave 0 only) -> bin bases
  if (t < 64) {
    int h = hist[t];
    int s = h;
#pragma unroll
    for (int off = 1; off < 64; off <<= 1) {
      int u = __shfl_up(s, off);
      if (t >= off) s += u;
    }
    cursor2[t] = s - h;
  }
}

// finalize rp and scatter nodes into degree-bucketed order[].
// Hierarchical rank: LDS histogram -> one global atomic per (block,bin).
__global__ void k_scan_c(int* __restrict__ rp, const int* __restrict__ boff,
                         const int* __restrict__ deg,   // aliases cnt (degree)
                         int* __restrict__ cursor2, int* __restrict__ order) {
  __shared__ int lh[64];
  __shared__ int lbase[64];
  int t = threadIdx.x, b = blockIdx.x;
  int i = b * 1024 + t;
  if (t < 64) lh[t] = 0;
  __syncthreads();
  int bin = 0, lr = 0;
  if (i < NN) {
    int d = deg[i];
    bin = d < 63 ? d : 63;
    lr = atomicAdd(&lh[bin], 1);       // local rank within (block, bin)
    rp[i] = rp[i] + boff[b];
  }
  __syncthreads();
  if (t < 64) {
    int h = lh[t];
    lbase[t] = h ? atomicAdd(&cursor2[t], h) : 0;   // reserve range
  }
  __syncthreads();
  if (i < NN) order[lbase[bin] + lr] = i;
  if (i == 0) rp[NN] = NEP;
}

// ============ scatter edges into CSR-ordered 32B records ============
// p = rp[dst] + rank  (no atomics; rp is L2-resident).
// rec[p] = {src_as_float, a0..a5, pad}.
__global__ void __launch_bounds__(256) k_scatter3(
    const int* __restrict__ src, const int* __restrict__ dst,
    const int* __restrict__ rank, const float* __restrict__ ea,
    const int* __restrict__ rp, float* __restrict__ rec) {
  int base = (blockIdx.x * 256 + threadIdx.x) * 4;
  if (base >= NE) return;
  int4 sv = *(const int4*)(src + base);
  int4 dv = *(const int4*)(dst + base);
  int4 rv = *(const int4*)(rank + base);
  const float4* e4 = (const float4*)(ea + (size_t)base * 6);
  float4 e0 = e4[0], e1 = e4[1], e2 = e4[2], e3 = e4[3], e4v = e4[4], e5 = e4[5];
  int d[4] = {dv.x, dv.y, dv.z, dv.w};
  int rk[4] = {rv.x, rv.y, rv.z, rv.w};
  int s[4] = {sv.x, sv.y, sv.z, sv.w};
  int p[4];
#pragma unroll
  for (int k = 0; k < 4; ++k) p[k] = rp[d[k]] + rk[k];
  float a[24] = {e0.x, e0.y, e0.z, e0.w, e1.x, e1.y, e1.z, e1.w,
                 e2.x, e2.y, e2.z, e2.w, e3.x, e3.y, e3.z, e3.w,
                 e4v.x, e4v.y, e4v.z, e4v.w, e5.x, e5.y, e5.z, e5.w};
#pragma unroll
  for (int k = 0; k < 4; ++k) {
    float* r = rec + (size_t)p[k] * 8;
    *(float4*)r       = make_float4(__int_as_float(s[k]),
                                    a[6 * k + 0], a[6 * k + 1], a[6 * k + 2]);
    *(float4*)(r + 4) = make_float4(a[6 * k + 3], a[6 * k + 4], a[6 * k + 5], 0.f);
  }
}

// self-loop attr = mean of incoming edge attrs; 16 lanes per node sweep the
// node's record segment (coalesced 512B per group), butterfly-reduce, and
// lane 0 writes the self record at slot rp[n].
__global__ void __launch_bounds__(256) k_lamean2(const int* __restrict__ rp,
                                                 float* __restrict__ rec) {
  int tid = threadIdx.x;
  int q = tid & 15;
  int n = (blockIdx.x * 256 + tid) >> 4;     // 16 groups/block, exact fit
  if (n >= NN) return;
  int p0 = rp[n], p1 = rp[n + 1];
  float s0 = 0, s1 = 0, s2 = 0, s3 = 0, s4 = 0, s5 = 0;
  for (int p = p0 + 1 + q; p < p1; p += 16) {
    const float* r = rec + (size_t)p * 8;
    float4 r0 = *(const float4*)r;
    float4 r1 = *(const float4*)(r + 4);
    s0 += r0.y; s1 += r0.z; s2 += r0.w;
    s3 += r1.x; s4 += r1.y; s5 += r1.z;
  }
#pragma unroll
  for (int off = 1; off < 16; off <<= 1) {
    s0 += __shfl_xor(s0, off); s1 += __shfl_xor(s1, off);
    s2 += __shfl_xor(s2, off); s3 += __shfl_xor(s3, off);
    s4 += __shfl_xor(s4, off); s5 += __shfl_xor(s5, off);
  }
  if (q == 0) {
    int c = p1 - p0 - 1;
    float inv = c > 0 ? 1.0f / (float)c : 0.0f;
    float* r = rec + (size_t)p0 * 8;
    *(float4*)r       = make_float4(__int_as_float(n), s0 * inv, s1 * inv, s2 * inv);
    *(float4*)(r + 4) = make_float4(s3 * inv, s4 * inv, s5 * inv, 0.f);
  }
}

// ====================== node transforms (xl, xr) ======================
template <int DIN>
__global__ void __launch_bounds__(256) k_xform(
    const float* __restrict__ x,
    const float* __restrict__ wl, const float* __restrict__ bl,
    const float* __restrict__ wr, const float* __restrict__ br,
    float* __restrict__ xl, float* __restrict__ xr) {
  int tid = threadIdx.x;
  int lane = tid & 63, wid = tid >> 6;
  int h = lane;
  float wlr[DIN], wrr[DIN];
#pragma unroll
  for (int k = 0; k < DIN; ++k) { wlr[k] = wl[k * 64 + h]; wrr[k] = wr[k * 64 + h]; }
  float blv = bl[h], brv = br[h];
  int stride = gridDim.x * 4;
  for (int n = blockIdx.x * 4 + wid; n < NN; n += stride) {
    float xv = (lane < DIN) ? x[(size_t)n * DIN + lane] : 0.0f;
    float aL = blv, aR = brv;
#pragma unroll
    for (int k = 0; k < DIN; ++k) {
      float xk = __shfl(xv, k);
      aL = fmaf(xk, wlr[k], aL);
      aR = fmaf(xk, wrr[k], aR);
    }
    xl[(size_t)n * 64 + h] = aL;
    xr[(size_t)n * 64 + h] = aR;
  }
}

// ============== fused edge-logit + online softmax + aggregate ==============
// 16 lanes per node, 4 channels per lane (2x f2 for v_pk_fma_f32), 4 groups
// per wave. LPT: slots consumed in reverse degree order (heavy blocks first).
// Unrolled by 2 edges; paired online-softmax update (3 exp2 per pair).
__global__ void __launch_bounds__(256) k_fused(
    const float* __restrict__ xl, const float* __restrict__ xr,
    const float* __restrict__ rec,
    const int* __restrict__ rp, const int* __restrict__ order,
    const float* __restrict__ we, const float* __restrict__ att,
    const float* __restrict__ bo, float* __restrict__ hout) {
  int tid = threadIdx.x;
  int lane = tid & 63;
  int q = lane & 15;
  int c0 = q * 4;
  f2 w0a, w0b, w1a, w1b, w2a, w2b, w3a, w3b, w4a, w4b, w5a, w5b;
  w0a = *(const f2*)(we + 0 * 64 + c0); w0b = *(const f2*)(we + 0 * 64 + c0 + 2);
  w1a = *(const f2*)(we + 1 * 64 + c0); w1b = *(const f2*)(we + 1 * 64 + c0 + 2);
  w2a = *(const f2*)(we + 2 * 64 + c0); w2b = *(const f2*)(we + 2 * 64 + c0 + 2);
  w3a = *(const f2*)(we + 3 * 64 + c0); w3b = *(const f2*)(we + 3 * 64 + c0 + 2);
  w4a = *(const f2*)(we + 4 * 64 + c0); w4b = *(const f2*)(we + 4 * 64 + c0 + 2);
  w5a = *(const f2*)(we + 5 * 64 + c0); w5b = *(const f2*)(we + 5 * 64 + c0 + 2);
  f2 ata = *(const f2*)(att + c0) * 1.44269504f;       // fold log2(e)
  f2 atb = *(const f2*)(att + c0 + 2) * 1.44269504f;
  f2 boa = *(const f2*)(bo + c0);
  f2 bob = *(const f2*)(bo + c0 + 2);
  int gw = (blockIdx.x * 256 + tid) >> 6;       // global wave id
  int slot = gw * 4 + (lane >> 4);              // node slot for this group
  int n = (slot < NN) ? order[NN - 1 - slot] : -1;   // LPT: heavy first
  int p0 = 0, p1 = 0;
  f2 xra = (f2){0, 0}, xrb2 = (f2){0, 0};
  if (n >= 0) {
    p0 = rp[n]; p1 = rp[n + 1];
    const f4 t = *(const f4*)(xr + (size_t)n * 64 + c0);
    xra = (f2){t.x, t.y}; xrb2 = (f2){t.z, t.w};
  }
  float m = -INFINITY, den = 0.0f;
  f2 acca = (f2){0, 0}, accb = (f2){0, 0};
  int p = p0;
  for (; p + 2 <= p1; p += 2) {
    const f4* ra = (const f4*)(rec + (size_t)p * 8);
    f4 qa0 = ra[0], qa1 = ra[1], qb0 = ra[2], qb1 = ra[3];
    int sA = __float_as_int(qa0.x), sB = __float_as_int(qb0.x);
    f4 xA = *(const f4*)(xl + (size_t)sA * 64 + c0);
    f4 xB = *(const f4*)(xl + (size_t)sB * 64 + c0);
    f2 xAa = (f2){xA.x, xA.y}, xAb = (f2){xA.z, xA.w};
    f2 xBa = (f2){xB.x, xB.y}, xBb = (f2){xB.z, xB.w};
    // edge A logit (packed pairs)
    f2 tA = xAa + xra;
    tA = ffma2(sp2(qa0.y), w0a, tA); tA = ffma2(sp2(qa0.z), w1a, tA);
    tA = ffma2(sp2(qa0.w), w2a, tA); tA = ffma2(sp2(qa1.x), w3a, tA);
    tA = ffma2(sp2(qa1.y), w4a, tA); tA = ffma2(sp2(qa1.z), w5a, tA);
    f2 pav = fmax2(tA, sp2(0.2f) * tA) * ata;
    f2 uA = xAb + xrb2;
    uA = ffma2(sp2(qa0.y), w0b, uA); uA = ffma2(sp2(qa0.z), w1b, uA);
    uA = ffma2(sp2(qa0.w), w2b, uA); uA = ffma2(sp2(qa1.x), w3b, uA);
    uA = ffma2(sp2(qa1.y), w4b, uA); uA = ffma2(sp2(qa1.z), w5b, uA);
    pav = ffma2(fmax2(uA, sp2(0.2f) * uA), atb, pav);
    // edge B logit
    f2 tB = xBa + xra;
    tB = ffma2(sp2(qb0.y), w0a, tB); tB = ffma2(sp2(qb0.z), w1a, tB);
    tB = ffma2(sp2(qb0.w), w2a, tB); tB = ffma2(sp2(qb1.x), w3a, tB);
    tB = ffma2(sp2(qb1.y), w4a, tB); tB = ffma2(sp2(qb1.z), w5a, tB);
    f2 pbv = fmax2(tB, sp2(0.2f) * tB) * ata;
    f2 uB = xBb + xrb2;
    uB = ffma2(sp2(qb0.y), w0b, uB); uB = ffma2(sp2(qb0.z), w1b, uB);
    uB = ffma2(sp2(qb0.w), w2b, uB); uB = ffma2(sp2(qb1.x), w3b, uB);
    uB = ffma2(sp2(qb1.y), w4b, uB); uB = ffma2(sp2(qb1.z), w5b, uB);
    pbv = ffma2(fmax2(uB, sp2(0.2f) * uB), atb, pbv);
    float pa = pav.x + pav.y;
    float pb = pbv.x + pbv.y;
    pa += __shfl_xor(pa, 1); pb += __shfl_xor(pb, 1);
    pa += __shfl_xor(pa, 2); pb += __shfl_xor(pb, 2);
    pa += __shfl_xor(pa, 4); pb += __shfl_xor(pb, 4);
    pa += __shfl_xor(pa, 8); pb += __shfl_xor(pb, 8);
    float nm = fmaxf(m, fmaxf(pa, pb));
    float sc = exp2f(m - nm);                 // first iter: exp2(-inf)=0
    float eA = exp2f(pa - nm);
    float eB = exp2f(pb - nm);
    m = nm;
    den = fmaf(den, sc, eA + eB);
    acca = ffma2(acca, sp2(sc), ffma2(sp2(eA), xAa, sp2(eB) * xBa));
    accb = ffma2(accb, sp2(sc), ffma2(sp2(eA), xAb, sp2(eB) * xBb));
  }
  if (p < p1) {                                  // tail edge
    const f4* ra = (const f4*)(rec + (size_t)p * 8);
    f4 r0 = ra[0], r1 = ra[1];
    int s = __float_as_int(r0.x);
    f4 xt = *(const f4*)(xl + (size_t)s * 64 + c0);
    f2 xa = (f2){xt.x, xt.y}, xb = (f2){xt.z, xt.w};
    f2 t = xa + xra;
    t = ffma2(sp2(r0.y), w0a, t); t = ffma2(sp2(r0.z), w1a, t);
    t = ffma2(sp2(r0.w), w2a, t); t = ffma2(sp2(r1.x), w3a, t);
    t = ffma2(sp2(r1.y), w4a, t); t = ffma2(sp2(r1.z), w5a, t);
    f2 pv = fmax2(t, sp2(0.2f) * t) * ata;
    f2 u = xb + xrb2;
    u = ffma2(sp2(r0.y), w0b, u); u = ffma2(sp2(r0.z), w1b, u);
    u = ffma2(sp2(r0.w), w2b, u); u = ffma2(sp2(r1.x), w3b, u);
    u = ffma2(sp2(r1.y), w4b, u); u = ffma2(sp2(r1.z), w5b, u);
    pv = ffma2(fmax2(u, sp2(0.2f) * u), atb, pv);
    float part = pv.x + pv.y;
    part += __shfl_xor(part, 1);
    part += __shfl_xor(part, 2);
    part += __shfl_xor(part, 4);
    part += __shfl_xor(part, 8);
    float nm = fmaxf(m, part);
    float sc = exp2f(m - nm);
    float ex = exp2f(part - nm);
    m = nm;
    den = fmaf(den, sc, ex);
    acca = ffma2(acca, sp2(sc), sp2(ex) * xa);
    accb = ffma2(accb, sp2(sc), sp2(ex) * xb);
  }
  if (n >= 0) {
    float inv = 1.0f / (den + 1e-16f);
    f2 oa = ffma2(acca, sp2(inv), boa);
    f2 ob = ffma2(accb, sp2(inv), bob);
    oa = fmax2(oa, (f2){0, 0});
    ob = fmax2(ob, (f2){0, 0});
    f4 o = (f4){oa.x, oa.y, ob.x, ob.y};
    *(f4*)(hout + (size_t)n * 64 + c0) = o;
  }
}

// ====================== MLP head: 64 -> 32 (relu) -> 4 ======================
// Thread-per-node; weights broadcast from LDS; 8 independent f4 acc chains.
__global__ void __launch_bounds__(256) k_mlp2(
    const float* __restrict__ hin,
    const float* __restrict__ wlin, const float* __restrict__ blin,
    const float* __restrict__ wout, const float* __restrict__ bout,
    float* __restrict__ out) {
  __shared__ float wl_s[64 * 32];
  __shared__ float bl_s[32];
  __shared__ float wo_s[32 * 4];
  __shared__ float bo_s[4];
  int tid = threadIdx.x;
#pragma unroll
  for (int i = 0; i < 8; ++i) wl_s[tid + i * 256] = wlin[tid + i * 256];
  if (tid < 128) wo_s[tid] = wout[tid];
  if (tid < 32) bl_s[tid] = blin[tid];
  if (tid >= 32 && tid < 36) bo_s[tid - 32] = bout[tid - 32];
  __syncthreads();
  int n = blockIdx.x * 256 + tid;
  if (n >= NN) return;
  // node features -> 16 f4 regs (contiguous 256B per thread)
  const f4* hp = (const f4*)(hin + (size_t)n * 64);
  f4 h[16];
#pragma unroll
  for (int i = 0; i < 16; ++i) h[i] = hp[i];
  // hidden[32] = relu(h @ wlin + blin): 8 f4 accumulators, broadcast LDS reads
  f4 acc[8];
#pragma unroll
  for (int j4 = 0; j4 < 8; ++j4) acc[j4] = *(const f4*)(bl_s + j4 * 4);
#pragma unroll
  for (int k = 0; k < 64; ++k) {
    float hk = ((const float*)h)[k];
    const f4* wrow = (const f4*)(wl_s + k * 32);
#pragma unroll
    for (int j4 = 0; j4 < 8; ++j4)
      acc[j4] = ffma4(sp4(hk), wrow[j4], acc[j4]);
  }
  // out[4] = relu(hidden) @ wout + bout
  f4 o4 = *(const f4*)(bo_s);
#pragma unroll
  for (int j4 = 0; j4 < 8; ++j4) {
    f4 hid = fmax4(acc[j4], sp4(0.0f));
    const f4* wo = (const f4*)(wo_s + j4 * 16);
    o4 = ffma4(sp4(hid.x), wo[0], o4);
    o4 = ffma4(sp4(hid.y), wo[1], o4);
    o4 = ffma4(sp4(hid.z), wo[2], o4);
    o4 = ffma4(sp4(hid.w), wo[3], o4);
  }
  *(f4*)(out + (size_t)n * 4) = o4;
}

// ============================ launch ============================

extern "C" void kernel_launch(void* const* d_in, const int* in_sizes, int n_in,
                              void* d_out, int out_size, void* d_ws, size_t ws_size,
                              hipStream_t stream) {
  const float* x  = (const float*)d_in[0];
  const int*   ei = (const int*)d_in[1];
  const float* ea = (const float*)d_in[2];
  const int* src = ei;
  const int* dst = ei + NE;

  const float *wl[3], *bl[3], *wrm[3], *br[3], *wem[3], *attv[3], *bov[3];
  for (int l = 0; l < 3; ++l) {
    int b = 3 + l * 7;
    wl[l]  = (const float*)d_in[b + 0];
    bl[l]  = (const float*)d_in[b + 1];
    wrm[l] = (const float*)d_in[b + 2];
    br[l]  = (const float*)d_in[b + 3];
    wem[l] = (const float*)d_in[b + 4];
    attv[l]= (const float*)d_in[b + 5];
    bov[l] = (const float*)d_in[b + 6];
  }
  const float* wlin = (const float*)d_in[24];
  const float* blin = (const float*)d_in[25];
  const float* wout = (const float*)d_in[26];
  const float* bout = (const float*)d_in[27];
  float* outp = (float*)d_out;

  // workspace carve (256B aligned)
  char* w = (char*)d_ws;
  size_t off = 0;
  auto carve = [&](size_t bytes) -> void* {
    void* p = w + off;
    off += (bytes + 255) & ~(size_t)255;
    return p;
  };
  int*   cnt  = (int*)carve((size_t)NN * 4);
  int*   rp   = (int*)carve((size_t)(NN + 1) * 4);
  int*   bsum = (int*)carve(1024 * 4);
  int*   boff = (int*)carve(1024 * 4);
  int*   hist = (int*)carve(64 * 4);
  int*   cur2 = (int*)carve(64 * 4);
  int*   order= (int*)carve((size_t)NN * 4);
  int*   rank = (int*)carve((size_t)NE * 4);
  float* rec  = (float*)carve((size_t)NEP * 32);      // 32B records
  float* xlb  = (float*)carve((size_t)NN * 64 * 4);
  float* xrb  = (float*)carve((size_t)NN * 64 * 4);
  float* hA   = (float*)carve((size_t)NN * 64 * 4);
  float* hB   = (float*)carve((size_t)NN * 64 * 4);
  (void)ws_size; (void)n_in; (void)in_sizes; (void)out_size;

  const int SCAN_NB = (NN + 1023) / 1024;  // 98
  const int FUSE_NB = (NN + 15) / 16;      // 6250 blocks: 4 waves x 4 groups each
  const int CR_NB   = (NE / 4 + 255) / 256;

  hipLaunchKernelGGL(k_init_cnt, dim3((NN + 255) / 256), dim3(256), 0, stream,
                     cnt, hist, cur2);
  hipLaunchKernelGGL(k_count_rank, dim3(CR_NB), dim3(256), 0, stream, dst, cnt, rank);
  hipLaunchKernelGGL(k_scan_a, dim3(SCAN_NB), dim3(1024), 0, stream, cnt, rp, bsum, hist);
  hipLaunchKernelGGL(k_scan_b, dim3(1), dim3(1024), 0, stream, bsum, boff, SCAN_NB,
                     hist, cur2);
  hipLaunchKernelGGL(k_scan_c, dim3(SCAN_NB), dim3(1024), 0, stream, rp, boff, cnt,
                     cur2, order);
  hipLaunchKernelGGL(k_scatter3, dim3(CR_NB), dim3(256), 0, stream,
                     src, dst, rank, ea, rp, rec);
  hipLaunchKernelGGL(k_lamean2, dim3((NN + 15) / 16), dim3(256), 0, stream, rp, rec);

  // layer 1 (din=6): x -> hA
  hipLaunchKernelGGL((k_xform<6>), dim3(1024), dim3(256), 0, stream,
                     x, wl[0], bl[0], wrm[0], br[0], xlb, xrb);
  hipLaunchKernelGGL(k_fused, dim3(FUSE_NB), dim3(256), 0, stream,
                     xlb, xrb, rec, rp, order, wem[0], attv[0], bov[0], hA);
  // layer 2: hA -> hB
  hipLaunchKernelGGL((k_xform<64>), dim3(2048), dim3(256), 0, stream,
                     hA, wl[1], bl[1], wrm[1], br[1], xlb, xrb);
  hipLaunchKernelGGL(k_fused, dim3(FUSE_NB), dim3(256), 0, stream,
                     xlb, xrb, rec, rp, order, wem[1], attv[1], bov[1], hB);
  // layer 3: hB -> hA
  hipLaunchKernelGGL((k_xform<64>), dim3(2048), dim3(256), 0, stream,
                     hB, wl[2], bl[2], wrm[2], br[2], xlb, xrb);
  hipLaunchKernelGGL(k_fused, dim3(FUSE_NB), dim3(256), 0, stream,
                     xlb, xrb, rec, rp, order, wem[2], attv[2], bov[2], hA);
  // MLP head
  hipLaunchKernelGGL(k_mlp2, dim3((NN + 255) / 256), dim3(256), 0, stream,
                     hA, wlin, blin, wout, bout, outp);
}

// Round 9
// 526.747 us; speedup vs baseline: 2.4337x; 1.0246x over previous
//
#include <hip/hip_runtime.h>
#include <hip/hip_bf16.h>
#include <math.h>

#define NN 100000
#define NE 1600000
#define NEP 1700000        // NE + NN (self loops)
#define HD 64
#define NEGS 0.2f

typedef float f2 __attribute__((ext_vector_type(2)));
typedef float f4 __attribute__((ext_vector_type(4)));

__device__ __forceinline__ f2 sp2(float v) { return (f2){v, v}; }
__device__ __forceinline__ f4 sp4(float v) { return (f4){v, v, v, v}; }
__device__ __forceinline__ f2 ffma2(f2 a, f2 b, f2 c) {
#if __has_builtin(__builtin_elementwise_fma)
  return __builtin_elementwise_fma(a, b, c);
#else
  return a * b + c;
#endif
}
__device__ __forceinline__ f4 ffma4(f4 a, f4 b, f4 c) {
#if __has_builtin(__builtin_elementwise_fma)
  return __builtin_elementwise_fma(a, b, c);
#else
  return a * b + c;
#endif
}
__device__ __forceinline__ f2 fmax2(f2 a, f2 b) {
#if __has_builtin(__builtin_elementwise_max)
  return __builtin_elementwise_max(a, b);
#else
  f2 r; r.x = fmaxf(a.x, b.x); r.y = fmaxf(a.y, b.y); return r;
#endif
}
__device__ __forceinline__ f4 fmax4(f4 a, f4 b) {
#if __has_builtin(__builtin_elementwise_max)
  return __builtin_elementwise_max(a, b);
#else
  f4 r; r.x = fmaxf(a.x, b.x); r.y = fmaxf(a.y, b.y);
  r.z = fmaxf(a.z, b.z); r.w = fmaxf(a.w, b.w); return r;
#endif
}

// ============================ CSR build ============================

__global__ void k_init_cnt(int* __restrict__ cnt, int* __restrict__ hist,
                           int* __restrict__ cursor2) {
  int i = blockIdx.x * 256 + threadIdx.x;
  if (i < NN) cnt[i] = 1;             // self loop pre-counted -> ranks start at 1
  if (blockIdx.x == 0) {
    if (threadIdx.x < 64) hist[threadIdx.x] = 0;
    else if (threadIdx.x < 128) cursor2[threadIdx.x - 64] = 0;
  }
}

// count in-degree AND record each edge's rank within its dst segment.
// rank >= 1; slot rp[dst]+0 is reserved for the self loop.
__global__ void k_count_rank(const int* __restrict__ dst, int* __restrict__ cnt,
                             int* __restrict__ rank) {
  int base = (blockIdx.x * 256 + threadIdx.x) * 4;
  if (base >= NE) return;
  int4 dv = *(const int4*)(dst + base);
  int4 rv;
  rv.x = atomicAdd(&cnt[dv.x], 1);
  rv.y = atomicAdd(&cnt[dv.y], 1);
  rv.z = atomicAdd(&cnt[dv.z], 1);
  rv.w = atomicAdd(&cnt[dv.w], 1);
  *(int4*)(rank + base) = rv;
}

// scan of cnt -> rp (exclusive) ; also 64-bin degree histogram (LDS-batched)
__global__ void k_scan_a(const int* __restrict__ cnt, int* __restrict__ rp,
                         int* __restrict__ bsum, int* __restrict__ hist) {
  __shared__ int tmp[1024];
  __shared__ int lh[64];
  int t = threadIdx.x, b = blockIdx.x;
  int i = b * 1024 + t;
  int v = (i < NN) ? cnt[i] : 0;
  tmp[t] = v;
  if (t < 64) lh[t] = 0;
  __syncthreads();
  if (i < NN) atomicAdd(&lh[v < 63 ? v : 63], 1);
  for (int off = 1; off < 1024; off <<= 1) {
    int a = (t >= off) ? tmp[t - off] : 0;
    __syncthreads(); tmp[t] += a; __syncthreads();
  }
  if (i < NN) rp[i] = tmp[t] - v;     // exclusive
  if (t == 1023) bsum[b] = tmp[t];    // block total
  if (t < 64) { int h = lh[t]; if (h) atomicAdd(&hist[t], h); }
}

__global__ void k_scan_b(const int* __restrict__ bsum, int* __restrict__ boff, int nb,
                         const int* __restrict__ hist, int* __restrict__ cursor2) {
  __shared__ int tmp[1024];
  int t = threadIdx.x;
  int v = (t < nb) ? bsum[t] : 0;
  tmp[t] = v; __syncthreads();
  for (int off = 1; off < 1024; off <<= 1) {
    int a = (t >= off) ? tmp[t - off] : 0;
    __syncthreads(); tmp[t] += a; __syncthreads();
  }
  if (t < nb) boff[t] = tmp[t] - v;
  // exclusive scan of 64-bin degree histogram (wave 0 only) -> bin bases
  if (t < 64) {
    int h = hist[t];
    int s = h;
#pragma unroll
    for (int off = 1; off < 64; off <<= 1) {
      int u = __shfl_up(s, off);
      if (t >= off) s += u;
    }
    cursor2[t] = s - h;
  }
}

// finalize rp and scatter nodes into degree-bucketed order[].
// Hierarchical rank: LDS histogram -> one global atomic per (block,bin).
__global__ void k_scan_c(int* __restrict__ rp, const int* __restrict__ boff,
                         const int* __restrict__ deg,   // aliases cnt (degree)
                         int* __restrict__ cursor2, int* __restrict__ order) {
  __shared__ int lh[64];
  __shared__ int lbase[64];
  int t = threadIdx.x, b = blockIdx.x;
  int i = b * 1024 + t;
  if (t < 64) lh[t] = 0;
  __syncthreads();
  int bin = 0, lr = 0;
  if (i < NN) {
    int d = deg[i];
    bin = d < 63 ? d : 63;
    lr = atomicAdd(&lh[bin], 1);       // local rank within (block, bin)
    rp[i] = rp[i] + boff[b];
  }
  __syncthreads();
  if (t < 64) {
    int h = lh[t];
    lbase[t] = h ? atomicAdd(&cursor2[t], h) : 0;   // reserve range
  }
  __syncthreads();
  if (i < NN) order[lbase[bin] + lr] = i;
  if (i == 0) rp[NN] = NEP;
}

// ============ scatter edges into CSR-ordered 32B records ============
// p = rp[dst] + rank  (no atomics; rp is L2-resident).
// rec[p] = {src_as_float, a0..a5, pad}.
__global__ void __launch_bounds__(256) k_scatter3(
    const int* __restrict__ src, const int* __restrict__ dst,
    const int* __restrict__ rank, const float* __restrict__ ea,
    const int* __restrict__ rp, float* __restrict__ rec) {
  int base = (blockIdx.x * 256 + threadIdx.x) * 4;
  if (base >= NE) return;
  int4 sv = *(const int4*)(src + base);
  int4 dv = *(const int4*)(dst + base);
  int4 rv = *(const int4*)(rank + base);
  const float4* e4 = (const float4*)(ea + (size_t)base * 6);
  float4 e0 = e4[0], e1 = e4[1], e2 = e4[2], e3 = e4[3], e4v = e4[4], e5 = e4[5];
  int d[4] = {dv.x, dv.y, dv.z, dv.w};
  int rk[4] = {rv.x, rv.y, rv.z, rv.w};
  int s[4] = {sv.x, sv.y, sv.z, sv.w};
  int p[4];
#pragma unroll
  for (int k = 0; k < 4; ++k) p[k] = rp[d[k]] + rk[k];
  float a[24] = {e0.x, e0.y, e0.z, e0.w, e1.x, e1.y, e1.z, e1.w,
                 e2.x, e2.y, e2.z, e2.w, e3.x, e3.y, e3.z, e3.w,
                 e4v.x, e4v.y, e4v.z, e4v.w, e5.x, e5.y, e5.z, e5.w};
#pragma unroll
  for (int k = 0; k < 4; ++k) {
    float* r = rec + (size_t)p[k] * 8;
    *(float4*)r       = make_float4(__int_as_float(s[k]),
                                    a[6 * k + 0], a[6 * k + 1], a[6 * k + 2]);
    *(float4*)(r + 4) = make_float4(a[6 * k + 3], a[6 * k + 4], a[6 * k + 5], 0.f);
  }
}

// self-loop attr = mean of incoming edge attrs; 16 lanes per node sweep the
// node's record segment (coalesced 512B per group), butterfly-reduce, and
// lane 0 writes the self record at slot rp[n].
__global__ void __launch_bounds__(256) k_lamean2(const int* __restrict__ rp,
                                                 float* __restrict__ rec) {
  int tid = threadIdx.x;
  int q = tid & 15;
  int n = (blockIdx.x * 256 + tid) >> 4;     // 16 groups/block, exact fit
  if (n >= NN) return;
  int p0 = rp[n], p1 = rp[n + 1];
  float s0 = 0, s1 = 0, s2 = 0, s3 = 0, s4 = 0, s5 = 0;
  for (int p = p0 + 1 + q; p < p1; p += 16) {
    const float* r = rec + (size_t)p * 8;
    float4 r0 = *(const float4*)r;
    float4 r1 = *(const float4*)(r + 4);
    s0 += r0.y; s1 += r0.z; s2 += r0.w;
    s3 += r1.x; s4 += r1.y; s5 += r1.z;
  }
#pragma unroll
  for (int off = 1; off < 16; off <<= 1) {
    s0 += __shfl_xor(s0, off); s1 += __shfl_xor(s1, off);
    s2 += __shfl_xor(s2, off); s3 += __shfl_xor(s3, off);
    s4 += __shfl_xor(s4, off); s5 += __shfl_xor(s5, off);
  }
  if (q == 0) {
    int c = p1 - p0 - 1;
    float inv = c > 0 ? 1.0f / (float)c : 0.0f;
    float* r = rec + (size_t)p0 * 8;
    *(float4*)r       = make_float4(__int_as_float(n), s0 * inv, s1 * inv, s2 * inv);
    *(float4*)(r + 4) = make_float4(s3 * inv, s4 * inv, s5 * inv, 0.f);
  }
}

// ====================== node transforms (xl, xr) ======================
// Wave per 4 nodes per iteration; lane h owns channel h; weights f2-packed
// {wl[k][h], wr[k][h]} in registers (loaded once, amortized via grid-stride).
// 4 independent pk_fma chains -> ILP covers FMA latency without occupancy.
template <int DIN>
__global__ void __launch_bounds__(256) k_xform(
    const float* __restrict__ x,
    const float* __restrict__ wl, const float* __restrict__ bl,
    const float* __restrict__ wr, const float* __restrict__ br,
    float* __restrict__ xl, float* __restrict__ xr) {
  int tid = threadIdx.x;
  int lane = tid & 63, wid = tid >> 6;
  int h = lane;
  f2 wpk[DIN];
#pragma unroll
  for (int k = 0; k < DIN; ++k) wpk[k] = (f2){wl[k * 64 + h], wr[k * 64 + h]};
  f2 bpk = (f2){bl[h], br[h]};
  int gw = blockIdx.x * 4 + wid;          // global wave id
  int nw = gridDim.x * 4;                 // total waves
  const int NG = NN / 4;                  // 4-node groups (NN % 4 == 0)
  for (int g = gw; g < NG; g += nw) {
    int n0 = g * 4;
    float xv[4];
#pragma unroll
    for (int j = 0; j < 4; ++j)
      xv[j] = (lane < DIN) ? x[(size_t)(n0 + j) * DIN + lane] : 0.0f;
    f2 acc[4];
#pragma unroll
    for (int j = 0; j < 4; ++j) acc[j] = bpk;
#pragma unroll
    for (int k = 0; k < DIN; ++k) {
#pragma unroll
      for (int j = 0; j < 4; ++j) {
        float xk = __shfl(xv[j], k);
        acc[j] = ffma2(sp2(xk), wpk[k], acc[j]);
      }
    }
#pragma unroll
    for (int j = 0; j < 4; ++j) {
      xl[(size_t)(n0 + j) * 64 + h] = acc[j].x;
      xr[(size_t)(n0 + j) * 64 + h] = acc[j].y;
    }
  }
}

// ============== fused edge-logit + online softmax + aggregate ==============
// 16 lanes per node, 4 channels per lane (2x f2 for v_pk_fma_f32), 4 groups
// per wave. LPT: slots consumed in reverse degree order (heavy blocks first).
// Unrolled by 2 edges; paired online-softmax update (3 exp2 per pair).
__global__ void __launch_bounds__(256) k_fused(
    const float* __restrict__ xl, const float* __restrict__ xr,
    const float* __restrict__ rec,
    const int* __restrict__ rp, const int* __restrict__ order,
    const float* __restrict__ we, const float* __restrict__ att,
    const float* __restrict__ bo, float* __restrict__ hout) {
  int tid = threadIdx.x;
  int lane = tid & 63;
  int q = lane & 15;
  int c0 = q * 4;
  f2 w0a, w0b, w1a, w1b, w2a, w2b, w3a, w3b, w4a, w4b, w5a, w5b;
  w0a = *(const f2*)(we + 0 * 64 + c0); w0b = *(const f2*)(we + 0 * 64 + c0 + 2);
  w1a = *(const f2*)(we + 1 * 64 + c0); w1b = *(const f2*)(we + 1 * 64 + c0 + 2);
  w2a = *(const f2*)(we + 2 * 64 + c0); w2b = *(const f2*)(we + 2 * 64 + c0 + 2);
  w3a = *(const f2*)(we + 3 * 64 + c0); w3b = *(const f2*)(we + 3 * 64 + c0 + 2);
  w4a = *(const f2*)(we + 4 * 64 + c0); w4b = *(const f2*)(we + 4 * 64 + c0 + 2);
  w5a = *(const f2*)(we + 5 * 64 + c0); w5b = *(const f2*)(we + 5 * 64 + c0 + 2);
  f2 ata = *(const f2*)(att + c0) * 1.44269504f;       // fold log2(e)
  f2 atb = *(const f2*)(att + c0 + 2) * 1.44269504f;
  f2 boa = *(const f2*)(bo + c0);
  f2 bob = *(const f2*)(bo + c0 + 2);
  int gw = (blockIdx.x * 256 + tid) >> 6;       // global wave id
  int slot = gw * 4 + (lane >> 4);              // node slot for this group
  int n = (slot < NN) ? order[NN - 1 - slot] : -1;   // LPT: heavy first
  int p0 = 0, p1 = 0;
  f2 xra = (f2){0, 0}, xrb2 = (f2){0, 0};
  if (n >= 0) {
    p0 = rp[n]; p1 = rp[n + 1];
    const f4 t = *(const f4*)(xr + (size_t)n * 64 + c0);
    xra = (f2){t.x, t.y}; xrb2 = (f2){t.z, t.w};
  }
  float m = -INFINITY, den = 0.0f;
  f2 acca = (f2){0, 0}, accb = (f2){0, 0};
  int p = p0;
  for (; p + 2 <= p1; p += 2) {
    const f4* ra = (const f4*)(rec + (size_t)p * 8);
    f4 qa0 = ra[0], qa1 = ra[1], qb0 = ra[2], qb1 = ra[3];
    int sA = __float_as_int(qa0.x), sB = __float_as_int(qb0.x);
    f4 xA = *(const f4*)(xl + (size_t)sA * 64 + c0);
    f4 xB = *(const f4*)(xl + (size_t)sB * 64 + c0);
    f2 xAa = (f2){xA.x, xA.y}, xAb = (f2){xA.z, xA.w};
    f2 xBa = (f2){xB.x, xB.y}, xBb = (f2){xB.z, xB.w};
    // edge A logit (packed pairs)
    f2 tA = xAa + xra;
    tA = ffma2(sp2(qa0.y), w0a, tA); tA = ffma2(sp2(qa0.z), w1a, tA);
    tA = ffma2(sp2(qa0.w), w2a, tA); tA = ffma2(sp2(qa1.x), w3a, tA);
    tA = ffma2(sp2(qa1.y), w4a, tA); tA = ffma2(sp2(qa1.z), w5a, tA);
    f2 pav = fmax2(tA, sp2(0.2f) * tA) * ata;
    f2 uA = xAb + xrb2;
    uA = ffma2(sp2(qa0.y), w0b, uA); uA = ffma2(sp2(qa0.z), w1b, uA);
    uA = ffma2(sp2(qa0.w), w2b, uA); uA = ffma2(sp2(qa1.x), w3b, uA);
    uA = ffma2(sp2(qa1.y), w4b, uA); uA = ffma2(sp2(qa1.z), w5b, uA);
    pav = ffma2(fmax2(uA, sp2(0.2f) * uA), atb, pav);
    // edge B logit
    f2 tB = xBa + xra;
    tB = ffma2(sp2(qb0.y), w0a, tB); tB = ffma2(sp2(qb0.z), w1a, tB);
    tB = ffma2(sp2(qb0.w), w2a, tB); tB = ffma2(sp2(qb1.x), w3a, tB);
    tB = ffma2(sp2(qb1.y), w4a, tB); tB = ffma2(sp2(qb1.z), w5a, tB);
    f2 pbv = fmax2(tB, sp2(0.2f) * tB) * ata;
    f2 uB = xBb + xrb2;
    uB = ffma2(sp2(qb0.y), w0b, uB); uB = ffma2(sp2(qb0.z), w1b, uB);
    uB = ffma2(sp2(qb0.w), w2b, uB); uB = ffma2(sp2(qb1.x), w3b, uB);
    uB = ffma2(sp2(qb1.y), w4b, uB); uB = ffma2(sp2(qb1.z), w5b, uB);
    pbv = ffma2(fmax2(uB, sp2(0.2f) * uB), atb, pbv);
    float pa = pav.x + pav.y;
    float pb = pbv.x + pbv.y;
    pa += __shfl_xor(pa, 1); pb += __shfl_xor(pb, 1);
    pa += __shfl_xor(pa, 2); pb += __shfl_xor(pb, 2);
    pa += __shfl_xor(pa, 4); pb += __shfl_xor(pb, 4);
    pa += __shfl_xor(pa, 8); pb += __shfl_xor(pb, 8);
    float nm = fmaxf(m, fmaxf(pa, pb));
    float sc = exp2f(m - nm);                 // first iter: exp2(-inf)=0
    float eA = exp2f(pa - nm);
    float eB = exp2f(pb - nm);
    m = nm;
    den = fmaf(den, sc, eA + eB);
    acca = ffma2(acca, sp2(sc), ffma2(sp2(eA), xAa, sp2(eB) * xBa));
    accb = ffma2(accb, sp2(sc), ffma2(sp2(eA), xAb, sp2(eB) * xBb));
  }
  if (p < p1) {                                  // tail edge
    const f4* ra = (const f4*)(rec + (size_t)p * 8);
    f4 r0 = ra[0], r1 = ra[1];
    int s = __float_as_int(r0.x);
    f4 xt = *(const f4*)(xl + (size_t)s * 64 + c0);
    f2 xa = (f2){xt.x, xt.y}, xb = (f2){xt.z, xt.w};
    f2 t = xa + xra;
    t = ffma2(sp2(r0.y), w0a, t); t = ffma2(sp2(r0.z), w1a, t);
    t = ffma2(sp2(r0.w), w2a, t); t = ffma2(sp2(r1.x), w3a, t);
    t = ffma2(sp2(r1.y), w4a, t); t = ffma2(sp2(r1.z), w5a, t);
    f2 pv = fmax2(t, sp2(0.2f) * t) * ata;
    f2 u = xb + xrb2;
    u = ffma2(sp2(r0.y), w0b, u); u = ffma2(sp2(r0.z), w1b, u);
    u = ffma2(sp2(r0.w), w2b, u); u = ffma2(sp2(r1.x), w3b, u);
    u = ffma2(sp2(r1.y), w4b, u); u = ffma2(sp2(r1.z), w5b, u);
    pv = ffma2(fmax2(u, sp2(0.2f) * u), atb, pv);
    float part = pv.x + pv.y;
    part += __shfl_xor(part, 1);
    part += __shfl_xor(part, 2);
    part += __shfl_xor(part, 4);
    part += __shfl_xor(part, 8);
    float nm = fmaxf(m, part);
    float sc = exp2f(m - nm);
    float ex = exp2f(part - nm);
    m = nm;
    den = fmaf(den, sc, ex);
    acca = ffma2(acca, sp2(sc), sp2(ex) * xa);
    accb = ffma2(accb, sp2(sc), sp2(ex) * xb);
  }
  if (n >= 0) {
    float inv = 1.0f / (den + 1e-16f);
    f2 oa = ffma2(acca, sp2(inv), boa);
    f2 ob = ffma2(accb, sp2(inv), bob);
    oa = fmax2(oa, (f2){0, 0});
    ob = fmax2(ob, (f2){0, 0});
    f4 o = (f4){oa.x, oa.y, ob.x, ob.y};
    *(f4*)(hout + (size_t)n * 64 + c0) = o;
  }
}

// ====================== MLP head: 64 -> 32 (relu) -> 4 ======================
// Thread-per-node; weights broadcast from LDS; 8 independent f4 acc chains.
__global__ void __launch_bounds__(256) k_mlp2(
    const float* __restrict__ hin,
    const float* __restrict__ wlin, const float* __restrict__ blin,
    const float* __restrict__ wout, const float* __restrict__ bout,
    float* __restrict__ out) {
  __shared__ float wl_s[64 * 32];
  __shared__ float bl_s[32];
  __shared__ float wo_s[32 * 4];
  __shared__ float bo_s[4];
  int tid = threadIdx.x;
#pragma unroll
  for (int i = 0; i < 8; ++i) wl_s[tid + i * 256] = wlin[tid + i * 256];
  if (tid < 128) wo_s[tid] = wout[tid];
  if (tid < 32) bl_s[tid] = blin[tid];
  if (tid >= 32 && tid < 36) bo_s[tid - 32] = bout[tid - 32];
  __syncthreads();
  int n = blockIdx.x * 256 + tid;
  if (n >= NN) return;
  // node features -> 16 f4 regs (contiguous 256B per thread)
  const f4* hp = (const f4*)(hin + (size_t)n * 64);
  f4 h[16];
#pragma unroll
  for (int i = 0; i < 16; ++i) h[i] = hp[i];
  // hidden[32] = relu(h @ wlin + blin): 8 f4 accumulators, broadcast LDS reads
  f4 acc[8];
#pragma unroll
  for (int j4 = 0; j4 < 8; ++j4) acc[j4] = *(const f4*)(bl_s + j4 * 4);
#pragma unroll
  for (int k = 0; k < 64; ++k) {
    float hk = ((const float*)h)[k];
    const f4* wrow = (const f4*)(wl_s + k * 32);
#pragma unroll
    for (int j4 = 0; j4 < 8; ++j4)
      acc[j4] = ffma4(sp4(hk), wrow[j4], acc[j4]);
  }
  // out[4] = relu(hidden) @ wout + bout
  f4 o4 = *(const f4*)(bo_s);
#pragma unroll
  for (int j4 = 0; j4 < 8; ++j4) {
    f4 hid = fmax4(acc[j4], sp4(0.0f));
    const f4* wo = (const f4*)(wo_s + j4 * 16);
    o4 = ffma4(sp4(hid.x), wo[0], o4);
    o4 = ffma4(sp4(hid.y), wo[1], o4);
    o4 = ffma4(sp4(hid.z), wo[2], o4);
    o4 = ffma4(sp4(hid.w), wo[3], o4);
  }
  *(f4*)(out + (size_t)n * 4) = o4;
}

// ============================ launch ============================

extern "C" void kernel_launch(void* const* d_in, const int* in_sizes, int n_in,
                              void* d_out, int out_size, void* d_ws, size_t ws_size,
                              hipStream_t stream) {
  const float* x  = (const float*)d_in[0];
  const int*   ei = (const int*)d_in[1];
  const float* ea = (const float*)d_in[2];
  const int* src = ei;
  const int* dst = ei + NE;

  const float *wl[3], *bl[3], *wrm[3], *br[3], *wem[3], *attv[3], *bov[3];
  for (int l = 0; l < 3; ++l) {
    int b = 3 + l * 7;
    wl[l]  = (const float*)d_in[b + 0];
    bl[l]  = (const float*)d_in[b + 1];
    wrm[l] = (const float*)d_in[b + 2];
    br[l]  = (const float*)d_in[b + 3];
    wem[l] = (const float*)d_in[b + 4];
    attv[l]= (const float*)d_in[b + 5];
    bov[l] = (const float*)d_in[b + 6];
  }
  const float* wlin = (const float*)d_in[24];
  const float* blin = (const float*)d_in[25];
  const float* wout = (const float*)d_in[26];
  const float* bout = (const float*)d_in[27];
  float* outp = (float*)d_out;

  // workspace carve (256B aligned)
  char* w = (char*)d_ws;
  size_t off = 0;
  auto carve = [&](size_t bytes) -> void* {
    void* p = w + off;
    off += (bytes + 255) & ~(size_t)255;
    return p;
  };
  int*   cnt  = (int*)carve((size_t)NN * 4);
  int*   rp   = (int*)carve((size_t)(NN + 1) * 4);
  int*   bsum = (int*)carve(1024 * 4);
  int*   boff = (int*)carve(1024 * 4);
  int*   hist = (int*)carve(64 * 4);
  int*   cur2 = (int*)carve(64 * 4);
  int*   order= (int*)carve((size_t)NN * 4);
  int*   rank = (int*)carve((size_t)NE * 4);
  float* rec  = (float*)carve((size_t)NEP * 32);      // 32B records
  float* xlb  = (float*)carve((size_t)NN * 64 * 4);
  float* xrb  = (float*)carve((size_t)NN * 64 * 4);
  float* hA   = (float*)carve((size_t)NN * 64 * 4);
  float* hB   = (float*)carve((size_t)NN * 64 * 4);
  (void)ws_size; (void)n_in; (void)in_sizes; (void)out_size;

  const int SCAN_NB = (NN + 1023) / 1024;  // 98
  const int FUSE_NB = (NN + 15) / 16;      // 6250 blocks: 4 waves x 4 groups each
  const int CR_NB   = (NE / 4 + 255) / 256;
  const int XF_NB   = 1024;                // grid-stride; weights amortized

  hipLaunchKernelGGL(k_init_cnt, dim3((NN + 255) / 256), dim3(256), 0, stream,
                     cnt, hist, cur2);
  hipLaunchKernelGGL(k_count_rank, dim3(CR_NB), dim3(256), 0, stream, dst, cnt, rank);
  hipLaunchKernelGGL(k_scan_a, dim3(SCAN_NB), dim3(1024), 0, stream, cnt, rp, bsum, hist);
  hipLaunchKernelGGL(k_scan_b, dim3(1), dim3(1024), 0, stream, bsum, boff, SCAN_NB,
                     hist, cur2);
  hipLaunchKernelGGL(k_scan_c, dim3(SCAN_NB), dim3(1024), 0, stream, rp, boff, cnt,
                     cur2, order);
  hipLaunchKernelGGL(k_scatter3, dim3(CR_NB), dim3(256), 0, stream,
                     src, dst, rank, ea, rp, rec);
  hipLaunchKernelGGL(k_lamean2, dim3((NN + 15) / 16), dim3(256), 0, stream, rp, rec);

  // layer 1 (din=6): x -> hA
  hipLaunchKernelGGL((k_xform<6>), dim3(XF_NB), dim3(256), 0, stream,
                     x, wl[0], bl[0], wrm[0], br[0], xlb, xrb);
  hipLaunchKernelGGL(k_fused, dim3(FUSE_NB), dim3(256), 0, stream,
                     xlb, xrb, rec, rp, order, wem[0], attv[0], bov[0], hA);
  // layer 2: hA -> hB
  hipLaunchKernelGGL((k_xform<64>), dim3(XF_NB), dim3(256), 0, stream,
                     hA, wl[1], bl[1], wrm[1], br[1], xlb, xrb);
  hipLaunchKernelGGL(k_fused, dim3(FUSE_NB), dim3(256), 0, stream,
                     xlb, xrb, rec, rp, order, wem[1], attv[1], bov[1], hB);
  // layer 3: hB -> hA
  hipLaunchKernelGGL((k_xform<64>), dim3(XF_NB), dim3(256), 0, stream,
                     hB, wl[2], bl[2], wrm[2], br[2], xlb, xrb);
  hipLaunchKernelGGL(k_fused, dim3(FUSE_NB), dim3(256), 0, stream,
                     xlb, xrb, rec, rp, order, wem[2], attv[2], bov[2], hA);
  // MLP head
  hipLaunchKernelGGL(k_mlp2, dim3((NN + 255) / 256), dim3(256), 0, stream,
                     hA, wlin, blin, wout, bout, outp);
}

// Round 10
// 526.008 us; speedup vs baseline: 2.4371x; 1.0014x over previous
//
#include <hip/hip_runtime.h>
#include <hip/hip_bf16.h>
#include <math.h>

#define NN 100000
#define NE 1600000
#define NEP 1700000        // NE + NN (self loops)
#define HD 64
#define NEGS 0.2f

typedef float f2 __attribute__((ext_vector_type(2)));
typedef float f4 __attribute__((ext_vector_type(4)));

__device__ __forceinline__ f2 sp2(float v) { return (f2){v, v}; }
__device__ __forceinline__ f4 sp4(float v) { return (f4){v, v, v, v}; }
__device__ __forceinline__ f2 ffma2(f2 a, f2 b, f2 c) {
#if __has_builtin(__builtin_elementwise_fma)
  return __builtin_elementwise_fma(a, b, c);
#else
  return a * b + c;
#endif
}
__device__ __forceinline__ f4 ffma4(f4 a, f4 b, f4 c) {
#if __has_builtin(__builtin_elementwise_fma)
  return __builtin_elementwise_fma(a, b, c);
#else
  return a * b + c;
#endif
}
__device__ __forceinline__ f2 fmax2(f2 a, f2 b) {
#if __has_builtin(__builtin_elementwise_max)
  return __builtin_elementwise_max(a, b);
#else
  f2 r; r.x = fmaxf(a.x, b.x); r.y = fmaxf(a.y, b.y); return r;
#endif
}
__device__ __forceinline__ f4 fmax4(f4 a, f4 b) {
#if __has_builtin(__builtin_elementwise_max)
  return __builtin_elementwise_max(a, b);
#else
  f4 r; r.x = fmaxf(a.x, b.x); r.y = fmaxf(a.y, b.y);
  r.z = fmaxf(a.z, b.z); r.w = fmaxf(a.w, b.w); return r;
#endif
}

// ============================ CSR build ============================

__global__ void k_init_cnt(int* __restrict__ cnt, int* __restrict__ hist,
                           int* __restrict__ cursor2) {
  int i = blockIdx.x * 256 + threadIdx.x;
  if (i < NN) cnt[i] = 1;             // self loop pre-counted -> ranks start at 1
  if (blockIdx.x == 0) {
    if (threadIdx.x < 64) hist[threadIdx.x] = 0;
    else if (threadIdx.x < 128) cursor2[threadIdx.x - 64] = 0;
  }
}

// count in-degree AND record each edge's rank within its dst segment.
// rank >= 1; slot rp[dst]+0 is reserved for the self loop.
__global__ void k_count_rank(const int* __restrict__ dst, int* __restrict__ cnt,
                             int* __restrict__ rank) {
  int base = (blockIdx.x * 256 + threadIdx.x) * 4;
  if (base >= NE) return;
  int4 dv = *(const int4*)(dst + base);
  int4 rv;
  rv.x = atomicAdd(&cnt[dv.x], 1);
  rv.y = atomicAdd(&cnt[dv.y], 1);
  rv.z = atomicAdd(&cnt[dv.z], 1);
  rv.w = atomicAdd(&cnt[dv.w], 1);
  *(int4*)(rank + base) = rv;
}

// scan of cnt -> rp (exclusive) ; also 64-bin degree histogram (LDS-batched)
__global__ void k_scan_a(const int* __restrict__ cnt, int* __restrict__ rp,
                         int* __restrict__ bsum, int* __restrict__ hist) {
  __shared__ int tmp[1024];
  __shared__ int lh[64];
  int t = threadIdx.x, b = blockIdx.x;
  int i = b * 1024 + t;
  int v = (i < NN) ? cnt[i] : 0;
  tmp[t] = v;
  if (t < 64) lh[t] = 0;
  __syncthreads();
  if (i < NN) atomicAdd(&lh[v < 63 ? v : 63], 1);
  for (int off = 1; off < 1024; off <<= 1) {
    int a = (t >= off) ? tmp[t - off] : 0;
    __syncthreads(); tmp[t] += a; __syncthreads();
  }
  if (i < NN) rp[i] = tmp[t] - v;     // exclusive
  if (t == 1023) bsum[b] = tmp[t];    // block total
  if (t < 64) { int h = lh[t]; if (h) atomicAdd(&hist[t], h); }
}

__global__ void k_scan_b(const int* __restrict__ bsum, int* __restrict__ boff, int nb,
                         const int* __restrict__ hist, int* __restrict__ cursor2) {
  __shared__ int tmp[1024];
  int t = threadIdx.x;
  int v = (t < nb) ? bsum[t] : 0;
  tmp[t] = v; __syncthreads();
  for (int off = 1; off < 1024; off <<= 1) {
    int a = (t >= off) ? tmp[t - off] : 0;
    __syncthreads(); tmp[t] += a; __syncthreads();
  }
  if (t < nb) boff[t] = tmp[t] - v;
  // exclusive scan of 64-bin degree histogram (wave 0 only) -> bin bases
  if (t < 64) {
    int h = hist[t];
    int s = h;
#pragma unroll
    for (int off = 1; off < 64; off <<= 1) {
      int u = __shfl_up(s, off);
      if (t >= off) s += u;
    }
    cursor2[t] = s - h;
  }
}

// finalize rp and scatter nodes into degree-bucketed order[].
// Hierarchical rank: LDS histogram -> one global atomic per (block,bin).
__global__ void k_scan_c(int* __restrict__ rp, const int* __restrict__ boff,
                         const int* __restrict__ deg,   // aliases cnt (degree)
                         int* __restrict__ cursor2, int* __restrict__ order) {
  __shared__ int lh[64];
  __shared__ int lbase[64];
  int t = threadIdx.x, b = blockIdx.x;
  int i = b * 1024 + t;
  if (t < 64) lh[t] = 0;
  __syncthreads();
  int bin = 0, lr = 0;
  if (i < NN) {
    int d = deg[i];
    bin = d < 63 ? d : 63;
    lr = atomicAdd(&lh[bin], 1);       // local rank within (block, bin)
    rp[i] = rp[i] + boff[b];
  }
  __syncthreads();
  if (t < 64) {
    int h = lh[t];
    lbase[t] = h ? atomicAdd(&cursor2[t], h) : 0;   // reserve range
  }
  __syncthreads();
  if (i < NN) order[lbase[bin] + lr] = i;
  if (i == 0) rp[NN] = NEP;
}

// ============ scatter edges into CSR-ordered 32B records ============
// p = rp[dst] + rank  (no atomics; rp is L2-resident).
// rec[p] = {src_as_float, a0..a5, pad}.
__global__ void __launch_bounds__(256) k_scatter3(
    const int* __restrict__ src, const int* __restrict__ dst,
    const int* __restrict__ rank, const float* __restrict__ ea,
    const int* __restrict__ rp, float* __restrict__ rec) {
  int base = (blockIdx.x * 256 + threadIdx.x) * 4;
  if (base >= NE) return;
  int4 sv = *(const int4*)(src + base);
  int4 dv = *(const int4*)(dst + base);
  int4 rv = *(const int4*)(rank + base);
  const float4* e4 = (const float4*)(ea + (size_t)base * 6);
  float4 e0 = e4[0], e1 = e4[1], e2 = e4[2], e3 = e4[3], e4v = e4[4], e5 = e4[5];
  int d[4] = {dv.x, dv.y, dv.z, dv.w};
  int rk[4] = {rv.x, rv.y, rv.z, rv.w};
  int s[4] = {sv.x, sv.y, sv.z, sv.w};
  int p[4];
#pragma unroll
  for (int k = 0; k < 4; ++k) p[k] = rp[d[k]] + rk[k];
  float a[24] = {e0.x, e0.y, e0.z, e0.w, e1.x, e1.y, e1.z, e1.w,
                 e2.x, e2.y, e2.z, e2.w, e3.x, e3.y, e3.z, e3.w,
                 e4v.x, e4v.y, e4v.z, e4v.w, e5.x, e5.y, e5.z, e5.w};
#pragma unroll
  for (int k = 0; k < 4; ++k) {
    float* r = rec + (size_t)p[k] * 8;
    *(float4*)r       = make_float4(__int_as_float(s[k]),
                                    a[6 * k + 0], a[6 * k + 1], a[6 * k + 2]);
    *(float4*)(r + 4) = make_float4(a[6 * k + 3], a[6 * k + 4], a[6 * k + 5], 0.f);
  }
}

// self-loop attr = mean of incoming edge attrs; 16 lanes per node sweep the
// node's record segment (coalesced 512B per group), butterfly-reduce, and
// lane 0 writes the self record at slot rp[n].
__global__ void __launch_bounds__(256) k_lamean2(const int* __restrict__ rp,
                                                 float* __restrict__ rec) {
  int tid = threadIdx.x;
  int q = tid & 15;
  int n = (blockIdx.x * 256 + tid) >> 4;     // 16 groups/block, exact fit
  if (n >= NN) return;
  int p0 = rp[n], p1 = rp[n + 1];
  float s0 = 0, s1 = 0, s2 = 0, s3 = 0, s4 = 0, s5 = 0;
  for (int p = p0 + 1 + q; p < p1; p += 16) {
    const float* r = rec + (size_t)p * 8;
    float4 r0 = *(const float4*)r;
    float4 r1 = *(const float4*)(r + 4);
    s0 += r0.y; s1 += r0.z; s2 += r0.w;
    s3 += r1.x; s4 += r1.y; s5 += r1.z;
  }
#pragma unroll
  for (int off = 1; off < 16; off <<= 1) {
    s0 += __shfl_xor(s0, off); s1 += __shfl_xor(s1, off);
    s2 += __shfl_xor(s2, off); s3 += __shfl_xor(s3, off);
    s4 += __shfl_xor(s4, off); s5 += __shfl_xor(s5, off);
  }
  if (q == 0) {
    int c = p1 - p0 - 1;
    float inv = c > 0 ? 1.0f / (float)c : 0.0f;
    float* r = rec + (size_t)p0 * 8;
    *(float4*)r       = make_float4(__int_as_float(n), s0 * inv, s1 * inv, s2 * inv);
    *(float4*)(r + 4) = make_float4(s3 * inv, s4 * inv, s5 * inv, 0.f);
  }
}

// ====================== node transforms (xl, xr) ======================
// Wave per 4 nodes per iteration; lane h owns channel h; weights f2-packed
// {wl[k][h], wr[k][h]} in registers. __launch_bounds__(256, 1) lifts the
// VGPR cap to 512 so wpk[64] (128 VGPRs) stays resident — no spill.
// 4 independent pk_fma chains -> ILP covers FMA latency at ~3 waves/SIMD.
template <int DIN>
__global__ void __launch_bounds__(256, 1) k_xform(
    const float* __restrict__ x,
    const float* __restrict__ wl, const float* __restrict__ bl,
    const float* __restrict__ wr, const float* __restrict__ br,
    float* __restrict__ xl, float* __restrict__ xr) {
  int tid = threadIdx.x;
  int lane = tid & 63, wid = tid >> 6;
  int h = lane;
  f2 wpk[DIN];
#pragma unroll
  for (int k = 0; k < DIN; ++k) wpk[k] = (f2){wl[k * 64 + h], wr[k * 64 + h]};
  f2 bpk = (f2){bl[h], br[h]};
  int gw = blockIdx.x * 4 + wid;          // global wave id
  int nw = gridDim.x * 4;                 // total waves
  const int NG = NN / 4;                  // 4-node groups (NN % 4 == 0)
  for (int g = gw; g < NG; g += nw) {
    int n0 = g * 4;
    float xv[4];
#pragma unroll
    for (int j = 0; j < 4; ++j)
      xv[j] = (lane < DIN) ? x[(size_t)(n0 + j) * DIN + lane] : 0.0f;
    f2 acc[4];
#pragma unroll
    for (int j = 0; j < 4; ++j) acc[j] = bpk;
#pragma unroll
    for (int k = 0; k < DIN; ++k) {
#pragma unroll
      for (int j = 0; j < 4; ++j) {
        float xk = __shfl(xv[j], k);
        acc[j] = ffma2(sp2(xk), wpk[k], acc[j]);
      }
    }
#pragma unroll
    for (int j = 0; j < 4; ++j) {
      xl[(size_t)(n0 + j) * 64 + h] = acc[j].x;
      xr[(size_t)(n0 + j) * 64 + h] = acc[j].y;
    }
  }
}

// ============== fused edge-logit + online softmax + aggregate ==============
// 16 lanes per node, 4 channels per lane (2x f2 for v_pk_fma_f32), 4 groups
// per wave. LPT: slots consumed in reverse degree order (heavy blocks first).
// Unrolled by 2 edges; paired online-softmax update (3 exp2 per pair).
__global__ void __launch_bounds__(256) k_fused(
    const float* __restrict__ xl, const float* __restrict__ xr,
    const float* __restrict__ rec,
    const int* __restrict__ rp, const int* __restrict__ order,
    const float* __restrict__ we, const float* __restrict__ att,
    const float* __restrict__ bo, float* __restrict__ hout) {
  int tid = threadIdx.x;
  int lane = tid & 63;
  int q = lane & 15;
  int c0 = q * 4;
  f2 w0a, w0b, w1a, w1b, w2a, w2b, w3a, w3b, w4a, w4b, w5a, w5b;
  w0a = *(const f2*)(we + 0 * 64 + c0); w0b = *(const f2*)(we + 0 * 64 + c0 + 2);
  w1a = *(const f2*)(we + 1 * 64 + c0); w1b = *(const f2*)(we + 1 * 64 + c0 + 2);
  w2a = *(const f2*)(we + 2 * 64 + c0); w2b = *(const f2*)(we + 2 * 64 + c0 + 2);
  w3a = *(const f2*)(we + 3 * 64 + c0); w3b = *(const f2*)(we + 3 * 64 + c0 + 2);
  w4a = *(const f2*)(we + 4 * 64 + c0); w4b = *(const f2*)(we + 4 * 64 + c0 + 2);
  w5a = *(const f2*)(we + 5 * 64 + c0); w5b = *(const f2*)(we + 5 * 64 + c0 + 2);
  f2 ata = *(const f2*)(att + c0) * 1.44269504f;       // fold log2(e)
  f2 atb = *(const f2*)(att + c0 + 2) * 1.44269504f;
  f2 boa = *(const f2*)(bo + c0);
  f2 bob = *(const f2*)(bo + c0 + 2);
  int gw = (blockIdx.x * 256 + tid) >> 6;       // global wave id
  int slot = gw * 4 + (lane >> 4);              // node slot for this group
  int n = (slot < NN) ? order[NN - 1 - slot] : -1;   // LPT: heavy first
  int p0 = 0, p1 = 0;
  f2 xra = (f2){0, 0}, xrb2 = (f2){0, 0};
  if (n >= 0) {
    p0 = rp[n]; p1 = rp[n + 1];
    const f4 t = *(const f4*)(xr + (size_t)n * 64 + c0);
    xra = (f2){t.x, t.y}; xrb2 = (f2){t.z, t.w};
  }
  float m = -INFINITY, den = 0.0f;
  f2 acca = (f2){0, 0}, accb = (f2){0, 0};
  int p = p0;
  for (; p + 2 <= p1; p += 2) {
    const f4* ra = (const f4*)(rec + (size_t)p * 8);
    f4 qa0 = ra[0], qa1 = ra[1], qb0 = ra[2], qb1 = ra[3];
    int sA = __float_as_int(qa0.x), sB = __float_as_int(qb0.x);
    f4 xA = *(const f4*)(xl + (size_t)sA * 64 + c0);
    f4 xB = *(const f4*)(xl + (size_t)sB * 64 + c0);
    f2 xAa = (f2){xA.x, xA.y}, xAb = (f2){xA.z, xA.w};
    f2 xBa = (f2){xB.x, xB.y}, xBb = (f2){xB.z, xB.w};
    // edge A logit (packed pairs)
    f2 tA = xAa + xra;
    tA = ffma2(sp2(qa0.y), w0a, tA); tA = ffma2(sp2(qa0.z), w1a, tA);
    tA = ffma2(sp2(qa0.w), w2a, tA); tA = ffma2(sp2(qa1.x), w3a, tA);
    tA = ffma2(sp2(qa1.y), w4a, tA); tA = ffma2(sp2(qa1.z), w5a, tA);
    f2 pav = fmax2(tA, sp2(0.2f) * tA) * ata;
    f2 uA = xAb + xrb2;
    uA = ffma2(sp2(qa0.y), w0b, uA); uA = ffma2(sp2(qa0.z), w1b, uA);
    uA = ffma2(sp2(qa0.w), w2b, uA); uA = ffma2(sp2(qa1.x), w3b, uA);
    uA = ffma2(sp2(qa1.y), w4b, uA); uA = ffma2(sp2(qa1.z), w5b, uA);
    pav = ffma2(fmax2(uA, sp2(0.2f) * uA), atb, pav);
    // edge B logit
    f2 tB = xBa + xra;
    tB = ffma2(sp2(qb0.y), w0a, tB); tB = ffma2(sp2(qb0.z), w1a, tB);
    tB = ffma2(sp2(qb0.w), w2a, tB); tB = ffma2(sp2(qb1.x), w3a, tB);
    tB = ffma2(sp2(qb1.y), w4a, tB); tB = ffma2(sp2(qb1.z), w5a, tB);
    f2 pbv = fmax2(tB, sp2(0.2f) * tB) * ata;
    f2 uB = xBb + xrb2;
    uB = ffma2(sp2(qb0.y), w0b, uB); uB = ffma2(sp2(qb0.z), w1b, uB);
    uB = ffma2(sp2(qb0.w), w2b, uB); uB = ffma2(sp2(qb1.x), w3b, uB);
    uB = ffma2(sp2(qb1.y), w4b, uB); uB = ffma2(sp2(qb1.z), w5b, uB);
    pbv = ffma2(fmax2(uB, sp2(0.2f) * uB), atb, pbv);
    float pa = pav.x + pav.y;
    float pb = pbv.x + pbv.y;
    pa += __shfl_xor(pa, 1); pb += __shfl_xor(pb, 1);
    pa += __shfl_xor(pa, 2); pb += __shfl_xor(pb, 2);
    pa += __shfl_xor(pa, 4); pb += __shfl_xor(pb, 4);
    pa += __shfl_xor(pa, 8); pb += __shfl_xor(pb, 8);
    float nm = fmaxf(m, fmaxf(pa, pb));
    float sc = exp2f(m - nm);                 // first iter: exp2(-inf)=0
    float eA = exp2f(pa - nm);
    float eB = exp2f(pb - nm);
    m = nm;
    den = fmaf(den, sc, eA + eB);
    acca = ffma2(acca, sp2(sc), ffma2(sp2(eA), xAa, sp2(eB) * xBa));
    accb = ffma2(accb, sp2(sc), ffma2(sp2(eA), xAb, sp2(eB) * xBb));
  }
  if (p < p1) {                                  // tail edge
    const f4* ra = (const f4*)(rec + (size_t)p * 8);
    f4 r0 = ra[0], r1 = ra[1];
    int s = __float_as_int(r0.x);
    f4 xt = *(const f4*)(xl + (size_t)s * 64 + c0);
    f2 xa = (f2){xt.x, xt.y}, xb = (f2){xt.z, xt.w};
    f2 t = xa + xra;
    t = ffma2(sp2(r0.y), w0a, t); t = ffma2(sp2(r0.z), w1a, t);
    t = ffma2(sp2(r0.w), w2a, t); t = ffma2(sp2(r1.x), w3a, t);
    t = ffma2(sp2(r1.y), w4a, t); t = ffma2(sp2(r1.z), w5a, t);
    f2 pv = fmax2(t, sp2(0.2f) * t) * ata;
    f2 u = xb + xrb2;
    u = ffma2(sp2(r0.y), w0b, u); u = ffma2(sp2(r0.z), w1b, u);
    u = ffma2(sp2(r0.w), w2b, u); u = ffma2(sp2(r1.x), w3b, u);
    u = ffma2(sp2(r1.y), w4b, u); u = ffma2(sp2(r1.z), w5b, u);
    pv = ffma2(fmax2(u, sp2(0.2f) * u), atb, pv);
    float part = pv.x + pv.y;
    part += __shfl_xor(part, 1);
    part += __shfl_xor(part, 2);
    part += __shfl_xor(part, 4);
    part += __shfl_xor(part, 8);
    float nm = fmaxf(m, part);
    float sc = exp2f(m - nm);
    float ex = exp2f(part - nm);
    m = nm;
    den = fmaf(den, sc, ex);
    acca = ffma2(acca, sp2(sc), sp2(ex) * xa);
    accb = ffma2(accb, sp2(sc), sp2(ex) * xb);
  }
  if (n >= 0) {
    float inv = 1.0f / (den + 1e-16f);
    f2 oa = ffma2(acca, sp2(inv), boa);
    f2 ob = ffma2(accb, sp2(inv), bob);
    oa = fmax2(oa, (f2){0, 0});
    ob = fmax2(ob, (f2){0, 0});
    f4 o = (f4){oa.x, oa.y, ob.x, ob.y};
    *(f4*)(hout + (size_t)n * 64 + c0) = o;
  }
}

// ====================== MLP head: 64 -> 32 (relu) -> 4 ======================
// Thread-per-node; weights broadcast from LDS; 8 independent f4 acc chains.
__global__ void __launch_bounds__(256) k_mlp2(
    const float* __restrict__ hin,
    const float* __restrict__ wlin, const float* __restrict__ blin,
    const float* __restrict__ wout, const float* __restrict__ bout,
    float* __restrict__ out) {
  __shared__ float wl_s[64 * 32];
  __shared__ float bl_s[32];
  __shared__ float wo_s[32 * 4];
  __shared__ float bo_s[4];
  int tid = threadIdx.x;
#pragma unroll
  for (int i = 0; i < 8; ++i) wl_s[tid + i * 256] = wlin[tid + i * 256];
  if (tid < 128) wo_s[tid] = wout[tid];
  if (tid < 32) bl_s[tid] = blin[tid];
  if (tid >= 32 && tid < 36) bo_s[tid - 32] = bout[tid - 32];
  __syncthreads();
  int n = blockIdx.x * 256 + tid;
  if (n >= NN) return;
  // node features -> 16 f4 regs (contiguous 256B per thread)
  const f4* hp = (const f4*)(hin + (size_t)n * 64);
  f4 h[16];
#pragma unroll
  for (int i = 0; i < 16; ++i) h[i] = hp[i];
  // hidden[32] = relu(h @ wlin + blin): 8 f4 accumulators, broadcast LDS reads
  f4 acc[8];
#pragma unroll
  for (int j4 = 0; j4 < 8; ++j4) acc[j4] = *(const f4*)(bl_s + j4 * 4);
#pragma unroll
  for (int k = 0; k < 64; ++k) {
    float hk = ((const float*)h)[k];
    const f4* wrow = (const f4*)(wl_s + k * 32);
#pragma unroll
    for (int j4 = 0; j4 < 8; ++j4)
      acc[j4] = ffma4(sp4(hk), wrow[j4], acc[j4]);
  }
  // out[4] = relu(hidden) @ wout + bout
  f4 o4 = *(const f4*)(bo_s);
#pragma unroll
  for (int j4 = 0; j4 < 8; ++j4) {
    f4 hid = fmax4(acc[j4], sp4(0.0f));
    const f4* wo = (const f4*)(wo_s + j4 * 16);
    o4 = ffma4(sp4(hid.x), wo[0], o4);
    o4 = ffma4(sp4(hid.y), wo[1], o4);
    o4 = ffma4(sp4(hid.z), wo[2], o4);
    o4 = ffma4(sp4(hid.w), wo[3], o4);
  }
  *(f4*)(out + (size_t)n * 4) = o4;
}

// ============================ launch ============================

extern "C" void kernel_launch(void* const* d_in, const int* in_sizes, int n_in,
                              void* d_out, int out_size, void* d_ws, size_t ws_size,
                              hipStream_t stream) {
  const float* x  = (const float*)d_in[0];
  const int*   ei = (const int*)d_in[1];
  const float* ea = (const float*)d_in[2];
  const int* src = ei;
  const int* dst = ei + NE;

  const float *wl[3], *bl[3], *wrm[3], *br[3], *wem[3], *attv[3], *bov[3];
  for (int l = 0; l < 3; ++l) {
    int b = 3 + l * 7;
    wl[l]  = (const float*)d_in[b + 0];
    bl[l]  = (const float*)d_in[b + 1];
    wrm[l] = (const float*)d_in[b + 2];
    br[l]  = (const float*)d_in[b + 3];
    wem[l] = (const float*)d_in[b + 4];
    attv[l]= (const float*)d_in[b + 5];
    bov[l] = (const float*)d_in[b + 6];
  }
  const float* wlin = (const float*)d_in[24];
  const float* blin = (const float*)d_in[25];
  const float* wout = (const float*)d_in[26];
  const float* bout = (const float*)d_in[27];
  float* outp = (float*)d_out;

  // workspace carve (256B aligned)
  char* w = (char*)d_ws;
  size_t off = 0;
  auto carve = [&](size_t bytes) -> void* {
    void* p = w + off;
    off += (bytes + 255) & ~(size_t)255;
    return p;
  };
  int*   cnt  = (int*)carve((size_t)NN * 4);
  int*   rp   = (int*)carve((size_t)(NN + 1) * 4);
  int*   bsum = (int*)carve(1024 * 4);
  int*   boff = (int*)carve(1024 * 4);
  int*   hist = (int*)carve(64 * 4);
  int*   cur2 = (int*)carve(64 * 4);
  int*   order= (int*)carve((size_t)NN * 4);
  int*   rank = (int*)carve((size_t)NE * 4);
  float* rec  = (float*)carve((size_t)NEP * 32);      // 32B records
  float* xlb  = (float*)carve((size_t)NN * 64 * 4);
  float* xrb  = (float*)carve((size_t)NN * 64 * 4);
  float* hA   = (float*)carve((size_t)NN * 64 * 4);
  float* hB   = (float*)carve((size_t)NN * 64 * 4);
  (void)ws_size; (void)n_in; (void)in_sizes; (void)out_size;

  const int SCAN_NB = (NN + 1023) / 1024;  // 98
  const int FUSE_NB = (NN + 15) / 16;      // 6250 blocks: 4 waves x 4 groups each
  const int CR_NB   = (NE / 4 + 255) / 256;
  const int XF_NB   = 1024;                // grid-stride; weights amortized

  hipLaunchKernelGGL(k_init_cnt, dim3((NN + 255) / 256), dim3(256), 0, stream,
                     cnt, hist, cur2);
  hipLaunchKernelGGL(k_count_rank, dim3(CR_NB), dim3(256), 0, stream, dst, cnt, rank);
  hipLaunchKernelGGL(k_scan_a, dim3(SCAN_NB), dim3(1024), 0, stream, cnt, rp, bsum, hist);
  hipLaunchKernelGGL(k_scan_b, dim3(1), dim3(1024), 0, stream, bsum, boff, SCAN_NB,
                     hist, cur2);
  hipLaunchKernelGGL(k_scan_c, dim3(SCAN_NB), dim3(1024), 0, stream, rp, boff, cnt,
                     cur2, order);
  hipLaunchKernelGGL(k_scatter3, dim3(CR_NB), dim3(256), 0, stream,
                     src, dst, rank, ea, rp, rec);
  hipLaunchKernelGGL(k_lamean2, dim3((NN + 15) / 16), dim3(256), 0, stream, rp, rec);

  // layer 1 (din=6): x -> hA
  hipLaunchKernelGGL((k_xform<6>), dim3(XF_NB), dim3(256), 0, stream,
                     x, wl[0], bl[0], wrm[0], br[0], xlb, xrb);
  hipLaunchKernelGGL(k_fused, dim3(FUSE_NB), dim3(256), 0, stream,
                     xlb, xrb, rec, rp, order, wem[0], attv[0], bov[0], hA);
  // layer 2: hA -> hB
  hipLaunchKernelGGL((k_xform<64>), dim3(XF_NB), dim3(256), 0, stream,
                     hA, wl[1], bl[1], wrm[1], br[1], xlb, xrb);
  hipLaunchKernelGGL(k_fused, dim3(FUSE_NB), dim3(256), 0, stream,
                     xlb, xrb, rec, rp, order, wem[1], attv[1], bov[1], hB);
  // layer 3: hB -> hA
  hipLaunchKernelGGL((k_xform<64>), dim3(XF_NB), dim3(256), 0, stream,
                     hB, wl[2], bl[2], wrm[2], br[2], xlb, xrb);
  hipLaunchKernelGGL(k_fused, dim3(FUSE_NB), dim3(256), 0, stream,
                     xlb, xrb, rec, rp, order, wem[2], attv[2], bov[2], hA);
  // MLP head
  hipLaunchKernelGGL(k_mlp2, dim3((NN + 255) / 256), dim3(256), 0, stream,
                     hA, wlin, blin, wout, bout, outp);
}